// Round 1
// baseline (3797.763 us; speedup 1.0000x reference)
//
#include <hip/hip_runtime.h>
#include <math.h>

#define HDIM 128
#define TPB 256
#define BM 64
#define BK 32

static inline int ceil_div(int a, int b){ return (a + b - 1) / b; }

__device__ __forceinline__ float wave_sum(float v){
#pragma unroll
  for (int o = 32; o > 0; o >>= 1) v += __shfl_down(v, o, 64);
  return v;
}

// ---------------------------------------------------------------------------
// 1. Edge raw features (rel, |rel|) + running sums for edge stats
// stats_raw layout (floats): e_sum[0..2] e_sq[3..5] n_sum[6..8] n_sq[9..11]
//                            t_sum[12..14] t_sq[15..17] loss[18] rmse[19..21]
// ---------------------------------------------------------------------------
__global__ void edge_raw_stats(const float* __restrict__ pos,
                               const int* __restrict__ snd,
                               const int* __restrict__ rcv,
                               float* __restrict__ ef_raw,
                               float* __restrict__ stats_raw, int E){
  int e = blockIdx.x * blockDim.x + threadIdx.x;
  float v0=0.f,v1=0.f,v2=0.f,q0=0.f,q1=0.f,q2=0.f;
  if (e < E){
    int s = snd[e], r = rcv[e];
    float rx = pos[2*s]   - pos[2*r];
    float ry = pos[2*s+1] - pos[2*r+1];
    float nm = sqrtf(rx*rx + ry*ry);
    ef_raw[3*e]   = rx;
    ef_raw[3*e+1] = ry;
    ef_raw[3*e+2] = nm;
    v0 = rx; v1 = ry; v2 = nm;
    q0 = rx*rx; q1 = ry*ry; q2 = nm*nm;
  }
  v0 = wave_sum(v0); v1 = wave_sum(v1); v2 = wave_sum(v2);
  q0 = wave_sum(q0); q1 = wave_sum(q1); q2 = wave_sum(q2);
  if ((threadIdx.x & 63) == 0){
    atomicAdd(&stats_raw[0], v0); atomicAdd(&stats_raw[1], v1); atomicAdd(&stats_raw[2], v2);
    atomicAdd(&stats_raw[3], q0); atomicAdd(&stats_raw[4], q1); atomicAdd(&stats_raw[5], q2);
  }
}

// ---------------------------------------------------------------------------
// 2. Node stats: zl stats + target(=z_target - zl) stats
// ---------------------------------------------------------------------------
__global__ void node_stats(const float* __restrict__ zl,
                           const float* __restrict__ z_target,
                           float* __restrict__ stats_raw, int N){
  int n = blockIdx.x * blockDim.x + threadIdx.x;
  float s[12];
#pragma unroll
  for (int i = 0; i < 12; i++) s[i] = 0.f;
  if (n < N){
#pragma unroll
    for (int d = 0; d < 3; d++){
      float z = zl[3*n+d];
      float t = z_target[3*n+d] - z;
      s[d]   = z;  s[3+d] = z*z;
      s[6+d] = t;  s[9+d] = t*t;
    }
  }
#pragma unroll
  for (int i = 0; i < 12; i++) s[i] = wave_sum(s[i]);
  if ((threadIdx.x & 63) == 0){
#pragma unroll
    for (int i = 0; i < 12; i++) atomicAdd(&stats_raw[6+i], s[i]);
  }
}

// ---------------------------------------------------------------------------
// 3. Finalize stats -> stats_fin: em[0..2] es[3..5] nm[6..8] ns[9..11]
//                                 om[12..14] os[15..17]
// ---------------------------------------------------------------------------
__global__ void finalize_stats(const float* __restrict__ raw,
                               float* __restrict__ fin, int E, int N){
  // single thread; trivial
#pragma unroll
  for (int d = 0; d < 3; d++){
    float cE = (float)E, cN = (float)N;
    float m, v;
    m = raw[0+d] / cE; v = fmaxf(raw[3+d]/cE - m*m, 0.f);
    fin[0+d] = m;  fin[3+d]  = fmaxf(sqrtf(v), 1e-8f);
    m = raw[6+d] / cN; v = fmaxf(raw[9+d]/cN - m*m, 0.f);
    fin[6+d] = m;  fin[9+d]  = fmaxf(sqrtf(v), 1e-8f);
    m = raw[12+d] / cN; v = fmaxf(raw[15+d]/cN - m*m, 0.f);
    fin[12+d] = m; fin[15+d] = fmaxf(sqrtf(v), 1e-8f);
  }
}

// ---------------------------------------------------------------------------
// 4. Encoder hidden layer: K=3 -> H, relu. raw is [rows,3], normalized on the fly
// ---------------------------------------------------------------------------
__global__ void enc_hidden(const float* __restrict__ raw,
                           const float* __restrict__ mptr,
                           const float* __restrict__ sptr,
                           const float* __restrict__ W1,
                           const float* __restrict__ b1,
                           float* __restrict__ h, int rows){
  int tid = blockIdx.x * blockDim.x + threadIdx.x;
  int r = tid >> 7;          // /128
  int j = tid & 127;
  if (r >= rows) return;
  float x0 = (raw[3*r]   - mptr[0]) / sptr[0];
  float x1 = (raw[3*r+1] - mptr[1]) / sptr[1];
  float x2 = (raw[3*r+2] - mptr[2]) / sptr[2];
  float acc = b1[j];
  acc += x0 * W1[j];
  acc += x1 * W1[HDIM + j];
  acc += x2 * W1[2*HDIM + j];
  h[(size_t)r*HDIM + j] = fmaxf(acc, 0.f);
}

// ---------------------------------------------------------------------------
// 5. Generic tiled GEMM: out[rows,128] = act(A[rows,K] @ W[K,128] + b) (+res)
//    A columns are segments of 128: seg0=A0 (identity rows), seg1=A1 (idx1 or
//    identity), seg2=A2 (idx2 or identity). K in {128,256,384}.
//    BM=64 rows/block, BN=128 (full), BK=32, 256 threads, 4x8 thread tile.
// ---------------------------------------------------------------------------
__launch_bounds__(256)
__global__ void gemm128(const float* __restrict__ A0,
                        const float* __restrict__ A1,
                        const float* __restrict__ A2,
                        const int* __restrict__ idx1,
                        const int* __restrict__ idx2,
                        const float* __restrict__ W,
                        const float* __restrict__ bias,
                        const float* __restrict__ res,
                        float* __restrict__ out,
                        int rows, int K, int relu){
  __shared__ float As[BK * 65];      // [k][m], stride 65 (conflict-free)
  __shared__ float Ws[BK * HDIM];    // [k][n]
  const int tid = threadIdx.x;
  const int tx = tid & 15;           // 16 col groups
  const int ty = tid >> 4;           // 16 row groups
  const int row0 = blockIdx.x * BM;
  float acc[4][8];
#pragma unroll
  for (int i = 0; i < 4; i++)
#pragma unroll
    for (int j = 0; j < 8; j++) acc[i][j] = 0.f;

  const int nkt = K >> 5;
  for (int kt = 0; kt < nkt; kt++){
    const int seg = kt >> 2;
    const int colbase = (kt & 3) * 32;
    const float* base = (seg == 0) ? A0 : ((seg == 1) ? A1 : A2);
    const int*   idx  = (seg == 0) ? (const int*)nullptr : ((seg == 1) ? idx1 : idx2);
#pragma unroll
    for (int i = 0; i < 8; i++){
      int lin = tid + i * 256;       // 0..2047
      int r  = lin >> 5;
      int cc = lin & 31;
      int e  = row0 + r;
      float v = 0.f;
      if (e < rows){
        int ri = idx ? idx[e] : e;
        v = base[(size_t)ri * HDIM + colbase + cc];
      }
      As[cc * 65 + r] = v;
    }
#pragma unroll
    for (int i = 0; i < 16; i++){
      int lin = tid + i * 256;       // 0..4095
      int kr = lin >> 7;
      int c  = lin & 127;
      Ws[kr * HDIM + c] = W[(size_t)(kt * 32 + kr) * HDIM + c];
    }
    __syncthreads();
#pragma unroll
    for (int k = 0; k < BK; k++){
      float a[4], b[8];
#pragma unroll
      for (int i = 0; i < 4; i++) a[i] = As[k * 65 + ty * 4 + i];
#pragma unroll
      for (int j = 0; j < 4; j++){
        b[j]     = Ws[k * HDIM + tx * 4 + j];
        b[4 + j] = Ws[k * HDIM + 64 + tx * 4 + j];
      }
#pragma unroll
      for (int i = 0; i < 4; i++)
#pragma unroll
        for (int j = 0; j < 8; j++) acc[i][j] += a[i] * b[j];
    }
    __syncthreads();
  }

#pragma unroll
  for (int i = 0; i < 4; i++){
    int r = row0 + ty * 4 + i;
    if (r >= rows) continue;
#pragma unroll
    for (int j = 0; j < 8; j++){
      int c = (j < 4) ? (tx * 4 + j) : (64 + tx * 4 + (j - 4));
      float v = acc[i][j] + bias[c];
      if (relu) v = fmaxf(v, 0.f);
      if (res)  v += res[(size_t)r * HDIM + c];
      out[(size_t)r * HDIM + c] = v;
    }
  }
}

// ---------------------------------------------------------------------------
// 6. Segment sum (scatter-add): agg[rcv[e]] += ef[e]
// ---------------------------------------------------------------------------
__global__ void segsum(const float* __restrict__ ef,
                       const int* __restrict__ rcv,
                       float* __restrict__ agg, int E){
  int tid = blockIdx.x * blockDim.x + threadIdx.x;
  if (tid >= E * HDIM) return;
  int e = tid >> 7;
  int j = tid & 127;
  atomicAdd(&agg[(size_t)rcv[e] * HDIM + j], ef[tid]);
}

// ---------------------------------------------------------------------------
// 7. Decoder final layer: [rows,128] @ [128,3] + b -> dec_out[rows,3]
// ---------------------------------------------------------------------------
__global__ void dec_final(const float* __restrict__ hbuf,
                          const float* __restrict__ W2,
                          const float* __restrict__ b2,
                          float* __restrict__ outd, int rows){
  __shared__ float hl[64 * 129];
  __shared__ float Wl[HDIM * 3];
  __shared__ float bl[3];
  int t = threadIdx.x;
  int node0 = blockIdx.x * 64;
  for (int i = t; i < HDIM * 3; i += 256) Wl[i] = W2[i];
  if (t < 3) bl[t] = b2[t];
#pragma unroll
  for (int i = 0; i < 32; i++){
    int lin = t + i * 256;           // 0..8191
    int r = lin >> 7;
    int c = lin & 127;
    int node = node0 + r;
    hl[r * 129 + c] = (node < rows) ? hbuf[(size_t)node * HDIM + c] : 0.f;
  }
  __syncthreads();
  if (t < 64){
    int node = node0 + t;
    if (node < rows){
      float a0 = bl[0], a1 = bl[1], a2 = bl[2];
      for (int k = 0; k < HDIM; k++){
        float v = hl[t * 129 + k];
        a0 += v * Wl[k * 3];
        a1 += v * Wl[k * 3 + 1];
        a2 += v * Wl[k * 3 + 2];
      }
      outd[3 * node]     = a0;
      outd[3 * node + 1] = a1;
      outd[3 * node + 2] = a2;
    }
  }
}

// ---------------------------------------------------------------------------
// 8. Epilogue: z_pred, loss partials, rmse partials
// ---------------------------------------------------------------------------
__global__ void epilogue(const float* __restrict__ dec_out,
                         const float* __restrict__ zl,
                         const float* __restrict__ z_target,
                         const float* __restrict__ fin,
                         float* __restrict__ d_out,
                         float* __restrict__ stats_raw, int N){
  int n = blockIdx.x * blockDim.x + threadIdx.x;
  float lsum = 0.f, r0 = 0.f, r1 = 0.f, r2 = 0.f;
  if (n < N){
#pragma unroll
    for (int d = 0; d < 3; d++){
      float om = fin[12 + d], os = fin[15 + d];
      float o   = dec_out[3*n + d];
      float zld = zl[3*n + d];
      float zt  = z_target[3*n + d];
      float tgt = zt - zld;
      float tn  = (tgt - om) / os;
      float diff = tn - o;
      lsum += diff * diff;
      float zp = zld + o * os + om;
      d_out[3*n + d] = zp;
      float e = zp - zt;
      e = e * e;
      if (d == 0) r0 = e; else if (d == 1) r1 = e; else r2 = e;
    }
  }
  lsum = wave_sum(lsum); r0 = wave_sum(r0); r1 = wave_sum(r1); r2 = wave_sum(r2);
  if ((threadIdx.x & 63) == 0){
    atomicAdd(&stats_raw[18], lsum);
    atomicAdd(&stats_raw[19], r0);
    atomicAdd(&stats_raw[20], r1);
    atomicAdd(&stats_raw[21], r2);
  }
}

__global__ void finalize_out(const float* __restrict__ raw,
                             float* __restrict__ d_out, int N){
  float cN = (float)N;
  float loss = raw[18] / (3.f * cN);
  float rmse = (sqrtf(raw[19] / cN) + sqrtf(raw[20] / cN) + sqrtf(raw[21] / cN)) / 3.f;
  d_out[(size_t)3 * N]     = loss;
  d_out[(size_t)3 * N + 1] = rmse;
}

// ---------------------------------------------------------------------------
extern "C" void kernel_launch(void* const* d_in, const int* in_sizes, int n_in,
                              void* d_out, int out_size, void* d_ws, size_t ws_size,
                              hipStream_t stream){
  const float* z           = (const float*)d_in[0];
  const float* z_target    = (const float*)d_in[1];
  const float* pos         = (const float*)d_in[2];
  const float* enc_node_W1 = (const float*)d_in[3];
  const float* enc_node_b1 = (const float*)d_in[4];
  const float* enc_node_W2 = (const float*)d_in[5];
  const float* enc_node_b2 = (const float*)d_in[6];
  const float* enc_edge_W1 = (const float*)d_in[7];
  const float* enc_edge_b1 = (const float*)d_in[8];
  const float* enc_edge_W2 = (const float*)d_in[9];
  const float* enc_edge_b2 = (const float*)d_in[10];
  const float* dec_W1      = (const float*)d_in[11];
  const float* dec_b1      = (const float*)d_in[12];
  const float* dec_W2      = (const float*)d_in[13];
  const float* dec_b2      = (const float*)d_in[14];
  const float* blk_edge_W1 = (const float*)d_in[15];
  const float* blk_edge_b1 = (const float*)d_in[16];
  const float* blk_edge_W2 = (const float*)d_in[17];
  const float* blk_edge_b2 = (const float*)d_in[18];
  const float* blk_node_W1 = (const float*)d_in[19];
  const float* blk_node_b1 = (const float*)d_in[20];
  const float* blk_node_W2 = (const float*)d_in[21];
  const float* blk_node_b2 = (const float*)d_in[22];
  const int*   senders     = (const int*)d_in[23];
  const int*   receivers   = (const int*)d_in[24];

  const int N = in_sizes[1] / 3;
  const int E = in_sizes[23];
  const float* zl = z + (size_t)N * 3;   // z[-1] with T=2

  float* ws        = (float*)d_ws;
  float* stats_raw = ws;                        // 32 floats
  float* stats_fin = ws + 32;                   // 18 floats
  float* ef_raw    = ws + 64;                   // E*3
  float* ef        = ef_raw + (size_t)E * 3;    // E*128
  float* hbuf      = ef + (size_t)E * HDIM;     // E*128 (reused for node hiddens)
  float* nf        = hbuf + (size_t)E * HDIM;   // N*128
  float* agg       = nf + (size_t)N * HDIM;     // N*128
  float* dec_out   = agg + (size_t)N * HDIM;    // N*3

  float* out = (float*)d_out;

  hipMemsetAsync(stats_raw, 0, 64 * sizeof(float), stream);

  edge_raw_stats<<<ceil_div(E, TPB), TPB, 0, stream>>>(pos, senders, receivers, ef_raw, stats_raw, E);
  node_stats<<<ceil_div(N, TPB), TPB, 0, stream>>>(zl, z_target, stats_raw, N);
  finalize_stats<<<1, 1, 0, stream>>>(stats_raw, stats_fin, E, N);

  // --- encoders ---
  enc_hidden<<<ceil_div(E * HDIM, TPB), TPB, 0, stream>>>(ef_raw, stats_fin + 0, stats_fin + 3,
                                                          enc_edge_W1, enc_edge_b1, hbuf, E);
  gemm128<<<ceil_div(E, BM), TPB, 0, stream>>>(hbuf, nullptr, nullptr, nullptr, nullptr,
                                               enc_edge_W2, enc_edge_b2, nullptr, ef, E, 128, 0);
  enc_hidden<<<ceil_div(N * HDIM, TPB), TPB, 0, stream>>>(zl, stats_fin + 6, stats_fin + 9,
                                                          enc_node_W1, enc_node_b1, hbuf, N);
  gemm128<<<ceil_div(N, BM), TPB, 0, stream>>>(hbuf, nullptr, nullptr, nullptr, nullptr,
                                               enc_node_W2, enc_node_b2, nullptr, nf, N, 128, 0);

  // --- message-passing blocks ---
  for (int b = 0; b < 4; b++){
    const float* eW1 = blk_edge_W1 + (size_t)b * 384 * 128;
    const float* eb1 = blk_edge_b1 + (size_t)b * 128;
    const float* eW2 = blk_edge_W2 + (size_t)b * 128 * 128;
    const float* eb2 = blk_edge_b2 + (size_t)b * 128;
    const float* nW1 = blk_node_W1 + (size_t)b * 256 * 128;
    const float* nb1 = blk_node_b1 + (size_t)b * 128;
    const float* nW2 = blk_node_W2 + (size_t)b * 128 * 128;
    const float* nb2 = blk_node_b2 + (size_t)b * 128;

    // edge MLP layer 1: [ef | nf[snd] | nf[rcv]] (K=384) -> hbuf, relu
    gemm128<<<ceil_div(E, BM), TPB, 0, stream>>>(ef, nf, nf, senders, receivers,
                                                 eW1, eb1, nullptr, hbuf, E, 384, 1);
    // edge MLP layer 2 + residual -> ef
    gemm128<<<ceil_div(E, BM), TPB, 0, stream>>>(hbuf, nullptr, nullptr, nullptr, nullptr,
                                                 eW2, eb2, ef, ef, E, 128, 0);
    // segment sum
    hipMemsetAsync(agg, 0, (size_t)N * HDIM * sizeof(float), stream);
    segsum<<<ceil_div(E * HDIM, TPB), TPB, 0, stream>>>(ef, receivers, agg, E);
    // node MLP layer 1: [nf | agg] (K=256) -> hbuf, relu
    gemm128<<<ceil_div(N, BM), TPB, 0, stream>>>(nf, agg, nullptr, nullptr, nullptr,
                                                 nW1, nb1, nullptr, hbuf, N, 256, 1);
    // node MLP layer 2 + residual -> nf
    gemm128<<<ceil_div(N, BM), TPB, 0, stream>>>(hbuf, nullptr, nullptr, nullptr, nullptr,
                                                 nW2, nb2, nf, nf, N, 128, 0);
  }

  // --- decoder ---
  gemm128<<<ceil_div(N, BM), TPB, 0, stream>>>(nf, nullptr, nullptr, nullptr, nullptr,
                                               dec_W1, dec_b1, nullptr, hbuf, N, 128, 1);
  dec_final<<<ceil_div(N, BM), TPB, 0, stream>>>(hbuf, dec_W2, dec_b2, dec_out, N);

  // --- loss / rmse / z_pred ---
  epilogue<<<ceil_div(N, TPB), TPB, 0, stream>>>(dec_out, zl, z_target, stats_fin,
                                                 out, stats_raw, N);
  finalize_out<<<1, 1, 0, stream>>>(stats_raw, out, N);
}

// Round 2
// 1601.826 us; speedup vs baseline: 2.3709x; 2.3709x over previous
//
#include <hip/hip_runtime.h>
#include <hip/hip_bf16.h>
#include <math.h>

#define HDIM 128
#define TPB 256

typedef __attribute__((ext_vector_type(8))) short bf16x8;
typedef __attribute__((ext_vector_type(4))) float f32x4;

static inline int ceil_div(int a, int b){ return (a + b - 1) / b; }

__device__ __forceinline__ float wave_sum(float v){
#pragma unroll
  for (int o = 32; o > 0; o >>= 1) v += __shfl_down(v, o, 64);
  return v;
}

__device__ __forceinline__ short f2bf(float f){
  __hip_bfloat16 h = __float2bfloat16(f);
  return *reinterpret_cast<short*>(&h);
}
__device__ __forceinline__ float bf2f(__hip_bfloat16 h){ return __bfloat162float(h); }

// ---------------------------------------------------------------------------
// stats_raw layout (floats): e_sum[0..2] e_sq[3..5] n_sum[6..8] n_sq[9..11]
//                            t_sum[12..14] t_sq[15..17] loss[18] rmse[19..21]
// ---------------------------------------------------------------------------
__global__ void edge_raw_stats(const float* __restrict__ pos,
                               const int* __restrict__ snd,
                               const int* __restrict__ rcv,
                               float* __restrict__ ef_raw,
                               float* __restrict__ stats_raw, int E){
  int e = blockIdx.x * blockDim.x + threadIdx.x;
  float v0=0.f,v1=0.f,v2=0.f,q0=0.f,q1=0.f,q2=0.f;
  if (e < E){
    int s = snd[e], r = rcv[e];
    float rx = pos[2*s]   - pos[2*r];
    float ry = pos[2*s+1] - pos[2*r+1];
    float nm = sqrtf(rx*rx + ry*ry);
    ef_raw[3*e]   = rx;
    ef_raw[3*e+1] = ry;
    ef_raw[3*e+2] = nm;
    v0 = rx; v1 = ry; v2 = nm;
    q0 = rx*rx; q1 = ry*ry; q2 = nm*nm;
  }
  v0 = wave_sum(v0); v1 = wave_sum(v1); v2 = wave_sum(v2);
  q0 = wave_sum(q0); q1 = wave_sum(q1); q2 = wave_sum(q2);
  if ((threadIdx.x & 63) == 0){
    atomicAdd(&stats_raw[0], v0); atomicAdd(&stats_raw[1], v1); atomicAdd(&stats_raw[2], v2);
    atomicAdd(&stats_raw[3], q0); atomicAdd(&stats_raw[4], q1); atomicAdd(&stats_raw[5], q2);
  }
}

__global__ void node_stats(const float* __restrict__ zl,
                           const float* __restrict__ z_target,
                           float* __restrict__ stats_raw, int N){
  int n = blockIdx.x * blockDim.x + threadIdx.x;
  float s[12];
#pragma unroll
  for (int i = 0; i < 12; i++) s[i] = 0.f;
  if (n < N){
#pragma unroll
    for (int d = 0; d < 3; d++){
      float z = zl[3*n+d];
      float t = z_target[3*n+d] - z;
      s[d]   = z;  s[3+d] = z*z;
      s[6+d] = t;  s[9+d] = t*t;
    }
  }
#pragma unroll
  for (int i = 0; i < 12; i++) s[i] = wave_sum(s[i]);
  if ((threadIdx.x & 63) == 0){
#pragma unroll
    for (int i = 0; i < 12; i++) atomicAdd(&stats_raw[6+i], s[i]);
  }
}

// stats_fin: em[0..2] es[3..5] nm[6..8] ns[9..11] om[12..14] os[15..17]
__global__ void finalize_stats(const float* __restrict__ raw,
                               float* __restrict__ fin, int E, int N){
#pragma unroll
  for (int d = 0; d < 3; d++){
    float cE = (float)E, cN = (float)N;
    float m, v;
    m = raw[0+d] / cE; v = fmaxf(raw[3+d]/cE - m*m, 0.f);
    fin[0+d] = m;  fin[3+d]  = fmaxf(sqrtf(v), 1e-8f);
    m = raw[6+d] / cN; v = fmaxf(raw[9+d]/cN - m*m, 0.f);
    fin[6+d] = m;  fin[9+d]  = fmaxf(sqrtf(v), 1e-8f);
    m = raw[12+d] / cN; v = fmaxf(raw[15+d]/cN - m*m, 0.f);
    fin[12+d] = m; fin[15+d] = fmaxf(sqrtf(v), 1e-8f);
  }
}

// ---------------------------------------------------------------------------
// Weight packing: fp32 row-major [K][128] -> bf16 transposed [128][K]
// wpack layout (bf16 elems):
//  0      : enc_edge_W2   (128x128 -> 16384)
//  16384  : enc_node_W2   (16384)
//  32768  : dec_W1        (16384)
//  49152 + b*114688 : eW1_b (49152) | +49152 eW2_b (16384) | +65536 nW1_b (32768) | +98304 nW2_b (16384)
// ---------------------------------------------------------------------------
__global__ void pack_weights(const float* __restrict__ encEW2,
                             const float* __restrict__ encNW2,
                             const float* __restrict__ decW1,
                             const float* __restrict__ beW1,
                             const float* __restrict__ beW2,
                             const float* __restrict__ bnW1,
                             const float* __restrict__ bnW2,
                             __hip_bfloat16* __restrict__ wp){
  int y = blockIdx.y;
  const float* src; __hip_bfloat16* dst; int K;
  if (y == 0){ src = encEW2; dst = wp;          K = 128; }
  else if (y == 1){ src = encNW2; dst = wp + 16384; K = 128; }
  else if (y == 2){ src = decW1;  dst = wp + 32768; K = 128; }
  else {
    int b = (y - 3) >> 2, j = (y - 3) & 3;
    __hip_bfloat16* base = wp + 49152 + b * 114688;
    if (j == 0){ src = beW1 + b*49152; dst = base;          K = 384; }
    else if (j == 1){ src = beW2 + b*16384; dst = base + 49152; K = 128; }
    else if (j == 2){ src = bnW1 + b*32768; dst = base + 65536; K = 256; }
    else { src = bnW2 + b*16384; dst = base + 98304; K = 128; }
  }
  int id = blockIdx.x * blockDim.x + threadIdx.x;
  if (id >= 128 * K) return;
  int n = id / K, k = id - n * K;
  dst[id] = __float2bfloat16(src[k * 128 + n]);
}

// ---------------------------------------------------------------------------
// Encoder hidden: K=3 -> 128, relu, bf16 out
// ---------------------------------------------------------------------------
__global__ void enc_hidden(const float* __restrict__ raw,
                           const float* __restrict__ mptr,
                           const float* __restrict__ sptr,
                           const float* __restrict__ W1,
                           const float* __restrict__ b1,
                           __hip_bfloat16* __restrict__ h, int rows){
  int tid = blockIdx.x * blockDim.x + threadIdx.x;
  int r = tid >> 7;
  int j = tid & 127;
  if (r >= rows) return;
  float x0 = (raw[3*r]   - mptr[0]) / sptr[0];
  float x1 = (raw[3*r+1] - mptr[1]) / sptr[1];
  float x2 = (raw[3*r+2] - mptr[2]) / sptr[2];
  float acc = b1[j] + x0 * W1[j] + x1 * W1[HDIM + j] + x2 * W1[2*HDIM + j];
  h[(size_t)r*HDIM + j] = __float2bfloat16(fmaxf(acc, 0.f));
}

// ---------------------------------------------------------------------------
// Plain MFMA GEMM: out[rows,128] = act(A[rows,128] @ Wt^T + b)
// Wt is [128 out][128 in] bf16. 64 rows/block, wave w -> rows w*16..w*16+15.
// A-frag: A[m=lane&15][k=quad*8+j]; B-frag: B[n=lane&15][k=quad*8+j];
// D: col=lane&15 (+16t), row=quad*4+reg.
// ---------------------------------------------------------------------------
__launch_bounds__(256)
__global__ void mfma_gemm128(const __hip_bfloat16* __restrict__ A,
                             const __hip_bfloat16* __restrict__ Wt,
                             const float* __restrict__ bias,
                             __hip_bfloat16* __restrict__ out_bf,
                             float* __restrict__ out_f32,
                             int rows, int relu){
  const int tid = threadIdx.x, w = tid >> 6, l = tid & 63, m = l & 15, q = l >> 4;
  const int row_a = blockIdx.x * 64 + w * 16 + m;
  const int ra = min(row_a, rows - 1);
  const short* pa0 = (const short*)A + (size_t)ra * HDIM + q * 8;
  const short* pb0 = (const short*)Wt + m * 128 + q * 8;
  f32x4 acc[8];
#pragma unroll
  for (int t = 0; t < 8; t++) acc[t] = (f32x4){0.f,0.f,0.f,0.f};
#pragma unroll
  for (int c = 0; c < 4; c++){
    bf16x8 a = *(const bf16x8*)(pa0 + c * 32);
#pragma unroll
    for (int t = 0; t < 8; t++){
      bf16x8 b = *(const bf16x8*)(pb0 + t * 16 * 128 + c * 32);
      acc[t] = __builtin_amdgcn_mfma_f32_16x16x32_bf16(a, b, acc[t], 0, 0, 0);
    }
  }
  const int row_d = blockIdx.x * 64 + w * 16 + q * 4;
#pragma unroll
  for (int t = 0; t < 8; t++){
    int col = t * 16 + m;
    float bb = bias[col];
#pragma unroll
    for (int r = 0; r < 4; r++){
      int e = row_d + r;
      if (e < rows){
        float v = acc[t][r] + bb;
        if (relu) v = fmaxf(v, 0.f);
        if (out_bf) out_bf[(size_t)e * HDIM + col] = __float2bfloat16(v);
        else        out_f32[(size_t)e * HDIM + col] = v;
      }
    }
  }
}

// ---------------------------------------------------------------------------
// Fused edge block: ef += MLP([ef | nf[snd] | nf[rcv]]); agg[rcv] += ef_new
// K1=384, K2=128. No barriers: each wave owns its 16 rows end-to-end;
// hidden round-trips through a wave-private LDS tile (16x136, pad=8 -> 2-way
// bank aliasing only, free). In-place ef update is safe: all reads of a row
// precede its write within the owning wave; no cross-wave row sharing.
// ---------------------------------------------------------------------------
__launch_bounds__(256)
__global__ void edge_block(const int* __restrict__ snd,
                           const int* __restrict__ rcv,
                           const __hip_bfloat16* __restrict__ nf,
                           __hip_bfloat16* __restrict__ ef,
                           const __hip_bfloat16* __restrict__ W1t,  // [128][384]
                           const float* __restrict__ b1,
                           const __hip_bfloat16* __restrict__ W2t,  // [128][128]
                           const float* __restrict__ b2,
                           float* __restrict__ agg,
                           int E){
  __shared__ __align__(16) short hsh[4][16][136];
  const int tid = threadIdx.x, w = tid >> 6, l = tid & 63, m = l & 15, q = l >> 4;
  const int row_a = blockIdx.x * 64 + w * 16 + m;
  const int ra = min(row_a, E - 1);
  const int si = snd[ra], ri = rcv[ra];
  const short* pe = (const short*)ef + (size_t)ra * HDIM + q * 8;
  const short* ps = (const short*)nf + (size_t)si * HDIM + q * 8;
  const short* pr = (const short*)nf + (size_t)ri * HDIM + q * 8;
  const short* pb1 = (const short*)W1t + m * 384 + q * 8;

  f32x4 acc[8];
#pragma unroll
  for (int t = 0; t < 8; t++) acc[t] = (f32x4){0.f,0.f,0.f,0.f};
#pragma unroll
  for (int c = 0; c < 12; c++){
    const short* pa = (c < 4 ? pe : (c < 8 ? ps : pr)) + (c & 3) * 32;
    bf16x8 a = *(const bf16x8*)pa;
#pragma unroll
    for (int t = 0; t < 8; t++){
      bf16x8 b = *(const bf16x8*)(pb1 + t * 16 * 384 + c * 32);
      acc[t] = __builtin_amdgcn_mfma_f32_16x16x32_bf16(a, b, acc[t], 0, 0, 0);
    }
  }
  // bias + relu -> wave-private LDS tile (D layout -> row-major)
#pragma unroll
  for (int t = 0; t < 8; t++){
    float bb = b1[t * 16 + m];
#pragma unroll
    for (int r = 0; r < 4; r++)
      hsh[w][q*4 + r][t*16 + m] = f2bf(fmaxf(acc[t][r] + bb, 0.f));
  }
  // L2: h @ W2
  const short* ph  = &hsh[w][m][0] + q * 8;
  const short* pb2 = (const short*)W2t + m * 128 + q * 8;
  f32x4 acc2[8];
#pragma unroll
  for (int t = 0; t < 8; t++) acc2[t] = (f32x4){0.f,0.f,0.f,0.f};
#pragma unroll
  for (int c = 0; c < 4; c++){
    bf16x8 a = *(const bf16x8*)(ph + c * 32);
#pragma unroll
    for (int t = 0; t < 8; t++){
      bf16x8 b = *(const bf16x8*)(pb2 + t * 16 * 128 + c * 32);
      acc2[t] = __builtin_amdgcn_mfma_f32_16x16x32_bf16(a, b, acc2[t], 0, 0, 0);
    }
  }
  // epilogue: + b2 + residual, write ef, scatter to agg
  const int row_d = blockIdx.x * 64 + w * 16 + q * 4;
  int rr[4];
#pragma unroll
  for (int r = 0; r < 4; r++){
    int e = row_d + r;
    rr[r] = (e < E) ? rcv[e] : 0;
  }
#pragma unroll
  for (int t = 0; t < 8; t++){
    int col = t * 16 + m;
    float bb = b2[col];
#pragma unroll
    for (int r = 0; r < 4; r++){
      int e = row_d + r;
      if (e < E){
        float v = acc2[t][r] + bb + bf2f(ef[(size_t)e * HDIM + col]);
        ef[(size_t)e * HDIM + col] = __float2bfloat16(v);
        unsafeAtomicAdd(&agg[(size_t)rr[r] * HDIM + col], v);
      }
    }
  }
}

// ---------------------------------------------------------------------------
// Fused node block: nf += MLP([nf | agg]) ; K1=256 (agg is fp32), K2=128.
// ---------------------------------------------------------------------------
__launch_bounds__(256)
__global__ void node_block(const float* __restrict__ agg,
                           __hip_bfloat16* __restrict__ nf,
                           const __hip_bfloat16* __restrict__ W1t,  // [128][256]
                           const float* __restrict__ b1,
                           const __hip_bfloat16* __restrict__ W2t,  // [128][128]
                           const float* __restrict__ b2,
                           int N){
  __shared__ __align__(16) short hsh[4][16][136];
  const int tid = threadIdx.x, w = tid >> 6, l = tid & 63, m = l & 15, q = l >> 4;
  const int row_a = blockIdx.x * 64 + w * 16 + m;
  const int ra = min(row_a, N - 1);
  const short* pn = (const short*)nf + (size_t)ra * HDIM + q * 8;
  const float* pg = agg + (size_t)ra * HDIM + q * 8;
  const short* pb1 = (const short*)W1t + m * 256 + q * 8;

  f32x4 acc[8];
#pragma unroll
  for (int t = 0; t < 8; t++) acc[t] = (f32x4){0.f,0.f,0.f,0.f};
#pragma unroll
  for (int c = 0; c < 8; c++){
    bf16x8 a;
    if (c < 4){
      a = *(const bf16x8*)(pn + c * 32);
    } else {
      f32x4 u0 = *(const f32x4*)(pg + (c - 4) * 32);
      f32x4 u1 = *(const f32x4*)(pg + (c - 4) * 32 + 4);
#pragma unroll
      for (int i = 0; i < 4; i++){ a[i] = f2bf(u0[i]); a[4+i] = f2bf(u1[i]); }
    }
#pragma unroll
    for (int t = 0; t < 8; t++){
      bf16x8 b = *(const bf16x8*)(pb1 + t * 16 * 256 + c * 32);
      acc[t] = __builtin_amdgcn_mfma_f32_16x16x32_bf16(a, b, acc[t], 0, 0, 0);
    }
  }
#pragma unroll
  for (int t = 0; t < 8; t++){
    float bb = b1[t * 16 + m];
#pragma unroll
    for (int r = 0; r < 4; r++)
      hsh[w][q*4 + r][t*16 + m] = f2bf(fmaxf(acc[t][r] + bb, 0.f));
  }
  const short* ph  = &hsh[w][m][0] + q * 8;
  const short* pb2 = (const short*)W2t + m * 128 + q * 8;
  f32x4 acc2[8];
#pragma unroll
  for (int t = 0; t < 8; t++) acc2[t] = (f32x4){0.f,0.f,0.f,0.f};
#pragma unroll
  for (int c = 0; c < 4; c++){
    bf16x8 a = *(const bf16x8*)(ph + c * 32);
#pragma unroll
    for (int t = 0; t < 8; t++){
      bf16x8 b = *(const bf16x8*)(pb2 + t * 16 * 128 + c * 32);
      acc2[t] = __builtin_amdgcn_mfma_f32_16x16x32_bf16(a, b, acc2[t], 0, 0, 0);
    }
  }
  const int row_d = blockIdx.x * 64 + w * 16 + q * 4;
#pragma unroll
  for (int t = 0; t < 8; t++){
    int col = t * 16 + m;
    float bb = b2[col];
#pragma unroll
    for (int r = 0; r < 4; r++){
      int e = row_d + r;
      if (e < N){
        float v = acc2[t][r] + bb + bf2f(nf[(size_t)e * HDIM + col]);
        nf[(size_t)e * HDIM + col] = __float2bfloat16(v);
      }
    }
  }
}

// ---------------------------------------------------------------------------
// Decoder final layer: [rows,128] fp32 @ [128,3] + b -> dec_out[rows,3]
// ---------------------------------------------------------------------------
__global__ void dec_final(const float* __restrict__ hbuf,
                          const float* __restrict__ W2,
                          const float* __restrict__ b2,
                          float* __restrict__ outd, int rows){
  __shared__ float hl[64 * 129];
  __shared__ float Wl[HDIM * 3];
  __shared__ float bl[3];
  int t = threadIdx.x;
  int node0 = blockIdx.x * 64;
  for (int i = t; i < HDIM * 3; i += 256) Wl[i] = W2[i];
  if (t < 3) bl[t] = b2[t];
#pragma unroll
  for (int i = 0; i < 32; i++){
    int lin = t + i * 256;
    int r = lin >> 7;
    int c = lin & 127;
    int node = node0 + r;
    hl[r * 129 + c] = (node < rows) ? hbuf[(size_t)node * HDIM + c] : 0.f;
  }
  __syncthreads();
  if (t < 64){
    int node = node0 + t;
    if (node < rows){
      float a0 = bl[0], a1 = bl[1], a2 = bl[2];
      for (int k = 0; k < HDIM; k++){
        float v = hl[t * 129 + k];
        a0 += v * Wl[k * 3];
        a1 += v * Wl[k * 3 + 1];
        a2 += v * Wl[k * 3 + 2];
      }
      outd[3 * node]     = a0;
      outd[3 * node + 1] = a1;
      outd[3 * node + 2] = a2;
    }
  }
}

__global__ void epilogue(const float* __restrict__ dec_out,
                         const float* __restrict__ zl,
                         const float* __restrict__ z_target,
                         const float* __restrict__ fin,
                         float* __restrict__ d_out,
                         float* __restrict__ stats_raw, int N){
  int n = blockIdx.x * blockDim.x + threadIdx.x;
  float lsum = 0.f, r0 = 0.f, r1 = 0.f, r2 = 0.f;
  if (n < N){
#pragma unroll
    for (int d = 0; d < 3; d++){
      float om = fin[12 + d], os = fin[15 + d];
      float o   = dec_out[3*n + d];
      float zld = zl[3*n + d];
      float zt  = z_target[3*n + d];
      float tgt = zt - zld;
      float tn  = (tgt - om) / os;
      float diff = tn - o;
      lsum += diff * diff;
      float zp = zld + o * os + om;
      d_out[3*n + d] = zp;
      float e = zp - zt;
      e = e * e;
      if (d == 0) r0 = e; else if (d == 1) r1 = e; else r2 = e;
    }
  }
  lsum = wave_sum(lsum); r0 = wave_sum(r0); r1 = wave_sum(r1); r2 = wave_sum(r2);
  if ((threadIdx.x & 63) == 0){
    atomicAdd(&stats_raw[18], lsum);
    atomicAdd(&stats_raw[19], r0);
    atomicAdd(&stats_raw[20], r1);
    atomicAdd(&stats_raw[21], r2);
  }
}

__global__ void finalize_out(const float* __restrict__ raw,
                             float* __restrict__ d_out, int N){
  float cN = (float)N;
  float loss = raw[18] / (3.f * cN);
  float rmse = (sqrtf(raw[19] / cN) + sqrtf(raw[20] / cN) + sqrtf(raw[21] / cN)) / 3.f;
  d_out[(size_t)3 * N]     = loss;
  d_out[(size_t)3 * N + 1] = rmse;
}

// ---------------------------------------------------------------------------
extern "C" void kernel_launch(void* const* d_in, const int* in_sizes, int n_in,
                              void* d_out, int out_size, void* d_ws, size_t ws_size,
                              hipStream_t stream){
  const float* z           = (const float*)d_in[0];
  const float* z_target    = (const float*)d_in[1];
  const float* pos         = (const float*)d_in[2];
  const float* enc_node_W1 = (const float*)d_in[3];
  const float* enc_node_b1 = (const float*)d_in[4];
  const float* enc_node_W2 = (const float*)d_in[5];
  const float* enc_node_b2 = (const float*)d_in[6];
  const float* enc_edge_W1 = (const float*)d_in[7];
  const float* enc_edge_b1 = (const float*)d_in[8];
  const float* enc_edge_W2 = (const float*)d_in[9];
  const float* enc_edge_b2 = (const float*)d_in[10];
  const float* dec_W1      = (const float*)d_in[11];
  const float* dec_b1      = (const float*)d_in[12];
  const float* dec_W2      = (const float*)d_in[13];
  const float* dec_b2      = (const float*)d_in[14];
  const float* blk_edge_W1 = (const float*)d_in[15];
  const float* blk_edge_b1 = (const float*)d_in[16];
  const float* blk_edge_W2 = (const float*)d_in[17];
  const float* blk_edge_b2 = (const float*)d_in[18];
  const float* blk_node_W1 = (const float*)d_in[19];
  const float* blk_node_b1 = (const float*)d_in[20];
  const float* blk_node_W2 = (const float*)d_in[21];
  const float* blk_node_b2 = (const float*)d_in[22];
  const int*   senders     = (const int*)d_in[23];
  const int*   receivers   = (const int*)d_in[24];

  const int N = in_sizes[1] / 3;
  const int E = in_sizes[23];
  const float* zl = z + (size_t)N * 3;

  // workspace carve (bytes, 256-aligned)
  char* p = (char*)d_ws;
  auto carve = [&](size_t bytes) -> char* {
    char* r = p; p += (bytes + 255) & ~(size_t)255; return r;
  };
  float* stats_raw = (float*)carve(64 * 4);
  float* stats_fin = (float*)carve(32 * 4);
  float* ef_raw    = (float*)carve((size_t)E * 3 * 4);
  float* dec_out   = (float*)carve((size_t)N * 3 * 4);
  float* hbuf      = (float*)carve((size_t)N * HDIM * 4);
  float* agg       = (float*)carve((size_t)N * HDIM * 4);
  __hip_bfloat16* wp   = (__hip_bfloat16*)carve((size_t)507904 * 2);
  __hip_bfloat16* ef   = (__hip_bfloat16*)carve((size_t)E * HDIM * 2);
  __hip_bfloat16* nf   = (__hip_bfloat16*)carve((size_t)N * HDIM * 2);
  __hip_bfloat16* htmp = (__hip_bfloat16*)carve((size_t)E * HDIM * 2);

  float* out = (float*)d_out;

  hipMemsetAsync(stats_raw, 0, 64 * sizeof(float), stream);

  edge_raw_stats<<<ceil_div(E, TPB), TPB, 0, stream>>>(pos, senders, receivers, ef_raw, stats_raw, E);
  node_stats<<<ceil_div(N, TPB), TPB, 0, stream>>>(zl, z_target, stats_raw, N);
  finalize_stats<<<1, 1, 0, stream>>>(stats_raw, stats_fin, E, N);

  pack_weights<<<dim3(192, 19), TPB, 0, stream>>>(enc_edge_W2, enc_node_W2, dec_W1,
                                                  blk_edge_W1, blk_edge_W2,
                                                  blk_node_W1, blk_node_W2, wp);

  // encoders
  enc_hidden<<<ceil_div(E * HDIM, TPB), TPB, 0, stream>>>(ef_raw, stats_fin + 0, stats_fin + 3,
                                                          enc_edge_W1, enc_edge_b1, htmp, E);
  mfma_gemm128<<<ceil_div(E, 64), TPB, 0, stream>>>(htmp, wp, enc_edge_b2, ef, nullptr, E, 0);
  enc_hidden<<<ceil_div(N * HDIM, TPB), TPB, 0, stream>>>(zl, stats_fin + 6, stats_fin + 9,
                                                          enc_node_W1, enc_node_b1, htmp, N);
  mfma_gemm128<<<ceil_div(N, 64), TPB, 0, stream>>>(htmp, wp + 16384, enc_node_b2, nf, nullptr, N, 0);

  // message-passing blocks
  for (int b = 0; b < 4; b++){
    const __hip_bfloat16* eW1t = wp + 49152 + (size_t)b * 114688;
    const __hip_bfloat16* eW2t = eW1t + 49152;
    const __hip_bfloat16* nW1t = eW1t + 65536;
    const __hip_bfloat16* nW2t = eW1t + 98304;
    const float* eb1 = blk_edge_b1 + (size_t)b * 128;
    const float* eb2 = blk_edge_b2 + (size_t)b * 128;
    const float* nb1 = blk_node_b1 + (size_t)b * 128;
    const float* nb2 = blk_node_b2 + (size_t)b * 128;

    hipMemsetAsync(agg, 0, (size_t)N * HDIM * sizeof(float), stream);
    edge_block<<<ceil_div(E, 64), TPB, 0, stream>>>(senders, receivers, nf, ef,
                                                    eW1t, eb1, eW2t, eb2, agg, E);
    node_block<<<ceil_div(N, 64), TPB, 0, stream>>>(agg, nf, nW1t, nb1, nW2t, nb2, N);
  }

  // decoder
  mfma_gemm128<<<ceil_div(N, 64), TPB, 0, stream>>>(nf, wp + 32768, dec_b1, nullptr, hbuf, N, 1);
  dec_final<<<ceil_div(N, 64), TPB, 0, stream>>>(hbuf, dec_W2, dec_b2, dec_out, N);

  // loss / rmse / z_pred
  epilogue<<<ceil_div(N, TPB), TPB, 0, stream>>>(dec_out, zl, z_target, stats_fin,
                                                 out, stats_raw, N);
  finalize_out<<<1, 1, 0, stream>>>(stats_raw, out, N);
}

// Round 3
// 1586.757 us; speedup vs baseline: 2.3934x; 1.0095x over previous
//
#include <hip/hip_runtime.h>
#include <hip/hip_bf16.h>
#include <math.h>

#define HDIM 128
#define TPB 256

typedef __attribute__((ext_vector_type(8))) short bf16x8;
typedef __attribute__((ext_vector_type(4))) float f32x4;

static inline int ceil_div(int a, int b){ return (a + b - 1) / b; }

__device__ __forceinline__ float wave_sum(float v){
#pragma unroll
  for (int o = 32; o > 0; o >>= 1) v += __shfl_down(v, o, 64);
  return v;
}

__device__ __forceinline__ short f2bf(float f){
  __hip_bfloat16 h = __float2bfloat16(f);
  return *reinterpret_cast<short*>(&h);
}
__device__ __forceinline__ float bf2f(__hip_bfloat16 h){ return __bfloat162float(h); }

// ---------------------------------------------------------------------------
// stats_raw layout (floats): e_sum[0..2] e_sq[3..5] n_sum[6..8] n_sq[9..11]
//                            t_sum[12..14] t_sq[15..17] loss[18] rmse[19..21]
// ---------------------------------------------------------------------------
__global__ void edge_raw_stats(const float* __restrict__ pos,
                               const int* __restrict__ snd,
                               const int* __restrict__ rcv,
                               float* __restrict__ ef_raw,
                               float* __restrict__ stats_raw, int E){
  int e = blockIdx.x * blockDim.x + threadIdx.x;
  float v0=0.f,v1=0.f,v2=0.f,q0=0.f,q1=0.f,q2=0.f;
  if (e < E){
    int s = snd[e], r = rcv[e];
    float rx = pos[2*s]   - pos[2*r];
    float ry = pos[2*s+1] - pos[2*r+1];
    float nm = sqrtf(rx*rx + ry*ry);
    ef_raw[3*e]   = rx;
    ef_raw[3*e+1] = ry;
    ef_raw[3*e+2] = nm;
    v0 = rx; v1 = ry; v2 = nm;
    q0 = rx*rx; q1 = ry*ry; q2 = nm*nm;
  }
  v0 = wave_sum(v0); v1 = wave_sum(v1); v2 = wave_sum(v2);
  q0 = wave_sum(q0); q1 = wave_sum(q1); q2 = wave_sum(q2);
  if ((threadIdx.x & 63) == 0){
    atomicAdd(&stats_raw[0], v0); atomicAdd(&stats_raw[1], v1); atomicAdd(&stats_raw[2], v2);
    atomicAdd(&stats_raw[3], q0); atomicAdd(&stats_raw[4], q1); atomicAdd(&stats_raw[5], q2);
  }
}

__global__ void node_stats(const float* __restrict__ zl,
                           const float* __restrict__ z_target,
                           float* __restrict__ stats_raw, int N){
  int n = blockIdx.x * blockDim.x + threadIdx.x;
  float s[12];
#pragma unroll
  for (int i = 0; i < 12; i++) s[i] = 0.f;
  if (n < N){
#pragma unroll
    for (int d = 0; d < 3; d++){
      float z = zl[3*n+d];
      float t = z_target[3*n+d] - z;
      s[d]   = z;  s[3+d] = z*z;
      s[6+d] = t;  s[9+d] = t*t;
    }
  }
#pragma unroll
  for (int i = 0; i < 12; i++) s[i] = wave_sum(s[i]);
  if ((threadIdx.x & 63) == 0){
#pragma unroll
    for (int i = 0; i < 12; i++) atomicAdd(&stats_raw[6+i], s[i]);
  }
}

// stats_fin: em[0..2] es[3..5] nm[6..8] ns[9..11] om[12..14] os[15..17]
__global__ void finalize_stats(const float* __restrict__ raw,
                               float* __restrict__ fin, int E, int N){
#pragma unroll
  for (int d = 0; d < 3; d++){
    float cE = (float)E, cN = (float)N;
    float m, v;
    m = raw[0+d] / cE; v = fmaxf(raw[3+d]/cE - m*m, 0.f);
    fin[0+d] = m;  fin[3+d]  = fmaxf(sqrtf(v), 1e-8f);
    m = raw[6+d] / cN; v = fmaxf(raw[9+d]/cN - m*m, 0.f);
    fin[6+d] = m;  fin[9+d]  = fmaxf(sqrtf(v), 1e-8f);
    m = raw[12+d] / cN; v = fmaxf(raw[15+d]/cN - m*m, 0.f);
    fin[12+d] = m; fin[15+d] = fmaxf(sqrtf(v), 1e-8f);
  }
}

// ---------------------------------------------------------------------------
// Weight packing: fp32 row-major [K][128] -> bf16 FRAGMENT-MAJOR:
//   dst[((c*8 + t)*64 + lane)*8 + j] = src[k][n],
//   k = c*32 + (lane>>4)*8 + j, n = t*16 + (lane&15)
// so each MFMA B-fragment (chunk c, col-tile t) is one contiguous 1KB block in
// lane order: LDS staging is a flat copy and ds_read_b128 is conflict-free.
// wp layout (bf16 elems):
//  0      : enc_edge_W2 (16384)   16384: enc_node_W2   32768: dec_W1
//  49152 + b*114688 : eW1_b(49152) | +49152 eW2_b(16384) | +65536 nW1_b(32768) | +98304 nW2_b(16384)
// ---------------------------------------------------------------------------
__global__ void pack_weights(const float* __restrict__ encEW2,
                             const float* __restrict__ encNW2,
                             const float* __restrict__ decW1,
                             const float* __restrict__ beW1,
                             const float* __restrict__ beW2,
                             const float* __restrict__ bnW1,
                             const float* __restrict__ bnW2,
                             __hip_bfloat16* __restrict__ wp){
  int y = blockIdx.y;
  const float* src; __hip_bfloat16* dst; int K;
  if (y == 0){ src = encEW2; dst = wp;          K = 128; }
  else if (y == 1){ src = encNW2; dst = wp + 16384; K = 128; }
  else if (y == 2){ src = decW1;  dst = wp + 32768; K = 128; }
  else {
    int b = (y - 3) >> 2, j = (y - 3) & 3;
    __hip_bfloat16* base = wp + 49152 + b * 114688;
    if (j == 0){ src = beW1 + b*49152; dst = base;          K = 384; }
    else if (j == 1){ src = beW2 + b*16384; dst = base + 49152; K = 128; }
    else if (j == 2){ src = bnW1 + b*32768; dst = base + 65536; K = 256; }
    else { src = bnW2 + b*16384; dst = base + 98304; K = 128; }
  }
  int id = blockIdx.x * blockDim.x + threadIdx.x;
  if (id >= 128 * K) return;
  int c = id >> 12;
  int r = id & 4095;
  int t = r >> 9;
  int l = (r >> 3) & 63;
  int j = r & 7;
  int k = c * 32 + ((l >> 4) << 3) + j;
  int n = t * 16 + (l & 15);
  dst[id] = __float2bfloat16(src[k * 128 + n]);
}

// ---------------------------------------------------------------------------
// Fused encoder: out[rows,128] = (relu(norm(raw3) @ W1 + b1)) @ W2 + b2
// W2 staged in LDS (frag-major, 16384 elems). 128 rows/block, 2 tiles/wave.
// Each lane computes exactly the 32 h-values it feeds as A-fragments.
// ---------------------------------------------------------------------------
__launch_bounds__(256)
__global__ void encoder_fused(const float* __restrict__ raw,
                              const float* __restrict__ mptr,
                              const float* __restrict__ sptr,
                              const float* __restrict__ W1,   // [3][128] f32
                              const float* __restrict__ b1,
                              const __hip_bfloat16* __restrict__ W2f, // frag-major
                              const float* __restrict__ b2,
                              __hip_bfloat16* __restrict__ out, int rows){
  __shared__ __align__(16) short wlds[16384];
  const int tid = threadIdx.x, w = tid >> 6, l = tid & 63, m = l & 15, q = l >> 4;
  for (int i = tid; i < 2048; i += 256)
    *(bf16x8*)&wlds[i*8] = *(const bf16x8*)((const short*)W2f + i*8);
  __syncthreads();

  float s0 = mptr[0], s1 = mptr[1], s2 = mptr[2];
  float d0 = sptr[0], d1 = sptr[1], d2 = sptr[2];

#pragma unroll
  for (int tile = 0; tile < 2; tile++){
    const int row0 = blockIdx.x * 128 + w * 32 + tile * 16;
    const int ra = min(row0 + m, rows - 1);
    float x0 = (raw[3*ra]   - s0) / d0;
    float x1 = (raw[3*ra+1] - s1) / d1;
    float x2 = (raw[3*ra+2] - s2) / d2;
    // compute the 32 h-values this lane feeds (cols c*32 + q*8 .. +8)
    bf16x8 afr[4];
#pragma unroll
    for (int c = 0; c < 4; c++){
      int nb = c * 32 + q * 8;
#pragma unroll
      for (int j = 0; j < 8; j++){
        float h = b1[nb+j] + x0 * W1[nb+j] + x1 * W1[128+nb+j] + x2 * W1[256+nb+j];
        afr[c][j] = f2bf(fmaxf(h, 0.f));
      }
    }
    f32x4 acc[8];
#pragma unroll
    for (int t = 0; t < 8; t++) acc[t] = (f32x4){0.f,0.f,0.f,0.f};
#pragma unroll
    for (int c = 0; c < 4; c++){
#pragma unroll
      for (int t = 0; t < 8; t++){
        bf16x8 b = *(const bf16x8*)&wlds[((c*8 + t)*64 + l)*8];
        acc[t] = __builtin_amdgcn_mfma_f32_16x16x32_bf16(afr[c], b, acc[t], 0, 0, 0);
      }
    }
    const int row_d = blockIdx.x * 128 + w * 32 + tile * 16 + q * 4;
#pragma unroll
    for (int t = 0; t < 8; t++){
      int col = t * 16 + m;
      float bb = b2[col];
#pragma unroll
      for (int r = 0; r < 4; r++){
        int e = row_d + r;
        if (e < rows) out[(size_t)e * HDIM + col] = __float2bfloat16(acc[t][r] + bb);
      }
    }
  }
}

// ---------------------------------------------------------------------------
// Single-layer LDS-staged GEMM (decoder W1): out_f32 = relu(A_bf16 @ W + b)
// ---------------------------------------------------------------------------
__launch_bounds__(256)
__global__ void gemm128_lds(const __hip_bfloat16* __restrict__ A,
                            const __hip_bfloat16* __restrict__ Wf,
                            const float* __restrict__ bias,
                            float* __restrict__ out, int rows){
  __shared__ __align__(16) short wlds[16384];
  const int tid = threadIdx.x, w = tid >> 6, l = tid & 63, m = l & 15, q = l >> 4;
  for (int i = tid; i < 2048; i += 256)
    *(bf16x8*)&wlds[i*8] = *(const bf16x8*)((const short*)Wf + i*8);
  __syncthreads();
#pragma unroll
  for (int tile = 0; tile < 2; tile++){
    const int row0 = blockIdx.x * 128 + w * 32 + tile * 16;
    const int ra = min(row0 + m, rows - 1);
    const short* pa = (const short*)A + (size_t)ra * HDIM + q * 8;
    f32x4 acc[8];
#pragma unroll
    for (int t = 0; t < 8; t++) acc[t] = (f32x4){0.f,0.f,0.f,0.f};
#pragma unroll
    for (int c = 0; c < 4; c++){
      bf16x8 a = *(const bf16x8*)(pa + c * 32);
#pragma unroll
      for (int t = 0; t < 8; t++){
        bf16x8 b = *(const bf16x8*)&wlds[((c*8 + t)*64 + l)*8];
        acc[t] = __builtin_amdgcn_mfma_f32_16x16x32_bf16(a, b, acc[t], 0, 0, 0);
      }
    }
    const int row_d = row0 + q * 4;
#pragma unroll
    for (int t = 0; t < 8; t++){
      int col = t * 16 + m;
      float bb = bias[col];
#pragma unroll
      for (int r = 0; r < 4; r++){
        int e = row_d + r;
        if (e < rows) out[(size_t)e * HDIM + col] = fmaxf(acc[t][r] + bb, 0.f);
      }
    }
  }
}

// ---------------------------------------------------------------------------
// Fused edge block v3: ef += MLP([ef | nf[snd] | nf[rcv]]); agg[rcv] += ef_new
// 256 rows/block; W1(96KB)+W2(32KB) staged in LDS frag-major, shared by all
// 4 waves; each wave owns 4 tiles of 16 rows, no barriers after staging.
// ---------------------------------------------------------------------------
__launch_bounds__(256)
__global__ void edge_block(const int* __restrict__ snd,
                           const int* __restrict__ rcv,
                           const __hip_bfloat16* __restrict__ nf,
                           __hip_bfloat16* __restrict__ ef,
                           const __hip_bfloat16* __restrict__ Wfrag, // W1|W2 frag-major, 65536 elems
                           const float* __restrict__ b1,
                           const float* __restrict__ b2,
                           float* __restrict__ agg,
                           int E){
  __shared__ __align__(16) short wlds[65536];          // 128 KB
  __shared__ __align__(16) short hsh[4][16][136];      // 17 KB
  const int tid = threadIdx.x, w = tid >> 6, l = tid & 63, m = l & 15, q = l >> 4;
  for (int i = tid; i < 8192; i += 256)
    *(bf16x8*)&wlds[i*8] = *(const bf16x8*)((const short*)Wfrag + i*8);
  __syncthreads();

#pragma unroll 1
  for (int tile = 0; tile < 4; tile++){
    const int row0 = blockIdx.x * 256 + w * 64 + tile * 16;
    const int ra = min(row0 + m, E - 1);
    const int si = snd[ra], ri = rcv[ra];
    const short* pe = (const short*)ef + (size_t)ra * HDIM + q * 8;
    const short* ps = (const short*)nf + (size_t)si * HDIM + q * 8;
    const short* pr = (const short*)nf + (size_t)ri * HDIM + q * 8;
    bf16x8 afr[12];
#pragma unroll
    for (int c = 0; c < 4; c++){
      afr[c]   = *(const bf16x8*)(pe + c * 32);
      afr[4+c] = *(const bf16x8*)(ps + c * 32);
      afr[8+c] = *(const bf16x8*)(pr + c * 32);
    }
    f32x4 acc[8];
#pragma unroll
    for (int t = 0; t < 8; t++) acc[t] = (f32x4){0.f,0.f,0.f,0.f};
#pragma unroll
    for (int c = 0; c < 12; c++){
#pragma unroll
      for (int t = 0; t < 8; t++){
        bf16x8 b = *(const bf16x8*)&wlds[((c*8 + t)*64 + l)*8];
        acc[t] = __builtin_amdgcn_mfma_f32_16x16x32_bf16(afr[c], b, acc[t], 0, 0, 0);
      }
    }
#pragma unroll
    for (int t = 0; t < 8; t++){
      float bb = b1[t * 16 + m];
#pragma unroll
      for (int r = 0; r < 4; r++)
        hsh[w][q*4 + r][t*16 + m] = f2bf(fmaxf(acc[t][r] + bb, 0.f));
    }
    const short* ph = &hsh[w][m][0] + q * 8;
    f32x4 acc2[8];
#pragma unroll
    for (int t = 0; t < 8; t++) acc2[t] = (f32x4){0.f,0.f,0.f,0.f};
#pragma unroll
    for (int c = 0; c < 4; c++){
      bf16x8 a = *(const bf16x8*)(ph + c * 32);
#pragma unroll
      for (int t = 0; t < 8; t++){
        bf16x8 b = *(const bf16x8*)&wlds[49152 + ((c*8 + t)*64 + l)*8];
        acc2[t] = __builtin_amdgcn_mfma_f32_16x16x32_bf16(a, b, acc2[t], 0, 0, 0);
      }
    }
    const int row_d = row0 + q * 4;
    int rr[4];
#pragma unroll
    for (int r = 0; r < 4; r++){
      int e = row_d + r;
      rr[r] = (e < E) ? rcv[e] : 0;
    }
#pragma unroll
    for (int t = 0; t < 8; t++){
      int col = t * 16 + m;
      float bb = b2[col];
#pragma unroll
      for (int r = 0; r < 4; r++){
        int e = row_d + r;
        if (e < E){
          float v = acc2[t][r] + bb + bf2f(ef[(size_t)e * HDIM + col]);
          ef[(size_t)e * HDIM + col] = __float2bfloat16(v);
          unsafeAtomicAdd(&agg[(size_t)rr[r] * HDIM + col], v);
        }
      }
    }
  }
}

// ---------------------------------------------------------------------------
// Fused node block v3: nf += MLP([nf | agg]); 128 rows/block, weights in LDS.
// ---------------------------------------------------------------------------
__launch_bounds__(256)
__global__ void node_block(const float* __restrict__ agg,
                           __hip_bfloat16* __restrict__ nf,
                           const __hip_bfloat16* __restrict__ Wfrag, // nW1|nW2 frag-major, 49152 elems
                           const float* __restrict__ b1,
                           const float* __restrict__ b2,
                           int N){
  __shared__ __align__(16) short wlds[49152];          // 96 KB
  __shared__ __align__(16) short hsh[4][16][136];
  const int tid = threadIdx.x, w = tid >> 6, l = tid & 63, m = l & 15, q = l >> 4;
  for (int i = tid; i < 6144; i += 256)
    *(bf16x8*)&wlds[i*8] = *(const bf16x8*)((const short*)Wfrag + i*8);
  __syncthreads();

#pragma unroll 1
  for (int tile = 0; tile < 2; tile++){
    const int row0 = blockIdx.x * 128 + w * 32 + tile * 16;
    const int ra = min(row0 + m, N - 1);
    const short* pn = (const short*)nf + (size_t)ra * HDIM + q * 8;
    const float* pg = agg + (size_t)ra * HDIM + q * 8;
    bf16x8 afr[8];
#pragma unroll
    for (int c = 0; c < 4; c++) afr[c] = *(const bf16x8*)(pn + c * 32);
#pragma unroll
    for (int c = 0; c < 4; c++){
      f32x4 u0 = *(const f32x4*)(pg + c * 32);
      f32x4 u1 = *(const f32x4*)(pg + c * 32 + 4);
#pragma unroll
      for (int i = 0; i < 4; i++){ afr[4+c][i] = f2bf(u0[i]); afr[4+c][4+i] = f2bf(u1[i]); }
    }
    f32x4 acc[8];
#pragma unroll
    for (int t = 0; t < 8; t++) acc[t] = (f32x4){0.f,0.f,0.f,0.f};
#pragma unroll
    for (int c = 0; c < 8; c++){
#pragma unroll
      for (int t = 0; t < 8; t++){
        bf16x8 b = *(const bf16x8*)&wlds[((c*8 + t)*64 + l)*8];
        acc[t] = __builtin_amdgcn_mfma_f32_16x16x32_bf16(afr[c], b, acc[t], 0, 0, 0);
      }
    }
#pragma unroll
    for (int t = 0; t < 8; t++){
      float bb = b1[t * 16 + m];
#pragma unroll
      for (int r = 0; r < 4; r++)
        hsh[w][q*4 + r][t*16 + m] = f2bf(fmaxf(acc[t][r] + bb, 0.f));
    }
    const short* ph = &hsh[w][m][0] + q * 8;
    f32x4 acc2[8];
#pragma unroll
    for (int t = 0; t < 8; t++) acc2[t] = (f32x4){0.f,0.f,0.f,0.f};
#pragma unroll
    for (int c = 0; c < 4; c++){
      bf16x8 a = *(const bf16x8*)(ph + c * 32);
#pragma unroll
      for (int t = 0; t < 8; t++){
        bf16x8 b = *(const bf16x8*)&wlds[32768 + ((c*8 + t)*64 + l)*8];
        acc2[t] = __builtin_amdgcn_mfma_f32_16x16x32_bf16(a, b, acc2[t], 0, 0, 0);
      }
    }
    const int row_d = row0 + q * 4;
#pragma unroll
    for (int t = 0; t < 8; t++){
      int col = t * 16 + m;
      float bb = b2[col];
#pragma unroll
      for (int r = 0; r < 4; r++){
        int e = row_d + r;
        if (e < N){
          float v = acc2[t][r] + bb + bf2f(nf[(size_t)e * HDIM + col]);
          nf[(size_t)e * HDIM + col] = __float2bfloat16(v);
        }
      }
    }
  }
}

// ---------------------------------------------------------------------------
// Decoder final layer: [rows,128] fp32 @ [128,3] + b -> dec_out[rows,3]
// ---------------------------------------------------------------------------
__global__ void dec_final(const float* __restrict__ hbuf,
                          const float* __restrict__ W2,
                          const float* __restrict__ b2,
                          float* __restrict__ outd, int rows){
  __shared__ float hl[64 * 129];
  __shared__ float Wl[HDIM * 3];
  __shared__ float bl[3];
  int t = threadIdx.x;
  int node0 = blockIdx.x * 64;
  for (int i = t; i < HDIM * 3; i += 256) Wl[i] = W2[i];
  if (t < 3) bl[t] = b2[t];
#pragma unroll
  for (int i = 0; i < 32; i++){
    int lin = t + i * 256;
    int r = lin >> 7;
    int c = lin & 127;
    int node = node0 + r;
    hl[r * 129 + c] = (node < rows) ? hbuf[(size_t)node * HDIM + c] : 0.f;
  }
  __syncthreads();
  if (t < 64){
    int node = node0 + t;
    if (node < rows){
      float a0 = bl[0], a1 = bl[1], a2 = bl[2];
      for (int k = 0; k < HDIM; k++){
        float v = hl[t * 129 + k];
        a0 += v * Wl[k * 3];
        a1 += v * Wl[k * 3 + 1];
        a2 += v * Wl[k * 3 + 2];
      }
      outd[3 * node]     = a0;
      outd[3 * node + 1] = a1;
      outd[3 * node + 2] = a2;
    }
  }
}

__global__ void epilogue(const float* __restrict__ dec_out,
                         const float* __restrict__ zl,
                         const float* __restrict__ z_target,
                         const float* __restrict__ fin,
                         float* __restrict__ d_out,
                         float* __restrict__ stats_raw, int N){
  int n = blockIdx.x * blockDim.x + threadIdx.x;
  float lsum = 0.f, r0 = 0.f, r1 = 0.f, r2 = 0.f;
  if (n < N){
#pragma unroll
    for (int d = 0; d < 3; d++){
      float om = fin[12 + d], os = fin[15 + d];
      float o   = dec_out[3*n + d];
      float zld = zl[3*n + d];
      float zt  = z_target[3*n + d];
      float tgt = zt - zld;
      float tn  = (tgt - om) / os;
      float diff = tn - o;
      lsum += diff * diff;
      float zp = zld + o * os + om;
      d_out[3*n + d] = zp;
      float e = zp - zt;
      e = e * e;
      if (d == 0) r0 = e; else if (d == 1) r1 = e; else r2 = e;
    }
  }
  lsum = wave_sum(lsum); r0 = wave_sum(r0); r1 = wave_sum(r1); r2 = wave_sum(r2);
  if ((threadIdx.x & 63) == 0){
    atomicAdd(&stats_raw[18], lsum);
    atomicAdd(&stats_raw[19], r0);
    atomicAdd(&stats_raw[20], r1);
    atomicAdd(&stats_raw[21], r2);
  }
}

__global__ void finalize_out(const float* __restrict__ raw,
                             float* __restrict__ d_out, int N){
  float cN = (float)N;
  float loss = raw[18] / (3.f * cN);
  float rmse = (sqrtf(raw[19] / cN) + sqrtf(raw[20] / cN) + sqrtf(raw[21] / cN)) / 3.f;
  d_out[(size_t)3 * N]     = loss;
  d_out[(size_t)3 * N + 1] = rmse;
}

// ---------------------------------------------------------------------------
extern "C" void kernel_launch(void* const* d_in, const int* in_sizes, int n_in,
                              void* d_out, int out_size, void* d_ws, size_t ws_size,
                              hipStream_t stream){
  const float* z           = (const float*)d_in[0];
  const float* z_target    = (const float*)d_in[1];
  const float* pos         = (const float*)d_in[2];
  const float* enc_node_W1 = (const float*)d_in[3];
  const float* enc_node_b1 = (const float*)d_in[4];
  const float* enc_node_W2 = (const float*)d_in[5];
  const float* enc_node_b2 = (const float*)d_in[6];
  const float* enc_edge_W1 = (const float*)d_in[7];
  const float* enc_edge_b1 = (const float*)d_in[8];
  const float* enc_edge_W2 = (const float*)d_in[9];
  const float* enc_edge_b2 = (const float*)d_in[10];
  const float* dec_W1      = (const float*)d_in[11];
  const float* dec_b1      = (const float*)d_in[12];
  const float* dec_W2      = (const float*)d_in[13];
  const float* dec_b2      = (const float*)d_in[14];
  const float* blk_edge_W1 = (const float*)d_in[15];
  const float* blk_edge_b1 = (const float*)d_in[16];
  const float* blk_edge_W2 = (const float*)d_in[17];
  const float* blk_edge_b2 = (const float*)d_in[18];
  const float* blk_node_W1 = (const float*)d_in[19];
  const float* blk_node_b1 = (const float*)d_in[20];
  const float* blk_node_W2 = (const float*)d_in[21];
  const float* blk_node_b2 = (const float*)d_in[22];
  const int*   senders     = (const int*)d_in[23];
  const int*   receivers   = (const int*)d_in[24];

  const int N = in_sizes[1] / 3;
  const int E = in_sizes[23];
  const float* zl = z + (size_t)N * 3;

  char* p = (char*)d_ws;
  auto carve = [&](size_t bytes) -> char* {
    char* r = p; p += (bytes + 255) & ~(size_t)255; return r;
  };
  float* stats_raw = (float*)carve(64 * 4);
  float* stats_fin = (float*)carve(32 * 4);
  float* ef_raw    = (float*)carve((size_t)E * 3 * 4);
  float* dec_out   = (float*)carve((size_t)N * 3 * 4);
  float* hbuf      = (float*)carve((size_t)N * HDIM * 4);
  float* agg       = (float*)carve((size_t)N * HDIM * 4);
  __hip_bfloat16* wp = (__hip_bfloat16*)carve((size_t)507904 * 2);
  __hip_bfloat16* ef = (__hip_bfloat16*)carve((size_t)E * HDIM * 2);
  __hip_bfloat16* nf = (__hip_bfloat16*)carve((size_t)N * HDIM * 2);

  float* out = (float*)d_out;

  hipMemsetAsync(stats_raw, 0, 64 * sizeof(float), stream);

  edge_raw_stats<<<ceil_div(E, TPB), TPB, 0, stream>>>(pos, senders, receivers, ef_raw, stats_raw, E);
  node_stats<<<ceil_div(N, TPB), TPB, 0, stream>>>(zl, z_target, stats_raw, N);
  finalize_stats<<<1, 1, 0, stream>>>(stats_raw, stats_fin, E, N);

  pack_weights<<<dim3(192, 19), TPB, 0, stream>>>(enc_edge_W2, enc_node_W2, dec_W1,
                                                  blk_edge_W1, blk_edge_W2,
                                                  blk_node_W1, blk_node_W2, wp);

  // encoders (hidden layer fused)
  encoder_fused<<<ceil_div(E, 128), TPB, 0, stream>>>(ef_raw, stats_fin + 0, stats_fin + 3,
                                                      enc_edge_W1, enc_edge_b1,
                                                      wp, enc_edge_b2, ef, E);
  encoder_fused<<<ceil_div(N, 128), TPB, 0, stream>>>(zl, stats_fin + 6, stats_fin + 9,
                                                      enc_node_W1, enc_node_b1,
                                                      wp + 16384, enc_node_b2, nf, N);

  // message-passing blocks
  for (int b = 0; b < 4; b++){
    const __hip_bfloat16* eWf = wp + 49152 + (size_t)b * 114688;          // eW1|eW2
    const __hip_bfloat16* nWf = eWf + 65536;                              // nW1|nW2
    const float* eb1 = blk_edge_b1 + (size_t)b * 128;
    const float* eb2 = blk_edge_b2 + (size_t)b * 128;
    const float* nb1 = blk_node_b1 + (size_t)b * 128;
    const float* nb2 = blk_node_b2 + (size_t)b * 128;

    hipMemsetAsync(agg, 0, (size_t)N * HDIM * sizeof(float), stream);
    edge_block<<<ceil_div(E, 256), TPB, 0, stream>>>(senders, receivers, nf, ef,
                                                     eWf, eb1, eb2, agg, E);
    node_block<<<ceil_div(N, 128), TPB, 0, stream>>>(agg, nf, nWf, nb1, nb2, N);
  }

  // decoder
  gemm128_lds<<<ceil_div(N, 128), TPB, 0, stream>>>(nf, wp + 32768, dec_b1, hbuf, N);
  dec_final<<<ceil_div(N, 64), TPB, 0, stream>>>(hbuf, dec_W2, dec_b2, dec_out, N);

  epilogue<<<ceil_div(N, TPB), TPB, 0, stream>>>(dec_out, zl, z_target, stats_fin,
                                                 out, stats_raw, N);
  finalize_out<<<1, 1, 0, stream>>>(stats_raw, out, N);
}

// Round 4
// 922.158 us; speedup vs baseline: 4.1183x; 1.7207x over previous
//
#include <hip/hip_runtime.h>
#include <hip/hip_bf16.h>
#include <math.h>

#define HDIM 128
#define TPB 256

typedef __attribute__((ext_vector_type(8))) short bf16x8;
typedef __attribute__((ext_vector_type(4))) float f32x4;

static inline int ceil_div(int a, int b){ return (a + b - 1) / b; }

__device__ __forceinline__ float wave_sum(float v){
#pragma unroll
  for (int o = 32; o > 0; o >>= 1) v += __shfl_down(v, o, 64);
  return v;
}

__device__ __forceinline__ short f2bf(float f){
  __hip_bfloat16 h = __float2bfloat16(f);
  return *reinterpret_cast<short*>(&h);
}
__device__ __forceinline__ float bfb2f(short s){
  unsigned int u = ((unsigned int)(unsigned short)s) << 16;
  return __builtin_bit_cast(float, u);
}

// ---------------------------------------------------------------------------
// stats_raw layout (floats): e_sum[0..2] e_sq[3..5] n_sum[6..8] n_sq[9..11]
//                            t_sum[12..14] t_sq[15..17] loss[18] rmse[19..21]
// ---------------------------------------------------------------------------
__global__ void edge_raw_stats(const float* __restrict__ pos,
                               const int* __restrict__ snd,
                               const int* __restrict__ rcv,
                               float* __restrict__ ef_raw,
                               float* __restrict__ stats_raw, int E){
  int e = blockIdx.x * blockDim.x + threadIdx.x;
  float v0=0.f,v1=0.f,v2=0.f,q0=0.f,q1=0.f,q2=0.f;
  if (e < E){
    int s = snd[e], r = rcv[e];
    float rx = pos[2*s]   - pos[2*r];
    float ry = pos[2*s+1] - pos[2*r+1];
    float nm = sqrtf(rx*rx + ry*ry);
    ef_raw[3*e]   = rx;
    ef_raw[3*e+1] = ry;
    ef_raw[3*e+2] = nm;
    v0 = rx; v1 = ry; v2 = nm;
    q0 = rx*rx; q1 = ry*ry; q2 = nm*nm;
  }
  v0 = wave_sum(v0); v1 = wave_sum(v1); v2 = wave_sum(v2);
  q0 = wave_sum(q0); q1 = wave_sum(q1); q2 = wave_sum(q2);
  if ((threadIdx.x & 63) == 0){
    atomicAdd(&stats_raw[0], v0); atomicAdd(&stats_raw[1], v1); atomicAdd(&stats_raw[2], v2);
    atomicAdd(&stats_raw[3], q0); atomicAdd(&stats_raw[4], q1); atomicAdd(&stats_raw[5], q2);
  }
}

__global__ void node_stats(const float* __restrict__ zl,
                           const float* __restrict__ z_target,
                           float* __restrict__ stats_raw, int N){
  int n = blockIdx.x * blockDim.x + threadIdx.x;
  float s[12];
#pragma unroll
  for (int i = 0; i < 12; i++) s[i] = 0.f;
  if (n < N){
#pragma unroll
    for (int d = 0; d < 3; d++){
      float z = zl[3*n+d];
      float t = z_target[3*n+d] - z;
      s[d]   = z;  s[3+d] = z*z;
      s[6+d] = t;  s[9+d] = t*t;
    }
  }
#pragma unroll
  for (int i = 0; i < 12; i++) s[i] = wave_sum(s[i]);
  if ((threadIdx.x & 63) == 0){
#pragma unroll
    for (int i = 0; i < 12; i++) atomicAdd(&stats_raw[6+i], s[i]);
  }
}

// stats_fin: em[0..2] es[3..5] nm[6..8] ns[9..11] om[12..14] os[15..17]
__global__ void finalize_stats(const float* __restrict__ raw,
                               float* __restrict__ fin, int E, int N){
#pragma unroll
  for (int d = 0; d < 3; d++){
    float cE = (float)E, cN = (float)N;
    float m, v;
    m = raw[0+d] / cE; v = fmaxf(raw[3+d]/cE - m*m, 0.f);
    fin[0+d] = m;  fin[3+d]  = fmaxf(sqrtf(v), 1e-8f);
    m = raw[6+d] / cN; v = fmaxf(raw[9+d]/cN - m*m, 0.f);
    fin[6+d] = m;  fin[9+d]  = fmaxf(sqrtf(v), 1e-8f);
    m = raw[12+d] / cN; v = fmaxf(raw[15+d]/cN - m*m, 0.f);
    fin[12+d] = m; fin[15+d] = fmaxf(sqrtf(v), 1e-8f);
  }
}

// ---------------------------------------------------------------------------
// CSR build for receivers (reused by all 4 blocks)
// ---------------------------------------------------------------------------
__global__ void csr_hist(const int* __restrict__ rcv, int* __restrict__ deg, int E){
  int e = blockIdx.x * blockDim.x + threadIdx.x;
  if (e < E) atomicAdd(&deg[rcv[e]], 1);
}

__global__ void csr_scan(const int* __restrict__ deg, int* __restrict__ row_start,
                         int N, int E){
  __shared__ int part[1024];
  int t = threadIdx.x;
  int chunk = (N + 1023) / 1024;
  int lo = t * chunk, hi = min(lo + chunk, N);
  int s = 0;
  for (int i = lo; i < hi; i++) s += deg[i];
  part[t] = s;
  __syncthreads();
  for (int off = 1; off < 1024; off <<= 1){
    int v = (t >= off) ? part[t - off] : 0;
    __syncthreads();
    part[t] += v;
    __syncthreads();
  }
  int base = (t == 0) ? 0 : part[t - 1];
  for (int i = lo; i < hi; i++){
    row_start[i] = base;
    base += deg[i];
  }
  if (t == 1023) row_start[N] = E;
}

__global__ void csr_scatter(const int* __restrict__ rcv, int* __restrict__ cursor,
                            int* __restrict__ eids, int E){
  int e = blockIdx.x * blockDim.x + threadIdx.x;
  if (e < E){
    int p = atomicAdd(&cursor[rcv[e]], 1);
    eids[p] = e;
  }
}

// ---------------------------------------------------------------------------
// Weight packing: fp32 row-major [K][128] -> bf16 FRAGMENT-MAJOR:
//   dst[((c*8 + t)*64 + lane)*8 + j] = src[k][n],
//   k = c*32 + (lane>>4)*8 + j, n = t*16 + (lane&15)
// Each MFMA B-fragment is one contiguous 1KB block in lane order -> each
// fragment load is a fully-coalesced 16B/lane global read (L2-resident).
// wp layout (bf16 elems):
//  0: enc_edge_W2 (16384)  16384: enc_node_W2  32768: dec_W1
//  49152 + b*114688 : eW1_b(49152) | +49152 eW2_b(16384) | +65536 nW1_b(32768) | +98304 nW2_b(16384)
// ---------------------------------------------------------------------------
__global__ void pack_weights(const float* __restrict__ encEW2,
                             const float* __restrict__ encNW2,
                             const float* __restrict__ decW1,
                             const float* __restrict__ beW1,
                             const float* __restrict__ beW2,
                             const float* __restrict__ bnW1,
                             const float* __restrict__ bnW2,
                             __hip_bfloat16* __restrict__ wp){
  int y = blockIdx.y;
  const float* src; __hip_bfloat16* dst; int K;
  if (y == 0){ src = encEW2; dst = wp;          K = 128; }
  else if (y == 1){ src = encNW2; dst = wp + 16384; K = 128; }
  else if (y == 2){ src = decW1;  dst = wp + 32768; K = 128; }
  else {
    int b = (y - 3) >> 2, j = (y - 3) & 3;
    __hip_bfloat16* base = wp + 49152 + b * 114688;
    if (j == 0){ src = beW1 + b*49152; dst = base;          K = 384; }
    else if (j == 1){ src = beW2 + b*16384; dst = base + 49152; K = 128; }
    else if (j == 2){ src = bnW1 + b*32768; dst = base + 65536; K = 256; }
    else { src = bnW2 + b*16384; dst = base + 98304; K = 128; }
  }
  int id = blockIdx.x * blockDim.x + threadIdx.x;
  if (id >= 128 * K) return;
  int c = id >> 12;
  int r = id & 4095;
  int t = r >> 9;
  int l = (r >> 3) & 63;
  int j = r & 7;
  int k = c * 32 + ((l >> 4) << 3) + j;
  int n = t * 16 + (l & 15);
  dst[id] = __float2bfloat16(src[k * 128 + n]);
}

// ---------------------------------------------------------------------------
// Fused encoder: out[rows,128] = (relu(norm(raw3) @ W1 + b1)) @ W2 + b2
// ---------------------------------------------------------------------------
__launch_bounds__(256)
__global__ void encoder_fused(const float* __restrict__ raw,
                              const float* __restrict__ mptr,
                              const float* __restrict__ sptr,
                              const float* __restrict__ W1,   // [3][128] f32
                              const float* __restrict__ b1,
                              const __hip_bfloat16* __restrict__ W2f, // frag-major
                              const float* __restrict__ b2,
                              __hip_bfloat16* __restrict__ out, int rows){
  const int tid = threadIdx.x, w = tid >> 6, l = tid & 63, m = l & 15, q = l >> 4;
  const short* wb = (const short*)W2f;

  float s0 = mptr[0], s1 = mptr[1], s2 = mptr[2];
  float d0 = sptr[0], d1 = sptr[1], d2 = sptr[2];

  const int row0 = blockIdx.x * 64 + w * 16;
  const int ra = min(row0 + m, rows - 1);
  float x0 = (raw[3*ra]   - s0) / d0;
  float x1 = (raw[3*ra+1] - s1) / d1;
  float x2 = (raw[3*ra+2] - s2) / d2;
  bf16x8 afr[4];
#pragma unroll
  for (int c = 0; c < 4; c++){
    int nb = c * 32 + q * 8;
#pragma unroll
    for (int j = 0; j < 8; j++){
      float h = b1[nb+j] + x0 * W1[nb+j] + x1 * W1[128+nb+j] + x2 * W1[256+nb+j];
      afr[c][j] = f2bf(fmaxf(h, 0.f));
    }
  }
  f32x4 acc[8];
#pragma unroll
  for (int t = 0; t < 8; t++) acc[t] = (f32x4){0.f,0.f,0.f,0.f};
#pragma unroll
  for (int c = 0; c < 4; c++){
#pragma unroll
    for (int t = 0; t < 8; t++){
      bf16x8 b = *(const bf16x8*)(wb + ((c*8 + t)*64 + l)*8);
      acc[t] = __builtin_amdgcn_mfma_f32_16x16x32_bf16(afr[c], b, acc[t], 0, 0, 0);
    }
  }
  const int row_d = row0 + q * 4;
#pragma unroll
  for (int t = 0; t < 8; t++){
    int col = t * 16 + m;
    float bb = b2[col];
#pragma unroll
    for (int r = 0; r < 4; r++){
      int e = row_d + r;
      if (e < rows) out[(size_t)e * HDIM + col] = __float2bfloat16(acc[t][r] + bb);
    }
  }
}

// ---------------------------------------------------------------------------
// Single-layer GEMM (decoder W1): out_f32 = relu(A_bf16 @ W + b)
// ---------------------------------------------------------------------------
__launch_bounds__(256)
__global__ void gemm128_g(const __hip_bfloat16* __restrict__ A,
                          const __hip_bfloat16* __restrict__ Wf,
                          const float* __restrict__ bias,
                          float* __restrict__ out, int rows){
  const int tid = threadIdx.x, w = tid >> 6, l = tid & 63, m = l & 15, q = l >> 4;
  const short* wb = (const short*)Wf;
  const int row0 = blockIdx.x * 64 + w * 16;
  const int ra = min(row0 + m, rows - 1);
  const short* pa = (const short*)A + (size_t)ra * HDIM + q * 8;
  f32x4 acc[8];
#pragma unroll
  for (int t = 0; t < 8; t++) acc[t] = (f32x4){0.f,0.f,0.f,0.f};
#pragma unroll
  for (int c = 0; c < 4; c++){
    bf16x8 a = *(const bf16x8*)(pa + c * 32);
#pragma unroll
    for (int t = 0; t < 8; t++){
      bf16x8 b = *(const bf16x8*)(wb + ((c*8 + t)*64 + l)*8);
      acc[t] = __builtin_amdgcn_mfma_f32_16x16x32_bf16(a, b, acc[t], 0, 0, 0);
    }
  }
  const int row_d = row0 + q * 4;
#pragma unroll
  for (int t = 0; t < 8; t++){
    int col = t * 16 + m;
    float bb = bias[col];
#pragma unroll
    for (int r = 0; r < 4; r++){
      int e = row_d + r;
      if (e < rows) out[(size_t)e * HDIM + col] = fmaxf(acc[t][r] + bb, 0.f);
    }
  }
}

// ---------------------------------------------------------------------------
// Edge block v4: ef += MLP([ef | nf[snd] | nf[rcv]])   (no atomics here)
// 64 rows/block, 1 tile/wave, weights from global (frag-major, L2-hot).
// hsh timeline per wave (wave-private, no barriers):
//   h (D->rowmajor) -> ds_read A-frags -> MFMA L2 -> overwrite with v ->
//   coalesced read rows -> global residual add + 16B stores.
// ---------------------------------------------------------------------------
__launch_bounds__(256)
__global__ void edge_block(const int* __restrict__ snd,
                           const int* __restrict__ rcv,
                           const __hip_bfloat16* __restrict__ nf,
                           __hip_bfloat16* __restrict__ ef,
                           const __hip_bfloat16* __restrict__ Wfrag, // W1|W2 frag-major
                           const float* __restrict__ b1,
                           const float* __restrict__ b2,
                           int E){
  __shared__ __align__(16) short hsh[4][16][136];
  const int tid = threadIdx.x, w = tid >> 6, l = tid & 63, m = l & 15, q = l >> 4;
  const short* wb = (const short*)Wfrag;
  const int row0 = blockIdx.x * 64 + w * 16;
  const int ra = min(row0 + m, E - 1);
  const int si = snd[ra], ri = rcv[ra];
  const short* pe = (const short*)ef + (size_t)ra * HDIM + q * 8;
  const short* ps = (const short*)nf + (size_t)si * HDIM + q * 8;
  const short* pr = (const short*)nf + (size_t)ri * HDIM + q * 8;
  bf16x8 afr[12];
#pragma unroll
  for (int c = 0; c < 4; c++){
    afr[c]   = *(const bf16x8*)(pe + c * 32);
    afr[4+c] = *(const bf16x8*)(ps + c * 32);
    afr[8+c] = *(const bf16x8*)(pr + c * 32);
  }
  f32x4 acc[8];
#pragma unroll
  for (int t = 0; t < 8; t++) acc[t] = (f32x4){0.f,0.f,0.f,0.f};
#pragma unroll
  for (int c = 0; c < 12; c++){
#pragma unroll
    for (int t = 0; t < 8; t++){
      bf16x8 b = *(const bf16x8*)(wb + ((c*8 + t)*64 + l)*8);
      acc[t] = __builtin_amdgcn_mfma_f32_16x16x32_bf16(afr[c], b, acc[t], 0, 0, 0);
    }
  }
#pragma unroll
  for (int t = 0; t < 8; t++){
    float bb = b1[t * 16 + m];
#pragma unroll
    for (int r = 0; r < 4; r++)
      hsh[w][q*4 + r][t*16 + m] = f2bf(fmaxf(acc[t][r] + bb, 0.f));
  }
  const short* ph = &hsh[w][m][0] + q * 8;
  f32x4 acc2[8];
#pragma unroll
  for (int t = 0; t < 8; t++) acc2[t] = (f32x4){0.f,0.f,0.f,0.f};
#pragma unroll
  for (int c = 0; c < 4; c++){
    bf16x8 a = *(const bf16x8*)(ph + c * 32);
#pragma unroll
    for (int t = 0; t < 8; t++){
      bf16x8 b = *(const bf16x8*)(wb + 49152 + ((c*8 + t)*64 + l)*8);
      acc2[t] = __builtin_amdgcn_mfma_f32_16x16x32_bf16(a, b, acc2[t], 0, 0, 0);
    }
  }
  // v = acc2 + b2 into hsh (reuse; same-wave DS ordering is in-order)
#pragma unroll
  for (int t = 0; t < 8; t++){
    float bb = b2[t * 16 + m];
#pragma unroll
    for (int r = 0; r < 4; r++)
      hsh[w][q*4 + r][t*16 + m] = f2bf(acc2[t][r] + bb);
  }
  // coalesced residual add + store: lane -> row l>>2, cols (l&3)*32..+31
  int orow = row0 + (l >> 2);
  if (orow < E){
    const short* src = &hsh[w][l >> 2][(l & 3) * 32];
    short* dst = (short*)ef + (size_t)orow * HDIM + (l & 3) * 32;
#pragma unroll
    for (int k = 0; k < 4; k++){
      bf16x8 vnew = *(const bf16x8*)(src + k * 8);
      bf16x8 vold = *(const bf16x8*)(dst + k * 8);
      bf16x8 vo;
#pragma unroll
      for (int j = 0; j < 8; j++) vo[j] = f2bf(bfb2f(vnew[j]) + bfb2f(vold[j]));
      *(bf16x8*)(dst + k * 8) = vo;
    }
  }
}

// ---------------------------------------------------------------------------
// Node block v4: agg = CSR-gather-sum(ef); nf += MLP([nf | agg])
// ---------------------------------------------------------------------------
__launch_bounds__(256)
__global__ void node_block(const int* __restrict__ row_start,
                           const int* __restrict__ eids,
                           const __hip_bfloat16* __restrict__ ef,
                           __hip_bfloat16* __restrict__ nf,
                           const __hip_bfloat16* __restrict__ Wfrag, // nW1|nW2 frag-major
                           const float* __restrict__ b1,
                           const float* __restrict__ b2,
                           int N){
  __shared__ __align__(16) short hsh[4][16][136];
  const int tid = threadIdx.x, w = tid >> 6, l = tid & 63, m = l & 15, q = l >> 4;
  const short* wb = (const short*)Wfrag;
  const int row0 = blockIdx.x * 64 + w * 16;
  const int ra = min(row0 + m, N - 1);
  const short* pn = (const short*)nf + (size_t)ra * HDIM + q * 8;
  bf16x8 afr[8];
#pragma unroll
  for (int c = 0; c < 4; c++) afr[c] = *(const bf16x8*)(pn + c * 32);
  // CSR aggregation: lane (m,q) sums cols {c*32+q*8..+7} over incident edges
  float sum[4][8];
#pragma unroll
  for (int c = 0; c < 4; c++)
#pragma unroll
    for (int j = 0; j < 8; j++) sum[c][j] = 0.f;
  int s0 = row_start[ra], s1 = row_start[ra + 1];
  for (int it = s0; it < s1; it++){
    int eid = eids[it];
    const short* pf = (const short*)ef + (size_t)eid * HDIM + q * 8;
#pragma unroll
    for (int c = 0; c < 4; c++){
      bf16x8 v = *(const bf16x8*)(pf + c * 32);
#pragma unroll
      for (int j = 0; j < 8; j++) sum[c][j] += bfb2f(v[j]);
    }
  }
#pragma unroll
  for (int c = 0; c < 4; c++)
#pragma unroll
    for (int j = 0; j < 8; j++) afr[4 + c][j] = f2bf(sum[c][j]);

  f32x4 acc[8];
#pragma unroll
  for (int t = 0; t < 8; t++) acc[t] = (f32x4){0.f,0.f,0.f,0.f};
#pragma unroll
  for (int c = 0; c < 8; c++){
#pragma unroll
    for (int t = 0; t < 8; t++){
      bf16x8 b = *(const bf16x8*)(wb + ((c*8 + t)*64 + l)*8);
      acc[t] = __builtin_amdgcn_mfma_f32_16x16x32_bf16(afr[c], b, acc[t], 0, 0, 0);
    }
  }
#pragma unroll
  for (int t = 0; t < 8; t++){
    float bb = b1[t * 16 + m];
#pragma unroll
    for (int r = 0; r < 4; r++)
      hsh[w][q*4 + r][t*16 + m] = f2bf(fmaxf(acc[t][r] + bb, 0.f));
  }
  const short* ph = &hsh[w][m][0] + q * 8;
  f32x4 acc2[8];
#pragma unroll
  for (int t = 0; t < 8; t++) acc2[t] = (f32x4){0.f,0.f,0.f,0.f};
#pragma unroll
  for (int c = 0; c < 4; c++){
    bf16x8 a = *(const bf16x8*)(ph + c * 32);
#pragma unroll
    for (int t = 0; t < 8; t++){
      bf16x8 b = *(const bf16x8*)(wb + 32768 + ((c*8 + t)*64 + l)*8);
      acc2[t] = __builtin_amdgcn_mfma_f32_16x16x32_bf16(a, b, acc2[t], 0, 0, 0);
    }
  }
#pragma unroll
  for (int t = 0; t < 8; t++){
    float bb = b2[t * 16 + m];
#pragma unroll
    for (int r = 0; r < 4; r++)
      hsh[w][q*4 + r][t*16 + m] = f2bf(acc2[t][r] + bb);
  }
  int orow = row0 + (l >> 2);
  if (orow < N){
    const short* src = &hsh[w][l >> 2][(l & 3) * 32];
    short* dst = (short*)nf + (size_t)orow * HDIM + (l & 3) * 32;
#pragma unroll
    for (int k = 0; k < 4; k++){
      bf16x8 vnew = *(const bf16x8*)(src + k * 8);
      bf16x8 vold = *(const bf16x8*)(dst + k * 8);
      bf16x8 vo;
#pragma unroll
      for (int j = 0; j < 8; j++) vo[j] = f2bf(bfb2f(vnew[j]) + bfb2f(vold[j]));
      *(bf16x8*)(dst + k * 8) = vo;
    }
  }
}

// ---------------------------------------------------------------------------
// Decoder final layer: [rows,128] fp32 @ [128,3] + b -> dec_out[rows,3]
// ---------------------------------------------------------------------------
__global__ void dec_final(const float* __restrict__ hbuf,
                          const float* __restrict__ W2,
                          const float* __restrict__ b2,
                          float* __restrict__ outd, int rows){
  __shared__ float hl[64 * 129];
  __shared__ float Wl[HDIM * 3];
  __shared__ float bl[3];
  int t = threadIdx.x;
  int node0 = blockIdx.x * 64;
  for (int i = t; i < HDIM * 3; i += 256) Wl[i] = W2[i];
  if (t < 3) bl[t] = b2[t];
#pragma unroll
  for (int i = 0; i < 32; i++){
    int lin = t + i * 256;
    int r = lin >> 7;
    int c = lin & 127;
    int node = node0 + r;
    hl[r * 129 + c] = (node < rows) ? hbuf[(size_t)node * HDIM + c] : 0.f;
  }
  __syncthreads();
  if (t < 64){
    int node = node0 + t;
    if (node < rows){
      float a0 = bl[0], a1 = bl[1], a2 = bl[2];
      for (int k = 0; k < HDIM; k++){
        float v = hl[t * 129 + k];
        a0 += v * Wl[k * 3];
        a1 += v * Wl[k * 3 + 1];
        a2 += v * Wl[k * 3 + 2];
      }
      outd[3 * node]     = a0;
      outd[3 * node + 1] = a1;
      outd[3 * node + 2] = a2;
    }
  }
}

__global__ void epilogue(const float* __restrict__ dec_out,
                         const float* __restrict__ zl,
                         const float* __restrict__ z_target,
                         const float* __restrict__ fin,
                         float* __restrict__ d_out,
                         float* __restrict__ stats_raw, int N){
  int n = blockIdx.x * blockDim.x + threadIdx.x;
  float lsum = 0.f, r0 = 0.f, r1 = 0.f, r2 = 0.f;
  if (n < N){
#pragma unroll
    for (int d = 0; d < 3; d++){
      float om = fin[12 + d], os = fin[15 + d];
      float o   = dec_out[3*n + d];
      float zld = zl[3*n + d];
      float zt  = z_target[3*n + d];
      float tgt = zt - zld;
      float tn  = (tgt - om) / os;
      float diff = tn - o;
      lsum += diff * diff;
      float zp = zld + o * os + om;
      d_out[3*n + d] = zp;
      float e = zp - zt;
      e = e * e;
      if (d == 0) r0 = e; else if (d == 1) r1 = e; else r2 = e;
    }
  }
  lsum = wave_sum(lsum); r0 = wave_sum(r0); r1 = wave_sum(r1); r2 = wave_sum(r2);
  if ((threadIdx.x & 63) == 0){
    atomicAdd(&stats_raw[18], lsum);
    atomicAdd(&stats_raw[19], r0);
    atomicAdd(&stats_raw[20], r1);
    atomicAdd(&stats_raw[21], r2);
  }
}

__global__ void finalize_out(const float* __restrict__ raw,
                             float* __restrict__ d_out, int N){
  float cN = (float)N;
  float loss = raw[18] / (3.f * cN);
  float rmse = (sqrtf(raw[19] / cN) + sqrtf(raw[20] / cN) + sqrtf(raw[21] / cN)) / 3.f;
  d_out[(size_t)3 * N]     = loss;
  d_out[(size_t)3 * N + 1] = rmse;
}

// ---------------------------------------------------------------------------
extern "C" void kernel_launch(void* const* d_in, const int* in_sizes, int n_in,
                              void* d_out, int out_size, void* d_ws, size_t ws_size,
                              hipStream_t stream){
  const float* z           = (const float*)d_in[0];
  const float* z_target    = (const float*)d_in[1];
  const float* pos         = (const float*)d_in[2];
  const float* enc_node_W1 = (const float*)d_in[3];
  const float* enc_node_b1 = (const float*)d_in[4];
  const float* enc_node_W2 = (const float*)d_in[5];
  const float* enc_node_b2 = (const float*)d_in[6];
  const float* enc_edge_W1 = (const float*)d_in[7];
  const float* enc_edge_b1 = (const float*)d_in[8];
  const float* enc_edge_W2 = (const float*)d_in[9];
  const float* enc_edge_b2 = (const float*)d_in[10];
  const float* dec_W1      = (const float*)d_in[11];
  const float* dec_b1      = (const float*)d_in[12];
  const float* dec_W2      = (const float*)d_in[13];
  const float* dec_b2      = (const float*)d_in[14];
  const float* blk_edge_W1 = (const float*)d_in[15];
  const float* blk_edge_b1 = (const float*)d_in[16];
  const float* blk_edge_W2 = (const float*)d_in[17];
  const float* blk_edge_b2 = (const float*)d_in[18];
  const float* blk_node_W1 = (const float*)d_in[19];
  const float* blk_node_b1 = (const float*)d_in[20];
  const float* blk_node_W2 = (const float*)d_in[21];
  const float* blk_node_b2 = (const float*)d_in[22];
  const int*   senders     = (const int*)d_in[23];
  const int*   receivers   = (const int*)d_in[24];

  const int N = in_sizes[1] / 3;
  const int E = in_sizes[23];
  const float* zl = z + (size_t)N * 3;

  char* p = (char*)d_ws;
  auto carve = [&](size_t bytes) -> char* {
    char* r = p; p += (bytes + 255) & ~(size_t)255; return r;
  };
  float* stats_raw = (float*)carve(64 * 4);
  float* stats_fin = (float*)carve(32 * 4);
  float* ef_raw    = (float*)carve((size_t)E * 3 * 4);
  float* dec_out   = (float*)carve((size_t)N * 3 * 4);
  float* hbuf      = (float*)carve((size_t)N * HDIM * 4);
  int*   deg       = (int*)carve((size_t)N * 4);
  int*   row_start = (int*)carve((size_t)(N + 1) * 4);
  int*   cursor    = (int*)carve((size_t)N * 4);
  int*   eids      = (int*)carve((size_t)E * 4);
  __hip_bfloat16* wp = (__hip_bfloat16*)carve((size_t)507904 * 2);
  __hip_bfloat16* ef = (__hip_bfloat16*)carve((size_t)E * HDIM * 2);
  __hip_bfloat16* nf = (__hip_bfloat16*)carve((size_t)N * HDIM * 2);

  float* out = (float*)d_out;

  hipMemsetAsync(stats_raw, 0, 64 * sizeof(float), stream);
  hipMemsetAsync(deg, 0, (size_t)N * 4, stream);

  edge_raw_stats<<<ceil_div(E, TPB), TPB, 0, stream>>>(pos, senders, receivers, ef_raw, stats_raw, E);
  node_stats<<<ceil_div(N, TPB), TPB, 0, stream>>>(zl, z_target, stats_raw, N);
  finalize_stats<<<1, 1, 0, stream>>>(stats_raw, stats_fin, E, N);

  // CSR build (receivers constant across blocks)
  csr_hist<<<ceil_div(E, TPB), TPB, 0, stream>>>(receivers, deg, E);
  csr_scan<<<1, 1024, 0, stream>>>(deg, row_start, N, E);
  hipMemcpyAsync(cursor, row_start, (size_t)N * 4, hipMemcpyDeviceToDevice, stream);
  csr_scatter<<<ceil_div(E, TPB), TPB, 0, stream>>>(receivers, cursor, eids, E);

  pack_weights<<<dim3(192, 19), TPB, 0, stream>>>(enc_edge_W2, enc_node_W2, dec_W1,
                                                  blk_edge_W1, blk_edge_W2,
                                                  blk_node_W1, blk_node_W2, wp);

  // encoders (hidden layer fused)
  encoder_fused<<<ceil_div(E, 64), TPB, 0, stream>>>(ef_raw, stats_fin + 0, stats_fin + 3,
                                                     enc_edge_W1, enc_edge_b1,
                                                     wp, enc_edge_b2, ef, E);
  encoder_fused<<<ceil_div(N, 64), TPB, 0, stream>>>(zl, stats_fin + 6, stats_fin + 9,
                                                     enc_node_W1, enc_node_b1,
                                                     wp + 16384, enc_node_b2, nf, N);

  // message-passing blocks
  for (int b = 0; b < 4; b++){
    const __hip_bfloat16* eWf = wp + 49152 + (size_t)b * 114688;          // eW1|eW2
    const __hip_bfloat16* nWf = eWf + 65536;                              // nW1|nW2
    const float* eb1 = blk_edge_b1 + (size_t)b * 128;
    const float* eb2 = blk_edge_b2 + (size_t)b * 128;
    const float* nb1 = blk_node_b1 + (size_t)b * 128;
    const float* nb2 = blk_node_b2 + (size_t)b * 128;

    edge_block<<<ceil_div(E, 64), TPB, 0, stream>>>(senders, receivers, nf, ef,
                                                    eWf, eb1, eb2, E);
    node_block<<<ceil_div(N, 64), TPB, 0, stream>>>(row_start, eids, ef, nf,
                                                    nWf, nb1, nb2, N);
  }

  // decoder
  gemm128_g<<<ceil_div(N, 64), TPB, 0, stream>>>(nf, wp + 32768, dec_b1, hbuf, N);
  dec_final<<<ceil_div(N, 64), TPB, 0, stream>>>(hbuf, dec_W2, dec_b2, dec_out, N);

  epilogue<<<ceil_div(N, TPB), TPB, 0, stream>>>(dec_out, zl, z_target, stats_fin,
                                                 out, stats_raw, N);
  finalize_out<<<1, 1, 0, stream>>>(stats_raw, out, N);
}

// Round 5
// 635.882 us; speedup vs baseline: 5.9724x; 1.4502x over previous
//
#include <hip/hip_runtime.h>
#include <hip/hip_bf16.h>
#include <math.h>

#define HDIM 128
#define TPB 256

typedef __attribute__((ext_vector_type(8))) short bf16x8;
typedef __attribute__((ext_vector_type(4))) float f32x4;

static inline int ceil_div(int a, int b){ return (a + b - 1) / b; }

__device__ __forceinline__ float wave_sum(float v){
#pragma unroll
  for (int o = 32; o > 0; o >>= 1) v += __shfl_down(v, o, 64);
  return v;
}

__device__ __forceinline__ short f2bf(float f){
  __hip_bfloat16 h = __float2bfloat16(f);
  return *reinterpret_cast<short*>(&h);
}
__device__ __forceinline__ float bfb2f(short s){
  unsigned int u = ((unsigned int)(unsigned short)s) << 16;
  return __builtin_bit_cast(float, u);
}

// ---------------------------------------------------------------------------
// 1. Edge raw features + per-block partial sums (NO global atomics)
//    epart[blk*6 + k] = block-sums of {rx, ry, nm, rx2, ry2, nm2}
// ---------------------------------------------------------------------------
__global__ void edge_raw_stats(const float* __restrict__ pos,
                               const int* __restrict__ snd,
                               const int* __restrict__ rcv,
                               float* __restrict__ ef_raw,
                               float* __restrict__ epart, int E){
  __shared__ float red[4][6];
  int tid = threadIdx.x, w = tid >> 6, l = tid & 63;
  int e = blockIdx.x * blockDim.x + tid;
  float s[6] = {0.f,0.f,0.f,0.f,0.f,0.f};
  if (e < E){
    int si = snd[e], ri = rcv[e];
    float rx = pos[2*si]   - pos[2*ri];
    float ry = pos[2*si+1] - pos[2*ri+1];
    float nm = sqrtf(rx*rx + ry*ry);
    ef_raw[3*e]   = rx;
    ef_raw[3*e+1] = ry;
    ef_raw[3*e+2] = nm;
    s[0] = rx; s[1] = ry; s[2] = nm;
    s[3] = rx*rx; s[4] = ry*ry; s[5] = nm*nm;
  }
#pragma unroll
  for (int k = 0; k < 6; k++) s[k] = wave_sum(s[k]);
  if (l == 0)
#pragma unroll
    for (int k = 0; k < 6; k++) red[w][k] = s[k];
  __syncthreads();
  if (tid < 6)
    epart[(size_t)blockIdx.x * 6 + tid] =
      red[0][tid] + red[1][tid] + red[2][tid] + red[3][tid];
}

// ---------------------------------------------------------------------------
// 2. Node stats partials: npart[blk*12 + k] = {zl, zl2, tgt, tgt2} x 3 dims
// ---------------------------------------------------------------------------
__global__ void node_stats(const float* __restrict__ zl,
                           const float* __restrict__ z_target,
                           float* __restrict__ npart, int N){
  __shared__ float red[4][12];
  int tid = threadIdx.x, w = tid >> 6, l = tid & 63;
  int n = blockIdx.x * blockDim.x + tid;
  float s[12];
#pragma unroll
  for (int i = 0; i < 12; i++) s[i] = 0.f;
  if (n < N){
#pragma unroll
    for (int d = 0; d < 3; d++){
      float z = zl[3*n+d];
      float t = z_target[3*n+d] - z;
      s[d]   = z;  s[3+d] = z*z;
      s[6+d] = t;  s[9+d] = t*t;
    }
  }
#pragma unroll
  for (int i = 0; i < 12; i++) s[i] = wave_sum(s[i]);
  if (l == 0)
#pragma unroll
    for (int i = 0; i < 12; i++) red[w][i] = s[i];
  __syncthreads();
  if (tid < 12)
    npart[(size_t)blockIdx.x * 12 + tid] =
      red[0][tid] + red[1][tid] + red[2][tid] + red[3][tid];
}

// ---------------------------------------------------------------------------
// 3. Reduce partials -> raw[0..5]=edge sums, raw[6..17]=node sums  (1 block)
// ---------------------------------------------------------------------------
__global__ void reduce_stats(const float* __restrict__ ep, int ne,
                             const float* __restrict__ np_, int nn,
                             float* __restrict__ raw){
  __shared__ float red[4];
  int tid = threadIdx.x, w = tid >> 6, l = tid & 63;
  for (int j = 0; j < 6; j++){
    float s = 0.f;
    for (int b = tid; b < ne; b += 256) s += ep[(size_t)b * 6 + j];
    s = wave_sum(s);
    if (l == 0) red[w] = s;
    __syncthreads();
    if (tid == 0) raw[j] = red[0] + red[1] + red[2] + red[3];
    __syncthreads();
  }
  for (int j = 0; j < 12; j++){
    float s = 0.f;
    for (int b = tid; b < nn; b += 256) s += np_[(size_t)b * 12 + j];
    s = wave_sum(s);
    if (l == 0) red[w] = s;
    __syncthreads();
    if (tid == 0) raw[6 + j] = red[0] + red[1] + red[2] + red[3];
    __syncthreads();
  }
}

// stats_fin: em[0..2] es[3..5] nm[6..8] ns[9..11] om[12..14] os[15..17]
__global__ void finalize_stats(const float* __restrict__ raw,
                               float* __restrict__ fin, int E, int N){
#pragma unroll
  for (int d = 0; d < 3; d++){
    float cE = (float)E, cN = (float)N;
    float m, v;
    m = raw[0+d] / cE; v = fmaxf(raw[3+d]/cE - m*m, 0.f);
    fin[0+d] = m;  fin[3+d]  = fmaxf(sqrtf(v), 1e-8f);
    m = raw[6+d] / cN; v = fmaxf(raw[9+d]/cN - m*m, 0.f);
    fin[6+d] = m;  fin[9+d]  = fmaxf(sqrtf(v), 1e-8f);
    m = raw[12+d] / cN; v = fmaxf(raw[15+d]/cN - m*m, 0.f);
    fin[12+d] = m; fin[15+d] = fmaxf(sqrtf(v), 1e-8f);
  }
}

// ---------------------------------------------------------------------------
// CSR build for receivers (reused by all 4 blocks)
// ---------------------------------------------------------------------------
__global__ void csr_hist(const int* __restrict__ rcv, int* __restrict__ deg, int E){
  int e = blockIdx.x * blockDim.x + threadIdx.x;
  if (e < E) atomicAdd(&deg[rcv[e]], 1);
}

__global__ void csr_scan(const int* __restrict__ deg, int* __restrict__ row_start,
                         int N, int E){
  __shared__ int part[1024];
  int t = threadIdx.x;
  int chunk = (N + 1023) / 1024;
  int lo = t * chunk, hi = min(lo + chunk, N);
  int s = 0;
  for (int i = lo; i < hi; i++) s += deg[i];
  part[t] = s;
  __syncthreads();
  for (int off = 1; off < 1024; off <<= 1){
    int v = (t >= off) ? part[t - off] : 0;
    __syncthreads();
    part[t] += v;
    __syncthreads();
  }
  int base = (t == 0) ? 0 : part[t - 1];
  for (int i = lo; i < hi; i++){
    row_start[i] = base;
    base += deg[i];
  }
  if (t == 1023) row_start[N] = E;
}

__global__ void csr_scatter(const int* __restrict__ rcv, int* __restrict__ cursor,
                            int* __restrict__ eids, int E){
  int e = blockIdx.x * blockDim.x + threadIdx.x;
  if (e < E){
    int p = atomicAdd(&cursor[rcv[e]], 1);
    eids[p] = e;
  }
}

// ---------------------------------------------------------------------------
// Weight packing: fp32 row-major [K][128] -> bf16 FRAGMENT-MAJOR:
//   dst[((c*8 + t)*64 + lane)*8 + j] = src[k][n],
//   k = c*32 + (lane>>4)*8 + j, n = t*16 + (lane&15)
// wp layout (bf16 elems):
//  0: enc_edge_W2 (16384)  16384: enc_node_W2  32768: dec_W1
//  49152 + b*114688 : eW1_b(49152) | +49152 eW2_b(16384) | +65536 nW1_b(32768) | +98304 nW2_b(16384)
// ---------------------------------------------------------------------------
__global__ void pack_weights(const float* __restrict__ encEW2,
                             const float* __restrict__ encNW2,
                             const float* __restrict__ decW1,
                             const float* __restrict__ beW1,
                             const float* __restrict__ beW2,
                             const float* __restrict__ bnW1,
                             const float* __restrict__ bnW2,
                             __hip_bfloat16* __restrict__ wp){
  int y = blockIdx.y;
  const float* src; __hip_bfloat16* dst; int K;
  if (y == 0){ src = encEW2; dst = wp;          K = 128; }
  else if (y == 1){ src = encNW2; dst = wp + 16384; K = 128; }
  else if (y == 2){ src = decW1;  dst = wp + 32768; K = 128; }
  else {
    int b = (y - 3) >> 2, j = (y - 3) & 3;
    __hip_bfloat16* base = wp + 49152 + b * 114688;
    if (j == 0){ src = beW1 + b*49152; dst = base;          K = 384; }
    else if (j == 1){ src = beW2 + b*16384; dst = base + 49152; K = 128; }
    else if (j == 2){ src = bnW1 + b*32768; dst = base + 65536; K = 256; }
    else { src = bnW2 + b*16384; dst = base + 98304; K = 128; }
  }
  int id = blockIdx.x * blockDim.x + threadIdx.x;
  if (id >= 128 * K) return;
  int c = id >> 12;
  int r = id & 4095;
  int t = r >> 9;
  int l = (r >> 3) & 63;
  int j = r & 7;
  int k = c * 32 + ((l >> 4) << 3) + j;
  int n = t * 16 + (l & 15);
  dst[id] = __float2bfloat16(src[k * 128 + n]);
}

// ---------------------------------------------------------------------------
// Fused encoder: out[rows,128] = (relu(norm(raw3) @ W1 + b1)) @ W2 + b2
// ---------------------------------------------------------------------------
__launch_bounds__(256)
__global__ void encoder_fused(const float* __restrict__ raw,
                              const float* __restrict__ mptr,
                              const float* __restrict__ sptr,
                              const float* __restrict__ W1,   // [3][128] f32
                              const float* __restrict__ b1,
                              const __hip_bfloat16* __restrict__ W2f, // frag-major
                              const float* __restrict__ b2,
                              __hip_bfloat16* __restrict__ out, int rows){
  const int tid = threadIdx.x, w = tid >> 6, l = tid & 63, m = l & 15, q = l >> 4;
  const short* wb = (const short*)W2f;

  float s0 = mptr[0], s1 = mptr[1], s2 = mptr[2];
  float d0 = sptr[0], d1 = sptr[1], d2 = sptr[2];

  const int row0 = blockIdx.x * 64 + w * 16;
  const int ra = min(row0 + m, rows - 1);
  float x0 = (raw[3*ra]   - s0) / d0;
  float x1 = (raw[3*ra+1] - s1) / d1;
  float x2 = (raw[3*ra+2] - s2) / d2;
  bf16x8 afr[4];
#pragma unroll
  for (int c = 0; c < 4; c++){
    int nb = c * 32 + q * 8;
#pragma unroll
    for (int j = 0; j < 8; j++){
      float h = b1[nb+j] + x0 * W1[nb+j] + x1 * W1[128+nb+j] + x2 * W1[256+nb+j];
      afr[c][j] = f2bf(fmaxf(h, 0.f));
    }
  }
  f32x4 acc[8];
#pragma unroll
  for (int t = 0; t < 8; t++) acc[t] = (f32x4){0.f,0.f,0.f,0.f};
#pragma unroll
  for (int c = 0; c < 4; c++){
#pragma unroll
    for (int t = 0; t < 8; t++){
      bf16x8 b = *(const bf16x8*)(wb + ((c*8 + t)*64 + l)*8);
      acc[t] = __builtin_amdgcn_mfma_f32_16x16x32_bf16(afr[c], b, acc[t], 0, 0, 0);
    }
  }
  const int row_d = row0 + q * 4;
#pragma unroll
  for (int t = 0; t < 8; t++){
    int col = t * 16 + m;
    float bb = b2[col];
#pragma unroll
    for (int r = 0; r < 4; r++){
      int e = row_d + r;
      if (e < rows) out[(size_t)e * HDIM + col] = __float2bfloat16(acc[t][r] + bb);
    }
  }
}

// ---------------------------------------------------------------------------
// Single-layer GEMM (decoder W1): out_f32 = relu(A_bf16 @ W + b)
// ---------------------------------------------------------------------------
__launch_bounds__(256)
__global__ void gemm128_g(const __hip_bfloat16* __restrict__ A,
                          const __hip_bfloat16* __restrict__ Wf,
                          const float* __restrict__ bias,
                          float* __restrict__ out, int rows){
  const int tid = threadIdx.x, w = tid >> 6, l = tid & 63, m = l & 15, q = l >> 4;
  const short* wb = (const short*)Wf;
  const int row0 = blockIdx.x * 64 + w * 16;
  const int ra = min(row0 + m, rows - 1);
  const short* pa = (const short*)A + (size_t)ra * HDIM + q * 8;
  f32x4 acc[8];
#pragma unroll
  for (int t = 0; t < 8; t++) acc[t] = (f32x4){0.f,0.f,0.f,0.f};
#pragma unroll
  for (int c = 0; c < 4; c++){
    bf16x8 a = *(const bf16x8*)(pa + c * 32);
#pragma unroll
    for (int t = 0; t < 8; t++){
      bf16x8 b = *(const bf16x8*)(wb + ((c*8 + t)*64 + l)*8);
      acc[t] = __builtin_amdgcn_mfma_f32_16x16x32_bf16(a, b, acc[t], 0, 0, 0);
    }
  }
  const int row_d = row0 + q * 4;
#pragma unroll
  for (int t = 0; t < 8; t++){
    int col = t * 16 + m;
    float bb = bias[col];
#pragma unroll
    for (int r = 0; r < 4; r++){
      int e = row_d + r;
      if (e < rows) out[(size_t)e * HDIM + col] = fmaxf(acc[t][r] + bb, 0.f);
    }
  }
}

// ---------------------------------------------------------------------------
// Edge block: ef += MLP([ef | nf[snd] | nf[rcv]])   (no atomics)
// 64 rows/block, 1 tile/wave, weights from global (frag-major, L2-hot).
// ---------------------------------------------------------------------------
__launch_bounds__(256)
__global__ void edge_block(const int* __restrict__ snd,
                           const int* __restrict__ rcv,
                           const __hip_bfloat16* __restrict__ nf,
                           __hip_bfloat16* __restrict__ ef,
                           const __hip_bfloat16* __restrict__ Wfrag, // W1|W2 frag-major
                           const float* __restrict__ b1,
                           const float* __restrict__ b2,
                           int E){
  __shared__ __align__(16) short hsh[4][16][136];
  const int tid = threadIdx.x, w = tid >> 6, l = tid & 63, m = l & 15, q = l >> 4;
  const short* wb = (const short*)Wfrag;
  const int row0 = blockIdx.x * 64 + w * 16;
  const int ra = min(row0 + m, E - 1);
  const int si = snd[ra], ri = rcv[ra];
  const short* pe = (const short*)ef + (size_t)ra * HDIM + q * 8;
  const short* ps = (const short*)nf + (size_t)si * HDIM + q * 8;
  const short* pr = (const short*)nf + (size_t)ri * HDIM + q * 8;
  bf16x8 afr[12];
#pragma unroll
  for (int c = 0; c < 4; c++){
    afr[c]   = *(const bf16x8*)(pe + c * 32);
    afr[4+c] = *(const bf16x8*)(ps + c * 32);
    afr[8+c] = *(const bf16x8*)(pr + c * 32);
  }
  f32x4 acc[8];
#pragma unroll
  for (int t = 0; t < 8; t++) acc[t] = (f32x4){0.f,0.f,0.f,0.f};
#pragma unroll
  for (int c = 0; c < 12; c++){
#pragma unroll
    for (int t = 0; t < 8; t++){
      bf16x8 b = *(const bf16x8*)(wb + ((c*8 + t)*64 + l)*8);
      acc[t] = __builtin_amdgcn_mfma_f32_16x16x32_bf16(afr[c], b, acc[t], 0, 0, 0);
    }
  }
#pragma unroll
  for (int t = 0; t < 8; t++){
    float bb = b1[t * 16 + m];
#pragma unroll
    for (int r = 0; r < 4; r++)
      hsh[w][q*4 + r][t*16 + m] = f2bf(fmaxf(acc[t][r] + bb, 0.f));
  }
  const short* ph = &hsh[w][m][0] + q * 8;
  f32x4 acc2[8];
#pragma unroll
  for (int t = 0; t < 8; t++) acc2[t] = (f32x4){0.f,0.f,0.f,0.f};
#pragma unroll
  for (int c = 0; c < 4; c++){
    bf16x8 a = *(const bf16x8*)(ph + c * 32);
#pragma unroll
    for (int t = 0; t < 8; t++){
      bf16x8 b = *(const bf16x8*)(wb + 49152 + ((c*8 + t)*64 + l)*8);
      acc2[t] = __builtin_amdgcn_mfma_f32_16x16x32_bf16(a, b, acc2[t], 0, 0, 0);
    }
  }
  // v = acc2 + b2 into hsh (reuse; same-wave DS ordering is in-order)
#pragma unroll
  for (int t = 0; t < 8; t++){
    float bb = b2[t * 16 + m];
#pragma unroll
    for (int r = 0; r < 4; r++)
      hsh[w][q*4 + r][t*16 + m] = f2bf(acc2[t][r] + bb);
  }
  // coalesced residual add + store: lane -> row l>>2, cols (l&3)*32..+31
  int orow = row0 + (l >> 2);
  if (orow < E){
    const short* src = &hsh[w][l >> 2][(l & 3) * 32];
    short* dst = (short*)ef + (size_t)orow * HDIM + (l & 3) * 32;
#pragma unroll
    for (int k = 0; k < 4; k++){
      bf16x8 vnew = *(const bf16x8*)(src + k * 8);
      bf16x8 vold = *(const bf16x8*)(dst + k * 8);
      bf16x8 vo;
#pragma unroll
      for (int j = 0; j < 8; j++) vo[j] = f2bf(bfb2f(vnew[j]) + bfb2f(vold[j]));
      *(bf16x8*)(dst + k * 8) = vo;
    }
  }
}

// ---------------------------------------------------------------------------
// Node block: agg = CSR-gather-sum(ef); nf += MLP([nf | agg])
// ---------------------------------------------------------------------------
__launch_bounds__(256)
__global__ void node_block(const int* __restrict__ row_start,
                           const int* __restrict__ eids,
                           const __hip_bfloat16* __restrict__ ef,
                           __hip_bfloat16* __restrict__ nf,
                           const __hip_bfloat16* __restrict__ Wfrag, // nW1|nW2 frag-major
                           const float* __restrict__ b1,
                           const float* __restrict__ b2,
                           int N){
  __shared__ __align__(16) short hsh[4][16][136];
  const int tid = threadIdx.x, w = tid >> 6, l = tid & 63, m = l & 15, q = l >> 4;
  const short* wb = (const short*)Wfrag;
  const int row0 = blockIdx.x * 64 + w * 16;
  const int ra = min(row0 + m, N - 1);
  const short* pn = (const short*)nf + (size_t)ra * HDIM + q * 8;
  bf16x8 afr[8];
#pragma unroll
  for (int c = 0; c < 4; c++) afr[c] = *(const bf16x8*)(pn + c * 32);
  float sum[4][8];
#pragma unroll
  for (int c = 0; c < 4; c++)
#pragma unroll
    for (int j = 0; j < 8; j++) sum[c][j] = 0.f;
  int s0 = row_start[ra], s1 = row_start[ra + 1];
  for (int it = s0; it < s1; it++){
    int eid = eids[it];
    const short* pf = (const short*)ef + (size_t)eid * HDIM + q * 8;
#pragma unroll
    for (int c = 0; c < 4; c++){
      bf16x8 v = *(const bf16x8*)(pf + c * 32);
#pragma unroll
      for (int j = 0; j < 8; j++) sum[c][j] += bfb2f(v[j]);
    }
  }
#pragma unroll
  for (int c = 0; c < 4; c++)
#pragma unroll
    for (int j = 0; j < 8; j++) afr[4 + c][j] = f2bf(sum[c][j]);

  f32x4 acc[8];
#pragma unroll
  for (int t = 0; t < 8; t++) acc[t] = (f32x4){0.f,0.f,0.f,0.f};
#pragma unroll
  for (int c = 0; c < 8; c++){
#pragma unroll
    for (int t = 0; t < 8; t++){
      bf16x8 b = *(const bf16x8*)(wb + ((c*8 + t)*64 + l)*8);
      acc[t] = __builtin_amdgcn_mfma_f32_16x16x32_bf16(afr[c], b, acc[t], 0, 0, 0);
    }
  }
#pragma unroll
  for (int t = 0; t < 8; t++){
    float bb = b1[t * 16 + m];
#pragma unroll
    for (int r = 0; r < 4; r++)
      hsh[w][q*4 + r][t*16 + m] = f2bf(fmaxf(acc[t][r] + bb, 0.f));
  }
  const short* ph = &hsh[w][m][0] + q * 8;
  f32x4 acc2[8];
#pragma unroll
  for (int t = 0; t < 8; t++) acc2[t] = (f32x4){0.f,0.f,0.f,0.f};
#pragma unroll
  for (int c = 0; c < 4; c++){
    bf16x8 a = *(const bf16x8*)(ph + c * 32);
#pragma unroll
    for (int t = 0; t < 8; t++){
      bf16x8 b = *(const bf16x8*)(wb + 32768 + ((c*8 + t)*64 + l)*8);
      acc2[t] = __builtin_amdgcn_mfma_f32_16x16x32_bf16(a, b, acc2[t], 0, 0, 0);
    }
  }
#pragma unroll
  for (int t = 0; t < 8; t++){
    float bb = b2[t * 16 + m];
#pragma unroll
    for (int r = 0; r < 4; r++)
      hsh[w][q*4 + r][t*16 + m] = f2bf(acc2[t][r] + bb);
  }
  int orow = row0 + (l >> 2);
  if (orow < N){
    const short* src = &hsh[w][l >> 2][(l & 3) * 32];
    short* dst = (short*)nf + (size_t)orow * HDIM + (l & 3) * 32;
#pragma unroll
    for (int k = 0; k < 4; k++){
      bf16x8 vnew = *(const bf16x8*)(src + k * 8);
      bf16x8 vold = *(const bf16x8*)(dst + k * 8);
      bf16x8 vo;
#pragma unroll
      for (int j = 0; j < 8; j++) vo[j] = f2bf(bfb2f(vnew[j]) + bfb2f(vold[j]));
      *(bf16x8*)(dst + k * 8) = vo;
    }
  }
}

// ---------------------------------------------------------------------------
// Decoder final layer: [rows,128] fp32 @ [128,3] + b -> dec_out[rows,3]
// ---------------------------------------------------------------------------
__global__ void dec_final(const float* __restrict__ hbuf,
                          const float* __restrict__ W2,
                          const float* __restrict__ b2,
                          float* __restrict__ outd, int rows){
  __shared__ float hl[64 * 129];
  __shared__ float Wl[HDIM * 3];
  __shared__ float bl[3];
  int t = threadIdx.x;
  int node0 = blockIdx.x * 64;
  for (int i = t; i < HDIM * 3; i += 256) Wl[i] = W2[i];
  if (t < 3) bl[t] = b2[t];
#pragma unroll
  for (int i = 0; i < 32; i++){
    int lin = t + i * 256;
    int r = lin >> 7;
    int c = lin & 127;
    int node = node0 + r;
    hl[r * 129 + c] = (node < rows) ? hbuf[(size_t)node * HDIM + c] : 0.f;
  }
  __syncthreads();
  if (t < 64){
    int node = node0 + t;
    if (node < rows){
      float a0 = bl[0], a1 = bl[1], a2 = bl[2];
      for (int k = 0; k < HDIM; k++){
        float v = hl[t * 129 + k];
        a0 += v * Wl[k * 3];
        a1 += v * Wl[k * 3 + 1];
        a2 += v * Wl[k * 3 + 2];
      }
      outd[3 * node]     = a0;
      outd[3 * node + 1] = a1;
      outd[3 * node + 2] = a2;
    }
  }
}

// ---------------------------------------------------------------------------
// Epilogue: z_pred + per-block loss/rmse partials (NO global atomics)
// lpart[blk*4 + {0:loss, 1..3: per-dim sq-err}]
// ---------------------------------------------------------------------------
__global__ void epilogue(const float* __restrict__ dec_out,
                         const float* __restrict__ zl,
                         const float* __restrict__ z_target,
                         const float* __restrict__ fin,
                         float* __restrict__ d_out,
                         float* __restrict__ lpart, int N){
  __shared__ float red[4][4];
  int tid = threadIdx.x, w = tid >> 6, l = tid & 63;
  int n = blockIdx.x * blockDim.x + tid;
  float s[4] = {0.f,0.f,0.f,0.f};
  if (n < N){
#pragma unroll
    for (int d = 0; d < 3; d++){
      float om = fin[12 + d], os = fin[15 + d];
      float o   = dec_out[3*n + d];
      float zld = zl[3*n + d];
      float zt  = z_target[3*n + d];
      float tgt = zt - zld;
      float tn  = (tgt - om) / os;
      float diff = tn - o;
      s[0] += diff * diff;
      float zp = zld + o * os + om;
      d_out[3*n + d] = zp;
      float e = zp - zt;
      s[1 + d] = e * e;
    }
  }
#pragma unroll
  for (int k = 0; k < 4; k++) s[k] = wave_sum(s[k]);
  if (l == 0)
#pragma unroll
    for (int k = 0; k < 4; k++) red[w][k] = s[k];
  __syncthreads();
  if (tid < 4)
    lpart[(size_t)blockIdx.x * 4 + tid] =
      red[0][tid] + red[1][tid] + red[2][tid] + red[3][tid];
}

__global__ void finalize_out(const float* __restrict__ lpart, int nb,
                             float* __restrict__ d_out, int N){
  __shared__ float red[4];
  __shared__ float vals[4];
  int tid = threadIdx.x, w = tid >> 6, l = tid & 63;
  for (int j = 0; j < 4; j++){
    float s = 0.f;
    for (int b = tid; b < nb; b += 256) s += lpart[(size_t)b * 4 + j];
    s = wave_sum(s);
    if (l == 0) red[w] = s;
    __syncthreads();
    if (tid == 0) vals[j] = red[0] + red[1] + red[2] + red[3];
    __syncthreads();
  }
  if (tid == 0){
    float cN = (float)N;
    float loss = vals[0] / (3.f * cN);
    float rmse = (sqrtf(vals[1] / cN) + sqrtf(vals[2] / cN) + sqrtf(vals[3] / cN)) / 3.f;
    d_out[(size_t)3 * N]     = loss;
    d_out[(size_t)3 * N + 1] = rmse;
  }
}

// ---------------------------------------------------------------------------
extern "C" void kernel_launch(void* const* d_in, const int* in_sizes, int n_in,
                              void* d_out, int out_size, void* d_ws, size_t ws_size,
                              hipStream_t stream){
  const float* z           = (const float*)d_in[0];
  const float* z_target    = (const float*)d_in[1];
  const float* pos         = (const float*)d_in[2];
  const float* enc_node_W1 = (const float*)d_in[3];
  const float* enc_node_b1 = (const float*)d_in[4];
  const float* enc_node_W2 = (const float*)d_in[5];
  const float* enc_node_b2 = (const float*)d_in[6];
  const float* enc_edge_W1 = (const float*)d_in[7];
  const float* enc_edge_b1 = (const float*)d_in[8];
  const float* enc_edge_W2 = (const float*)d_in[9];
  const float* enc_edge_b2 = (const float*)d_in[10];
  const float* dec_W1      = (const float*)d_in[11];
  const float* dec_b1      = (const float*)d_in[12];
  const float* dec_W2      = (const float*)d_in[13];
  const float* dec_b2      = (const float*)d_in[14];
  const float* blk_edge_W1 = (const float*)d_in[15];
  const float* blk_edge_b1 = (const float*)d_in[16];
  const float* blk_edge_W2 = (const float*)d_in[17];
  const float* blk_edge_b2 = (const float*)d_in[18];
  const float* blk_node_W1 = (const float*)d_in[19];
  const float* blk_node_b1 = (const float*)d_in[20];
  const float* blk_node_W2 = (const float*)d_in[21];
  const float* blk_node_b2 = (const float*)d_in[22];
  const int*   senders     = (const int*)d_in[23];
  const int*   receivers   = (const int*)d_in[24];

  const int N = in_sizes[1] / 3;
  const int E = in_sizes[23];
  const float* zl = z + (size_t)N * 3;

  const int neb = ceil_div(E, TPB);   // edge-stat blocks
  const int nnb = ceil_div(N, TPB);   // node-stat blocks

  char* p = (char*)d_ws;
  auto carve = [&](size_t bytes) -> char* {
    char* r = p; p += (bytes + 255) & ~(size_t)255; return r;
  };
  float* stats_raw = (float*)carve(32 * 4);
  float* stats_fin = (float*)carve(32 * 4);
  float* epart     = (float*)carve((size_t)neb * 6 * 4);
  float* npart     = (float*)carve((size_t)nnb * 12 * 4);
  float* lpart     = (float*)carve((size_t)nnb * 4 * 4);
  float* ef_raw    = (float*)carve((size_t)E * 3 * 4);
  float* dec_out   = (float*)carve((size_t)N * 3 * 4);
  float* hbuf      = (float*)carve((size_t)N * HDIM * 4);
  int*   deg       = (int*)carve((size_t)N * 4);
  int*   row_start = (int*)carve((size_t)(N + 1) * 4);
  int*   cursor    = (int*)carve((size_t)N * 4);
  int*   eids      = (int*)carve((size_t)E * 4);
  __hip_bfloat16* wp = (__hip_bfloat16*)carve((size_t)507904 * 2);
  __hip_bfloat16* ef = (__hip_bfloat16*)carve((size_t)E * HDIM * 2);
  __hip_bfloat16* nf = (__hip_bfloat16*)carve((size_t)N * HDIM * 2);

  float* out = (float*)d_out;

  hipMemsetAsync(deg, 0, (size_t)N * 4, stream);

  edge_raw_stats<<<neb, TPB, 0, stream>>>(pos, senders, receivers, ef_raw, epart, E);
  node_stats<<<nnb, TPB, 0, stream>>>(zl, z_target, npart, N);
  reduce_stats<<<1, TPB, 0, stream>>>(epart, neb, npart, nnb, stats_raw);
  finalize_stats<<<1, 1, 0, stream>>>(stats_raw, stats_fin, E, N);

  // CSR build (receivers constant across blocks)
  csr_hist<<<neb, TPB, 0, stream>>>(receivers, deg, E);
  csr_scan<<<1, 1024, 0, stream>>>(deg, row_start, N, E);
  hipMemcpyAsync(cursor, row_start, (size_t)N * 4, hipMemcpyDeviceToDevice, stream);
  csr_scatter<<<neb, TPB, 0, stream>>>(receivers, cursor, eids, E);

  pack_weights<<<dim3(192, 19), TPB, 0, stream>>>(enc_edge_W2, enc_node_W2, dec_W1,
                                                  blk_edge_W1, blk_edge_W2,
                                                  blk_node_W1, blk_node_W2, wp);

  // encoders (hidden layer fused)
  encoder_fused<<<ceil_div(E, 64), TPB, 0, stream>>>(ef_raw, stats_fin + 0, stats_fin + 3,
                                                     enc_edge_W1, enc_edge_b1,
                                                     wp, enc_edge_b2, ef, E);
  encoder_fused<<<ceil_div(N, 64), TPB, 0, stream>>>(zl, stats_fin + 6, stats_fin + 9,
                                                     enc_node_W1, enc_node_b1,
                                                     wp + 16384, enc_node_b2, nf, N);

  // message-passing blocks
  for (int b = 0; b < 4; b++){
    const __hip_bfloat16* eWf = wp + 49152 + (size_t)b * 114688;          // eW1|eW2
    const __hip_bfloat16* nWf = eWf + 65536;                              // nW1|nW2
    const float* eb1 = blk_edge_b1 + (size_t)b * 128;
    const float* eb2 = blk_edge_b2 + (size_t)b * 128;
    const float* nb1 = blk_node_b1 + (size_t)b * 128;
    const float* nb2 = blk_node_b2 + (size_t)b * 128;

    edge_block<<<ceil_div(E, 64), TPB, 0, stream>>>(senders, receivers, nf, ef,
                                                    eWf, eb1, eb2, E);
    node_block<<<ceil_div(N, 64), TPB, 0, stream>>>(row_start, eids, ef, nf,
                                                    nWf, nb1, nb2, N);
  }

  // decoder
  gemm128_g<<<ceil_div(N, 64), TPB, 0, stream>>>(nf, wp + 32768, dec_b1, hbuf, N);
  dec_final<<<ceil_div(N, 64), TPB, 0, stream>>>(hbuf, dec_W2, dec_b2, dec_out, N);

  epilogue<<<nnb, TPB, 0, stream>>>(dec_out, zl, z_target, stats_fin,
                                    out, lpart, N);
  finalize_out<<<1, TPB, 0, stream>>>(lpart, nnb, out, N);
}

// Round 6
// 602.655 us; speedup vs baseline: 6.3017x; 1.0551x over previous
//
#include <hip/hip_runtime.h>
#include <hip/hip_bf16.h>
#include <math.h>

#define HDIM 128
#define TPB 256

typedef __attribute__((ext_vector_type(8))) short bf16x8;
typedef __attribute__((ext_vector_type(4))) float f32x4;

static inline int ceil_div(int a, int b){ return (a + b - 1) / b; }

__device__ __forceinline__ float wave_sum(float v){
#pragma unroll
  for (int o = 32; o > 0; o >>= 1) v += __shfl_down(v, o, 64);
  return v;
}

__device__ __forceinline__ short f2bf(float f){
  __hip_bfloat16 h = __float2bfloat16(f);
  return *reinterpret_cast<short*>(&h);
}
__device__ __forceinline__ float bfb2f(short s){
  unsigned int u = ((unsigned int)(unsigned short)s) << 16;
  return __builtin_bit_cast(float, u);
}

// async global->LDS, 16B per lane; LDS dest = wave-uniform base + lane*16
__device__ __forceinline__ void gl_lds16(const short* g, short* l){
  __builtin_amdgcn_global_load_lds(
      (const __attribute__((address_space(1))) void*)g,
      (__attribute__((address_space(3))) void*)l, 16, 0, 0);
}

// ---------------------------------------------------------------------------
// 1. Edge raw features + per-block partial sums (no global atomics)
// ---------------------------------------------------------------------------
__global__ void edge_raw_stats(const float* __restrict__ pos,
                               const int* __restrict__ snd,
                               const int* __restrict__ rcv,
                               float* __restrict__ ef_raw,
                               float* __restrict__ epart, int E){
  __shared__ float red[4][6];
  int tid = threadIdx.x, w = tid >> 6, l = tid & 63;
  int e = blockIdx.x * blockDim.x + tid;
  float s[6] = {0.f,0.f,0.f,0.f,0.f,0.f};
  if (e < E){
    int si = snd[e], ri = rcv[e];
    float rx = pos[2*si]   - pos[2*ri];
    float ry = pos[2*si+1] - pos[2*ri+1];
    float nm = sqrtf(rx*rx + ry*ry);
    ef_raw[3*e]   = rx;
    ef_raw[3*e+1] = ry;
    ef_raw[3*e+2] = nm;
    s[0] = rx; s[1] = ry; s[2] = nm;
    s[3] = rx*rx; s[4] = ry*ry; s[5] = nm*nm;
  }
#pragma unroll
  for (int k = 0; k < 6; k++) s[k] = wave_sum(s[k]);
  if (l == 0)
#pragma unroll
    for (int k = 0; k < 6; k++) red[w][k] = s[k];
  __syncthreads();
  if (tid < 6)
    epart[(size_t)blockIdx.x * 6 + tid] =
      red[0][tid] + red[1][tid] + red[2][tid] + red[3][tid];
}

// ---------------------------------------------------------------------------
// 2. Node stats partials
// ---------------------------------------------------------------------------
__global__ void node_stats(const float* __restrict__ zl,
                           const float* __restrict__ z_target,
                           float* __restrict__ npart, int N){
  __shared__ float red[4][12];
  int tid = threadIdx.x, w = tid >> 6, l = tid & 63;
  int n = blockIdx.x * blockDim.x + tid;
  float s[12];
#pragma unroll
  for (int i = 0; i < 12; i++) s[i] = 0.f;
  if (n < N){
#pragma unroll
    for (int d = 0; d < 3; d++){
      float z = zl[3*n+d];
      float t = z_target[3*n+d] - z;
      s[d]   = z;  s[3+d] = z*z;
      s[6+d] = t;  s[9+d] = t*t;
    }
  }
#pragma unroll
  for (int i = 0; i < 12; i++) s[i] = wave_sum(s[i]);
  if (l == 0)
#pragma unroll
    for (int i = 0; i < 12; i++) red[w][i] = s[i];
  __syncthreads();
  if (tid < 12)
    npart[(size_t)blockIdx.x * 12 + tid] =
      red[0][tid] + red[1][tid] + red[2][tid] + red[3][tid];
}

// ---------------------------------------------------------------------------
// 3. Reduce partials -> raw[0..5] edge, raw[6..17] node
// ---------------------------------------------------------------------------
__global__ void reduce_stats(const float* __restrict__ ep, int ne,
                             const float* __restrict__ np_, int nn,
                             float* __restrict__ raw){
  __shared__ float red[4];
  int tid = threadIdx.x, w = tid >> 6, l = tid & 63;
  for (int j = 0; j < 6; j++){
    float s = 0.f;
    for (int b = tid; b < ne; b += 256) s += ep[(size_t)b * 6 + j];
    s = wave_sum(s);
    if (l == 0) red[w] = s;
    __syncthreads();
    if (tid == 0) raw[j] = red[0] + red[1] + red[2] + red[3];
    __syncthreads();
  }
  for (int j = 0; j < 12; j++){
    float s = 0.f;
    for (int b = tid; b < nn; b += 256) s += np_[(size_t)b * 12 + j];
    s = wave_sum(s);
    if (l == 0) red[w] = s;
    __syncthreads();
    if (tid == 0) raw[6 + j] = red[0] + red[1] + red[2] + red[3];
    __syncthreads();
  }
}

// stats_fin: em[0..2] es[3..5] nm[6..8] ns[9..11] om[12..14] os[15..17]
__global__ void finalize_stats(const float* __restrict__ raw,
                               float* __restrict__ fin, int E, int N){
#pragma unroll
  for (int d = 0; d < 3; d++){
    float cE = (float)E, cN = (float)N;
    float m, v;
    m = raw[0+d] / cE; v = fmaxf(raw[3+d]/cE - m*m, 0.f);
    fin[0+d] = m;  fin[3+d]  = fmaxf(sqrtf(v), 1e-8f);
    m = raw[6+d] / cN; v = fmaxf(raw[9+d]/cN - m*m, 0.f);
    fin[6+d] = m;  fin[9+d]  = fmaxf(sqrtf(v), 1e-8f);
    m = raw[12+d] / cN; v = fmaxf(raw[15+d]/cN - m*m, 0.f);
    fin[12+d] = m; fin[15+d] = fmaxf(sqrtf(v), 1e-8f);
  }
}

// ---------------------------------------------------------------------------
// CSR build for receivers
// ---------------------------------------------------------------------------
__global__ void csr_hist(const int* __restrict__ rcv, int* __restrict__ deg, int E){
  int e = blockIdx.x * blockDim.x + threadIdx.x;
  if (e < E) atomicAdd(&deg[rcv[e]], 1);
}

__global__ void csr_scan(const int* __restrict__ deg, int* __restrict__ row_start,
                         int N, int E){
  __shared__ int part[1024];
  int t = threadIdx.x;
  int chunk = (N + 1023) / 1024;
  int lo = t * chunk, hi = min(lo + chunk, N);
  int s = 0;
  for (int i = lo; i < hi; i++) s += deg[i];
  part[t] = s;
  __syncthreads();
  for (int off = 1; off < 1024; off <<= 1){
    int v = (t >= off) ? part[t - off] : 0;
    __syncthreads();
    part[t] += v;
    __syncthreads();
  }
  int base = (t == 0) ? 0 : part[t - 1];
  for (int i = lo; i < hi; i++){
    row_start[i] = base;
    base += deg[i];
  }
  if (t == 1023) row_start[N] = E;
}

__global__ void csr_scatter(const int* __restrict__ rcv, int* __restrict__ cursor,
                            int* __restrict__ eids, int E){
  int e = blockIdx.x * blockDim.x + threadIdx.x;
  if (e < E){
    int p = atomicAdd(&cursor[rcv[e]], 1);
    eids[p] = e;
  }
}

// ---------------------------------------------------------------------------
// Weight packing: fp32 [K][128] -> bf16 fragment-major (1KB per B-fragment)
// wp: 0 enc_edge_W2 | 16384 enc_node_W2 | 32768 dec_W1
//     49152 + b*114688: eW1(49152)|eW2(16384)|nW1(32768)|nW2(16384)
// ---------------------------------------------------------------------------
__global__ void pack_weights(const float* __restrict__ encEW2,
                             const float* __restrict__ encNW2,
                             const float* __restrict__ decW1,
                             const float* __restrict__ beW1,
                             const float* __restrict__ beW2,
                             const float* __restrict__ bnW1,
                             const float* __restrict__ bnW2,
                             __hip_bfloat16* __restrict__ wp){
  int y = blockIdx.y;
  const float* src; __hip_bfloat16* dst; int K;
  if (y == 0){ src = encEW2; dst = wp;          K = 128; }
  else if (y == 1){ src = encNW2; dst = wp + 16384; K = 128; }
  else if (y == 2){ src = decW1;  dst = wp + 32768; K = 128; }
  else {
    int b = (y - 3) >> 2, j = (y - 3) & 3;
    __hip_bfloat16* base = wp + 49152 + b * 114688;
    if (j == 0){ src = beW1 + b*49152; dst = base;          K = 384; }
    else if (j == 1){ src = beW2 + b*16384; dst = base + 49152; K = 128; }
    else if (j == 2){ src = bnW1 + b*32768; dst = base + 65536; K = 256; }
    else { src = bnW2 + b*16384; dst = base + 98304; K = 128; }
  }
  int id = blockIdx.x * blockDim.x + threadIdx.x;
  if (id >= 128 * K) return;
  int c = id >> 12;
  int r = id & 4095;
  int t = r >> 9;
  int l = (r >> 3) & 63;
  int j = r & 7;
  int k = c * 32 + ((l >> 4) << 3) + j;
  int n = t * 16 + (l & 15);
  dst[id] = __float2bfloat16(src[k * 128 + n]);
}

// ---------------------------------------------------------------------------
// Fused encoder: out = (relu(norm(raw3)@W1+b1)) @ W2 + b2
// W2 (32KB) staged once into LDS, shared by the block.
// ---------------------------------------------------------------------------
__launch_bounds__(256)
__global__ void encoder_fused(const float* __restrict__ raw,
                              const float* __restrict__ mptr,
                              const float* __restrict__ sptr,
                              const float* __restrict__ W1,   // [3][128] f32
                              const float* __restrict__ b1,
                              const __hip_bfloat16* __restrict__ W2f, // frag-major
                              const float* __restrict__ b2,
                              __hip_bfloat16* __restrict__ out, int rows){
  __shared__ __align__(16) short bsh[16384];   // 32 KB
  const int tid = threadIdx.x, w = tid >> 6, l = tid & 63, m = l & 15, q = l >> 4;
  const short* wsrc = (const short*)W2f;
#pragma unroll
  for (int i = 0; i < 8; i++){
    int inst = w * 8 + i;
    gl_lds16(wsrc + inst * 512 + l * 8, &bsh[inst * 512]);
  }

  float s0 = mptr[0], s1 = mptr[1], s2 = mptr[2];
  float d0 = sptr[0], d1 = sptr[1], d2 = sptr[2];
  const int row0 = blockIdx.x * 64 + w * 16;
  const int ra = min(row0 + m, rows - 1);
  float x0 = (raw[3*ra]   - s0) / d0;
  float x1 = (raw[3*ra+1] - s1) / d1;
  float x2 = (raw[3*ra+2] - s2) / d2;
  bf16x8 afr[4];
#pragma unroll
  for (int c = 0; c < 4; c++){
    int nb = c * 32 + q * 8;
#pragma unroll
    for (int j = 0; j < 8; j++){
      float h = b1[nb+j] + x0 * W1[nb+j] + x1 * W1[128+nb+j] + x2 * W1[256+nb+j];
      afr[c][j] = f2bf(fmaxf(h, 0.f));
    }
  }
  f32x4 acc[8];
#pragma unroll
  for (int t = 0; t < 8; t++) acc[t] = (f32x4){0.f,0.f,0.f,0.f};
  __syncthreads();   // staging drained (compiler emits vmcnt(0) before barrier)
#pragma unroll
  for (int c = 0; c < 4; c++){
#pragma unroll
    for (int t = 0; t < 8; t++){
      bf16x8 b = *(const bf16x8*)&bsh[(c*8 + t)*512 + l*8];
      acc[t] = __builtin_amdgcn_mfma_f32_16x16x32_bf16(afr[c], b, acc[t], 0, 0, 0);
    }
  }
  const int row_d = row0 + q * 4;
#pragma unroll
  for (int t = 0; t < 8; t++){
    int col = t * 16 + m;
    float bb = b2[col];
#pragma unroll
    for (int r = 0; r < 4; r++){
      int e = row_d + r;
      if (e < rows) out[(size_t)e * HDIM + col] = __float2bfloat16(acc[t][r] + bb);
    }
  }
}

// ---------------------------------------------------------------------------
// Decoder layer 1: out_f32 = relu(A_bf16 @ W + b); W staged once in LDS
// ---------------------------------------------------------------------------
__launch_bounds__(256)
__global__ void gemm128_g(const __hip_bfloat16* __restrict__ A,
                          const __hip_bfloat16* __restrict__ Wf,
                          const float* __restrict__ bias,
                          float* __restrict__ out, int rows){
  __shared__ __align__(16) short bsh[16384];
  const int tid = threadIdx.x, w = tid >> 6, l = tid & 63, m = l & 15, q = l >> 4;
  const short* wsrc = (const short*)Wf;
#pragma unroll
  for (int i = 0; i < 8; i++){
    int inst = w * 8 + i;
    gl_lds16(wsrc + inst * 512 + l * 8, &bsh[inst * 512]);
  }
  const int row0 = blockIdx.x * 64 + w * 16;
  const int ra = min(row0 + m, rows - 1);
  const short* pa = (const short*)A + (size_t)ra * HDIM + q * 8;
  bf16x8 afr[4];
#pragma unroll
  for (int c = 0; c < 4; c++) afr[c] = *(const bf16x8*)(pa + c * 32);
  f32x4 acc[8];
#pragma unroll
  for (int t = 0; t < 8; t++) acc[t] = (f32x4){0.f,0.f,0.f,0.f};
  __syncthreads();
#pragma unroll
  for (int c = 0; c < 4; c++){
#pragma unroll
    for (int t = 0; t < 8; t++){
      bf16x8 b = *(const bf16x8*)&bsh[(c*8 + t)*512 + l*8];
      acc[t] = __builtin_amdgcn_mfma_f32_16x16x32_bf16(afr[c], b, acc[t], 0, 0, 0);
    }
  }
  const int row_d = row0 + q * 4;
#pragma unroll
  for (int t = 0; t < 8; t++){
    int col = t * 16 + m;
    float bb = bias[col];
#pragma unroll
    for (int r = 0; r < 4; r++){
      int e = row_d + r;
      if (e < rows) out[(size_t)e * HDIM + col] = fmaxf(acc[t][r] + bb, 0.f);
    }
  }
}

// ---------------------------------------------------------------------------
// Edge block v5: ef += MLP([ef | nf[snd] | nf[rcv]])
// Weights (W1|W2 = 16 chunks x 8KB) double-buffer-staged into LDS via
// global_load_lds; one __syncthreads per chunk (drains vmcnt = stage wait).
// ---------------------------------------------------------------------------
__launch_bounds__(256)
__global__ void edge_block(const int* __restrict__ snd,
                           const int* __restrict__ rcv,
                           const __hip_bfloat16* __restrict__ nf,
                           __hip_bfloat16* __restrict__ ef,
                           const __hip_bfloat16* __restrict__ Wfrag, // eW1|eW2
                           const float* __restrict__ b1,
                           const float* __restrict__ b2,
                           int E){
  __shared__ __align__(16) short bsh[2][4096];   // 2 x 8 KB
  __shared__ __align__(16) short hsh[4][16][136];
  const int tid = threadIdx.x, w = tid >> 6, l = tid & 63, m = l & 15, q = l >> 4;
  const short* wsrc = (const short*)Wfrag;
  // stage chunk 0
  gl_lds16(wsrc + (w*2+0)*512 + l*8, &bsh[0][(w*2+0)*512]);
  gl_lds16(wsrc + (w*2+1)*512 + l*8, &bsh[0][(w*2+1)*512]);

  const int row0 = blockIdx.x * 64 + w * 16;
  const int ra = min(row0 + m, E - 1);
  const int si = snd[ra], ri = rcv[ra];
  const short* pe = (const short*)ef + (size_t)ra * HDIM + q * 8;
  const short* ps = (const short*)nf + (size_t)si * HDIM + q * 8;
  const short* pr = (const short*)nf + (size_t)ri * HDIM + q * 8;
  bf16x8 afr[12];
#pragma unroll
  for (int c = 0; c < 4; c++){
    afr[c]   = *(const bf16x8*)(pe + c * 32);
    afr[4+c] = *(const bf16x8*)(ps + c * 32);
    afr[8+c] = *(const bf16x8*)(pr + c * 32);
  }
  f32x4 acc[8];
#pragma unroll
  for (int t = 0; t < 8; t++) acc[t] = (f32x4){0.f,0.f,0.f,0.f};
  __syncthreads();   // chunk 0 ready
#pragma unroll
  for (int c = 0; c < 12; c++){
    {  // stage chunk c+1 into other buffer
      const short* src = wsrc + (c + 1) * 4096;
      short* dstb = &bsh[(c + 1) & 1][0];
      gl_lds16(src + (w*2+0)*512 + l*8, dstb + (w*2+0)*512);
      gl_lds16(src + (w*2+1)*512 + l*8, dstb + (w*2+1)*512);
    }
    const short* bb = &bsh[c & 1][0];
#pragma unroll
    for (int t = 0; t < 8; t++){
      bf16x8 b = *(const bf16x8*)(bb + t*512 + l*8);
      acc[t] = __builtin_amdgcn_mfma_f32_16x16x32_bf16(afr[c], b, acc[t], 0, 0, 0);
    }
    __syncthreads();
  }
  // h = relu(acc + b1) -> wave-private LDS tile
#pragma unroll
  for (int t = 0; t < 8; t++){
    float bb = b1[t * 16 + m];
#pragma unroll
    for (int r = 0; r < 4; r++)
      hsh[w][q*4 + r][t*16 + m] = f2bf(fmaxf(acc[t][r] + bb, 0.f));
  }
  const short* ph = &hsh[w][m][0] + q * 8;
  f32x4 acc2[8];
#pragma unroll
  for (int t = 0; t < 8; t++) acc2[t] = (f32x4){0.f,0.f,0.f,0.f};
#pragma unroll
  for (int c = 12; c < 16; c++){
    if (c + 1 < 16){
      const short* src = wsrc + (c + 1) * 4096;
      short* dstb = &bsh[(c + 1) & 1][0];
      gl_lds16(src + (w*2+0)*512 + l*8, dstb + (w*2+0)*512);
      gl_lds16(src + (w*2+1)*512 + l*8, dstb + (w*2+1)*512);
    }
    bf16x8 a = *(const bf16x8*)(ph + (c - 12) * 32);
    const short* bb = &bsh[c & 1][0];
#pragma unroll
    for (int t = 0; t < 8; t++){
      bf16x8 b = *(const bf16x8*)(bb + t*512 + l*8);
      acc2[t] = __builtin_amdgcn_mfma_f32_16x16x32_bf16(a, b, acc2[t], 0, 0, 0);
    }
    if (c < 15) __syncthreads();
  }
  // v = acc2 + b2 into hsh, then coalesced residual RMW
#pragma unroll
  for (int t = 0; t < 8; t++){
    float bb = b2[t * 16 + m];
#pragma unroll
    for (int r = 0; r < 4; r++)
      hsh[w][q*4 + r][t*16 + m] = f2bf(acc2[t][r] + bb);
  }
  int orow = row0 + (l >> 2);
  if (orow < E){
    const short* src = &hsh[w][l >> 2][(l & 3) * 32];
    short* dst = (short*)ef + (size_t)orow * HDIM + (l & 3) * 32;
#pragma unroll
    for (int k = 0; k < 4; k++){
      bf16x8 vnew = *(const bf16x8*)(src + k * 8);
      bf16x8 vold = *(const bf16x8*)(dst + k * 8);
      bf16x8 vo;
#pragma unroll
      for (int j = 0; j < 8; j++) vo[j] = f2bf(bfb2f(vnew[j]) + bfb2f(vold[j]));
      *(bf16x8*)(dst + k * 8) = vo;
    }
  }
}

// ---------------------------------------------------------------------------
// Node block v5: agg = CSR-gather-sum(ef); nf += MLP([nf | agg])
// Weights (nW1|nW2 = 12 chunks x 8KB) double-buffer staged as above.
// ---------------------------------------------------------------------------
__launch_bounds__(256)
__global__ void node_block(const int* __restrict__ row_start,
                           const int* __restrict__ eids,
                           const __hip_bfloat16* __restrict__ ef,
                           __hip_bfloat16* __restrict__ nf,
                           const __hip_bfloat16* __restrict__ Wfrag, // nW1|nW2
                           const float* __restrict__ b1,
                           const float* __restrict__ b2,
                           int N){
  __shared__ __align__(16) short bsh[2][4096];
  __shared__ __align__(16) short hsh[4][16][136];
  const int tid = threadIdx.x, w = tid >> 6, l = tid & 63, m = l & 15, q = l >> 4;
  const short* wsrc = (const short*)Wfrag;
  gl_lds16(wsrc + (w*2+0)*512 + l*8, &bsh[0][(w*2+0)*512]);
  gl_lds16(wsrc + (w*2+1)*512 + l*8, &bsh[0][(w*2+1)*512]);

  const int row0 = blockIdx.x * 64 + w * 16;
  const int ra = min(row0 + m, N - 1);
  const short* pn = (const short*)nf + (size_t)ra * HDIM + q * 8;
  bf16x8 afr[8];
#pragma unroll
  for (int c = 0; c < 4; c++) afr[c] = *(const bf16x8*)(pn + c * 32);
  float sum[4][8];
#pragma unroll
  for (int c = 0; c < 4; c++)
#pragma unroll
    for (int j = 0; j < 8; j++) sum[c][j] = 0.f;
  int s0 = row_start[ra], s1 = row_start[ra + 1];
  for (int it = s0; it < s1; it++){
    int eid = eids[it];
    const short* pf = (const short*)ef + (size_t)eid * HDIM + q * 8;
#pragma unroll
    for (int c = 0; c < 4; c++){
      bf16x8 v = *(const bf16x8*)(pf + c * 32);
#pragma unroll
      for (int j = 0; j < 8; j++) sum[c][j] += bfb2f(v[j]);
    }
  }
#pragma unroll
  for (int c = 0; c < 4; c++)
#pragma unroll
    for (int j = 0; j < 8; j++) afr[4 + c][j] = f2bf(sum[c][j]);

  f32x4 acc[8];
#pragma unroll
  for (int t = 0; t < 8; t++) acc[t] = (f32x4){0.f,0.f,0.f,0.f};
  __syncthreads();   // chunk 0 ready (also drains gather loads)
#pragma unroll
  for (int c = 0; c < 8; c++){
    {
      const short* src = wsrc + (c + 1) * 4096;
      short* dstb = &bsh[(c + 1) & 1][0];
      gl_lds16(src + (w*2+0)*512 + l*8, dstb + (w*2+0)*512);
      gl_lds16(src + (w*2+1)*512 + l*8, dstb + (w*2+1)*512);
    }
    const short* bb = &bsh[c & 1][0];
#pragma unroll
    for (int t = 0; t < 8; t++){
      bf16x8 b = *(const bf16x8*)(bb + t*512 + l*8);
      acc[t] = __builtin_amdgcn_mfma_f32_16x16x32_bf16(afr[c], b, acc[t], 0, 0, 0);
    }
    __syncthreads();
  }
#pragma unroll
  for (int t = 0; t < 8; t++){
    float bb = b1[t * 16 + m];
#pragma unroll
    for (int r = 0; r < 4; r++)
      hsh[w][q*4 + r][t*16 + m] = f2bf(fmaxf(acc[t][r] + bb, 0.f));
  }
  const short* ph = &hsh[w][m][0] + q * 8;
  f32x4 acc2[8];
#pragma unroll
  for (int t = 0; t < 8; t++) acc2[t] = (f32x4){0.f,0.f,0.f,0.f};
#pragma unroll
  for (int c = 8; c < 12; c++){
    if (c + 1 < 12){
      const short* src = wsrc + (c + 1) * 4096;
      short* dstb = &bsh[(c + 1) & 1][0];
      gl_lds16(src + (w*2+0)*512 + l*8, dstb + (w*2+0)*512);
      gl_lds16(src + (w*2+1)*512 + l*8, dstb + (w*2+1)*512);
    }
    bf16x8 a = *(const bf16x8*)(ph + (c - 8) * 32);
    const short* bb = &bsh[c & 1][0];
#pragma unroll
    for (int t = 0; t < 8; t++){
      bf16x8 b = *(const bf16x8*)(bb + t*512 + l*8);
      acc2[t] = __builtin_amdgcn_mfma_f32_16x16x32_bf16(a, b, acc2[t], 0, 0, 0);
    }
    if (c < 11) __syncthreads();
  }
#pragma unroll
  for (int t = 0; t < 8; t++){
    float bb = b2[t * 16 + m];
#pragma unroll
    for (int r = 0; r < 4; r++)
      hsh[w][q*4 + r][t*16 + m] = f2bf(acc2[t][r] + bb);
  }
  int orow = row0 + (l >> 2);
  if (orow < N){
    const short* src = &hsh[w][l >> 2][(l & 3) * 32];
    short* dst = (short*)nf + (size_t)orow * HDIM + (l & 3) * 32;
#pragma unroll
    for (int k = 0; k < 4; k++){
      bf16x8 vnew = *(const bf16x8*)(src + k * 8);
      bf16x8 vold = *(const bf16x8*)(dst + k * 8);
      bf16x8 vo;
#pragma unroll
      for (int j = 0; j < 8; j++) vo[j] = f2bf(bfb2f(vnew[j]) + bfb2f(vold[j]));
      *(bf16x8*)(dst + k * 8) = vo;
    }
  }
}

// ---------------------------------------------------------------------------
// Decoder final layer: [rows,128] fp32 @ [128,3] + b
// ---------------------------------------------------------------------------
__global__ void dec_final(const float* __restrict__ hbuf,
                          const float* __restrict__ W2,
                          const float* __restrict__ b2,
                          float* __restrict__ outd, int rows){
  __shared__ float hl[64 * 129];
  __shared__ float Wl[HDIM * 3];
  __shared__ float bl[3];
  int t = threadIdx.x;
  int node0 = blockIdx.x * 64;
  for (int i = t; i < HDIM * 3; i += 256) Wl[i] = W2[i];
  if (t < 3) bl[t] = b2[t];
#pragma unroll
  for (int i = 0; i < 32; i++){
    int lin = t + i * 256;
    int r = lin >> 7;
    int c = lin & 127;
    int node = node0 + r;
    hl[r * 129 + c] = (node < rows) ? hbuf[(size_t)node * HDIM + c] : 0.f;
  }
  __syncthreads();
  if (t < 64){
    int node = node0 + t;
    if (node < rows){
      float a0 = bl[0], a1 = bl[1], a2 = bl[2];
      for (int k = 0; k < HDIM; k++){
        float v = hl[t * 129 + k];
        a0 += v * Wl[k * 3];
        a1 += v * Wl[k * 3 + 1];
        a2 += v * Wl[k * 3 + 2];
      }
      outd[3 * node]     = a0;
      outd[3 * node + 1] = a1;
      outd[3 * node + 2] = a2;
    }
  }
}

// ---------------------------------------------------------------------------
// Epilogue + finalize (partials, no atomics)
// ---------------------------------------------------------------------------
__global__ void epilogue(const float* __restrict__ dec_out,
                         const float* __restrict__ zl,
                         const float* __restrict__ z_target,
                         const float* __restrict__ fin,
                         float* __restrict__ d_out,
                         float* __restrict__ lpart, int N){
  __shared__ float red[4][4];
  int tid = threadIdx.x, w = tid >> 6, l = tid & 63;
  int n = blockIdx.x * blockDim.x + tid;
  float s[4] = {0.f,0.f,0.f,0.f};
  if (n < N){
#pragma unroll
    for (int d = 0; d < 3; d++){
      float om = fin[12 + d], os = fin[15 + d];
      float o   = dec_out[3*n + d];
      float zld = zl[3*n + d];
      float zt  = z_target[3*n + d];
      float tgt = zt - zld;
      float tn  = (tgt - om) / os;
      float diff = tn - o;
      s[0] += diff * diff;
      float zp = zld + o * os + om;
      d_out[3*n + d] = zp;
      float e = zp - zt;
      s[1 + d] = e * e;
    }
  }
#pragma unroll
  for (int k = 0; k < 4; k++) s[k] = wave_sum(s[k]);
  if (l == 0)
#pragma unroll
    for (int k = 0; k < 4; k++) red[w][k] = s[k];
  __syncthreads();
  if (tid < 4)
    lpart[(size_t)blockIdx.x * 4 + tid] =
      red[0][tid] + red[1][tid] + red[2][tid] + red[3][tid];
}

__global__ void finalize_out(const float* __restrict__ lpart, int nb,
                             float* __restrict__ d_out, int N){
  __shared__ float red[4];
  __shared__ float vals[4];
  int tid = threadIdx.x, w = tid >> 6, l = tid & 63;
  for (int j = 0; j < 4; j++){
    float s = 0.f;
    for (int b = tid; b < nb; b += 256) s += lpart[(size_t)b * 4 + j];
    s = wave_sum(s);
    if (l == 0) red[w] = s;
    __syncthreads();
    if (tid == 0) vals[j] = red[0] + red[1] + red[2] + red[3];
    __syncthreads();
  }
  if (tid == 0){
    float cN = (float)N;
    float loss = vals[0] / (3.f * cN);
    float rmse = (sqrtf(vals[1] / cN) + sqrtf(vals[2] / cN) + sqrtf(vals[3] / cN)) / 3.f;
    d_out[(size_t)3 * N]     = loss;
    d_out[(size_t)3 * N + 1] = rmse;
  }
}

// ---------------------------------------------------------------------------
extern "C" void kernel_launch(void* const* d_in, const int* in_sizes, int n_in,
                              void* d_out, int out_size, void* d_ws, size_t ws_size,
                              hipStream_t stream){
  const float* z           = (const float*)d_in[0];
  const float* z_target    = (const float*)d_in[1];
  const float* pos         = (const float*)d_in[2];
  const float* enc_node_W1 = (const float*)d_in[3];
  const float* enc_node_b1 = (const float*)d_in[4];
  const float* enc_node_W2 = (const float*)d_in[5];
  const float* enc_node_b2 = (const float*)d_in[6];
  const float* enc_edge_W1 = (const float*)d_in[7];
  const float* enc_edge_b1 = (const float*)d_in[8];
  const float* enc_edge_W2 = (const float*)d_in[9];
  const float* enc_edge_b2 = (const float*)d_in[10];
  const float* dec_W1      = (const float*)d_in[11];
  const float* dec_b1      = (const float*)d_in[12];
  const float* dec_W2      = (const float*)d_in[13];
  const float* dec_b2      = (const float*)d_in[14];
  const float* blk_edge_W1 = (const float*)d_in[15];
  const float* blk_edge_b1 = (const float*)d_in[16];
  const float* blk_edge_W2 = (const float*)d_in[17];
  const float* blk_edge_b2 = (const float*)d_in[18];
  const float* blk_node_W1 = (const float*)d_in[19];
  const float* blk_node_b1 = (const float*)d_in[20];
  const float* blk_node_W2 = (const float*)d_in[21];
  const float* blk_node_b2 = (const float*)d_in[22];
  const int*   senders     = (const int*)d_in[23];
  const int*   receivers   = (const int*)d_in[24];

  const int N = in_sizes[1] / 3;
  const int E = in_sizes[23];
  const float* zl = z + (size_t)N * 3;

  const int neb = ceil_div(E, TPB);
  const int nnb = ceil_div(N, TPB);

  char* p = (char*)d_ws;
  auto carve = [&](size_t bytes) -> char* {
    char* r = p; p += (bytes + 255) & ~(size_t)255; return r;
  };
  float* stats_raw = (float*)carve(32 * 4);
  float* stats_fin = (float*)carve(32 * 4);
  float* epart     = (float*)carve((size_t)neb * 6 * 4);
  float* npart     = (float*)carve((size_t)nnb * 12 * 4);
  float* lpart     = (float*)carve((size_t)nnb * 4 * 4);
  float* ef_raw    = (float*)carve((size_t)E * 3 * 4);
  float* dec_out   = (float*)carve((size_t)N * 3 * 4);
  float* hbuf      = (float*)carve((size_t)N * HDIM * 4);
  int*   deg       = (int*)carve((size_t)N * 4);
  int*   row_start = (int*)carve((size_t)(N + 1) * 4);
  int*   cursor    = (int*)carve((size_t)N * 4);
  int*   eids      = (int*)carve((size_t)E * 4);
  __hip_bfloat16* wp = (__hip_bfloat16*)carve((size_t)507904 * 2);
  __hip_bfloat16* ef = (__hip_bfloat16*)carve((size_t)E * HDIM * 2);
  __hip_bfloat16* nf = (__hip_bfloat16*)carve((size_t)N * HDIM * 2);

  float* out = (float*)d_out;

  hipMemsetAsync(deg, 0, (size_t)N * 4, stream);

  edge_raw_stats<<<neb, TPB, 0, stream>>>(pos, senders, receivers, ef_raw, epart, E);
  node_stats<<<nnb, TPB, 0, stream>>>(zl, z_target, npart, N);
  reduce_stats<<<1, TPB, 0, stream>>>(epart, neb, npart, nnb, stats_raw);
  finalize_stats<<<1, 1, 0, stream>>>(stats_raw, stats_fin, E, N);

  csr_hist<<<neb, TPB, 0, stream>>>(receivers, deg, E);
  csr_scan<<<1, 1024, 0, stream>>>(deg, row_start, N, E);
  hipMemcpyAsync(cursor, row_start, (size_t)N * 4, hipMemcpyDeviceToDevice, stream);
  csr_scatter<<<neb, TPB, 0, stream>>>(receivers, cursor, eids, E);

  pack_weights<<<dim3(192, 19), TPB, 0, stream>>>(enc_edge_W2, enc_node_W2, dec_W1,
                                                  blk_edge_W1, blk_edge_W2,
                                                  blk_node_W1, blk_node_W2, wp);

  encoder_fused<<<ceil_div(E, 64), TPB, 0, stream>>>(ef_raw, stats_fin + 0, stats_fin + 3,
                                                     enc_edge_W1, enc_edge_b1,
                                                     wp, enc_edge_b2, ef, E);
  encoder_fused<<<ceil_div(N, 64), TPB, 0, stream>>>(zl, stats_fin + 6, stats_fin + 9,
                                                     enc_node_W1, enc_node_b1,
                                                     wp + 16384, enc_node_b2, nf, N);

  for (int b = 0; b < 4; b++){
    const __hip_bfloat16* eWf = wp + 49152 + (size_t)b * 114688;   // eW1|eW2 (16 chunks)
    const __hip_bfloat16* nWf = eWf + 65536;                       // nW1|nW2 (12 chunks)
    const float* eb1 = blk_edge_b1 + (size_t)b * 128;
    const float* eb2 = blk_edge_b2 + (size_t)b * 128;
    const float* nb1 = blk_node_b1 + (size_t)b * 128;
    const float* nb2 = blk_node_b2 + (size_t)b * 128;

    edge_block<<<ceil_div(E, 64), TPB, 0, stream>>>(senders, receivers, nf, ef,
                                                    eWf, eb1, eb2, E);
    node_block<<<ceil_div(N, 64), TPB, 0, stream>>>(row_start, eids, ef, nf,
                                                    nWf, nb1, nb2, N);
  }

  gemm128_g<<<ceil_div(N, 64), TPB, 0, stream>>>(nf, wp + 32768, dec_b1, hbuf, N);
  dec_final<<<ceil_div(N, 64), TPB, 0, stream>>>(hbuf, dec_W2, dec_b2, dec_out, N);

  epilogue<<<nnb, TPB, 0, stream>>>(dec_out, zl, z_target, stats_fin,
                                    out, lpart, N);
  finalize_out<<<1, TPB, 0, stream>>>(lpart, nnb, out, N);
}

// Round 7
// 573.803 us; speedup vs baseline: 6.6186x; 1.0503x over previous
//
#include <hip/hip_runtime.h>
#include <hip/hip_bf16.h>
#include <math.h>

#define HDIM 128
#define TPB 256

typedef __attribute__((ext_vector_type(8))) short bf16x8;
typedef __attribute__((ext_vector_type(4))) float f32x4;

static inline int ceil_div(int a, int b){ return (a + b - 1) / b; }

__device__ __forceinline__ float wave_sum(float v){
#pragma unroll
  for (int o = 32; o > 0; o >>= 1) v += __shfl_down(v, o, 64);
  return v;
}

__device__ __forceinline__ short f2bf(float f){
  __hip_bfloat16 h = __float2bfloat16(f);
  return *reinterpret_cast<short*>(&h);
}
__device__ __forceinline__ float bfb2f(short s){
  unsigned int u = ((unsigned int)(unsigned short)s) << 16;
  return __builtin_bit_cast(float, u);
}

// async global->LDS: 64 lanes x 16B; LDS dest is wave-uniform base (+lane*16 by HW)
__device__ __forceinline__ void gl_lds16(const short* g, short* l){
  __builtin_amdgcn_global_load_lds(
      (const __attribute__((address_space(1))) void*)g,
      (__attribute__((address_space(3))) void*)l, 16, 0, 0);
}

// ---------------------------------------------------------------------------
// CSR build for receivers + permutation arrays.
// ef lives in RECEIVER-SORTED (permuted) order: position p holds edge eids[p].
// pinv[e] = p, psnd[p]=snd[e], prcv[p]=rcv[e].
// ---------------------------------------------------------------------------
__global__ void csr_hist(const int* __restrict__ rcv, int* __restrict__ deg, int E){
  int e = blockIdx.x * blockDim.x + threadIdx.x;
  if (e < E) atomicAdd(&deg[rcv[e]], 1);
}

__global__ void csr_scan(const int* __restrict__ deg, int* __restrict__ row_start,
                         int N, int E){
  __shared__ int part[1024];
  int t = threadIdx.x;
  int chunk = (N + 1023) / 1024;
  int lo = t * chunk, hi = min(lo + chunk, N);
  int s = 0;
  for (int i = lo; i < hi; i++) s += deg[i];
  part[t] = s;
  __syncthreads();
  for (int off = 1; off < 1024; off <<= 1){
    int v = (t >= off) ? part[t - off] : 0;
    __syncthreads();
    part[t] += v;
    __syncthreads();
  }
  int base = (t == 0) ? 0 : part[t - 1];
  for (int i = lo; i < hi; i++){
    row_start[i] = base;
    base += deg[i];
  }
  if (t == 1023) row_start[N] = E;
}

__global__ void csr_scatter(const int* __restrict__ snd,
                            const int* __restrict__ rcv,
                            int* __restrict__ cursor,
                            int* __restrict__ pinv,
                            int* __restrict__ psnd,
                            int* __restrict__ prcv, int E){
  int e = blockIdx.x * blockDim.x + threadIdx.x;
  if (e < E){
    int r = rcv[e];
    int p = atomicAdd(&cursor[r], 1);
    pinv[e] = p;
    psnd[p] = snd[e];
    prcv[p] = r;
  }
}

// ---------------------------------------------------------------------------
// Edge raw features (written PERMUTED via pinv) + per-block partial sums
// ---------------------------------------------------------------------------
__global__ void edge_raw_stats(const float* __restrict__ pos,
                               const int* __restrict__ snd,
                               const int* __restrict__ rcv,
                               const int* __restrict__ pinv,
                               float* __restrict__ ef_raw,
                               float* __restrict__ epart, int E){
  __shared__ float red[4][6];
  int tid = threadIdx.x, w = tid >> 6, l = tid & 63;
  int e = blockIdx.x * blockDim.x + tid;
  float s[6] = {0.f,0.f,0.f,0.f,0.f,0.f};
  if (e < E){
    int si = snd[e], ri = rcv[e];
    float rx = pos[2*si]   - pos[2*ri];
    float ry = pos[2*si+1] - pos[2*ri+1];
    float nm = sqrtf(rx*rx + ry*ry);
    int p = pinv[e];
    ef_raw[3*p]   = rx;
    ef_raw[3*p+1] = ry;
    ef_raw[3*p+2] = nm;
    s[0] = rx; s[1] = ry; s[2] = nm;
    s[3] = rx*rx; s[4] = ry*ry; s[5] = nm*nm;
  }
#pragma unroll
  for (int k = 0; k < 6; k++) s[k] = wave_sum(s[k]);
  if (l == 0)
#pragma unroll
    for (int k = 0; k < 6; k++) red[w][k] = s[k];
  __syncthreads();
  if (tid < 6)
    epart[(size_t)blockIdx.x * 6 + tid] =
      red[0][tid] + red[1][tid] + red[2][tid] + red[3][tid];
}

// ---------------------------------------------------------------------------
// Node stats partials
// ---------------------------------------------------------------------------
__global__ void node_stats(const float* __restrict__ zl,
                           const float* __restrict__ z_target,
                           float* __restrict__ npart, int N){
  __shared__ float red[4][12];
  int tid = threadIdx.x, w = tid >> 6, l = tid & 63;
  int n = blockIdx.x * blockDim.x + tid;
  float s[12];
#pragma unroll
  for (int i = 0; i < 12; i++) s[i] = 0.f;
  if (n < N){
#pragma unroll
    for (int d = 0; d < 3; d++){
      float z = zl[3*n+d];
      float t = z_target[3*n+d] - z;
      s[d]   = z;  s[3+d] = z*z;
      s[6+d] = t;  s[9+d] = t*t;
    }
  }
#pragma unroll
  for (int i = 0; i < 12; i++) s[i] = wave_sum(s[i]);
  if (l == 0)
#pragma unroll
    for (int i = 0; i < 12; i++) red[w][i] = s[i];
  __syncthreads();
  if (tid < 12)
    npart[(size_t)blockIdx.x * 12 + tid] =
      red[0][tid] + red[1][tid] + red[2][tid] + red[3][tid];
}

__global__ void reduce_stats(const float* __restrict__ ep, int ne,
                             const float* __restrict__ np_, int nn,
                             float* __restrict__ raw){
  __shared__ float red[4];
  int tid = threadIdx.x, w = tid >> 6, l = tid & 63;
  for (int j = 0; j < 6; j++){
    float s = 0.f;
    for (int b = tid; b < ne; b += 256) s += ep[(size_t)b * 6 + j];
    s = wave_sum(s);
    if (l == 0) red[w] = s;
    __syncthreads();
    if (tid == 0) raw[j] = red[0] + red[1] + red[2] + red[3];
    __syncthreads();
  }
  for (int j = 0; j < 12; j++){
    float s = 0.f;
    for (int b = tid; b < nn; b += 256) s += np_[(size_t)b * 12 + j];
    s = wave_sum(s);
    if (l == 0) red[w] = s;
    __syncthreads();
    if (tid == 0) raw[6 + j] = red[0] + red[1] + red[2] + red[3];
    __syncthreads();
  }
}

// stats_fin: em[0..2] es[3..5] nm[6..8] ns[9..11] om[12..14] os[15..17]
__global__ void finalize_stats(const float* __restrict__ raw,
                               float* __restrict__ fin, int E, int N){
#pragma unroll
  for (int d = 0; d < 3; d++){
    float cE = (float)E, cN = (float)N;
    float m, v;
    m = raw[0+d] / cE; v = fmaxf(raw[3+d]/cE - m*m, 0.f);
    fin[0+d] = m;  fin[3+d]  = fmaxf(sqrtf(v), 1e-8f);
    m = raw[6+d] / cN; v = fmaxf(raw[9+d]/cN - m*m, 0.f);
    fin[6+d] = m;  fin[9+d]  = fmaxf(sqrtf(v), 1e-8f);
    m = raw[12+d] / cN; v = fmaxf(raw[15+d]/cN - m*m, 0.f);
    fin[12+d] = m; fin[15+d] = fmaxf(sqrtf(v), 1e-8f);
  }
}

// ---------------------------------------------------------------------------
// Weight packing: fp32 [K][128] -> bf16 fragment-major (1KB per B-fragment)
// ---------------------------------------------------------------------------
__global__ void pack_weights(const float* __restrict__ encEW2,
                             const float* __restrict__ encNW2,
                             const float* __restrict__ decW1,
                             const float* __restrict__ beW1,
                             const float* __restrict__ beW2,
                             const float* __restrict__ bnW1,
                             const float* __restrict__ bnW2,
                             __hip_bfloat16* __restrict__ wp){
  int y = blockIdx.y;
  const float* src; __hip_bfloat16* dst; int K;
  if (y == 0){ src = encEW2; dst = wp;          K = 128; }
  else if (y == 1){ src = encNW2; dst = wp + 16384; K = 128; }
  else if (y == 2){ src = decW1;  dst = wp + 32768; K = 128; }
  else {
    int b = (y - 3) >> 2, j = (y - 3) & 3;
    __hip_bfloat16* base = wp + 49152 + b * 114688;
    if (j == 0){ src = beW1 + b*49152; dst = base;          K = 384; }
    else if (j == 1){ src = beW2 + b*16384; dst = base + 49152; K = 128; }
    else if (j == 2){ src = bnW1 + b*32768; dst = base + 65536; K = 256; }
    else { src = bnW2 + b*16384; dst = base + 98304; K = 128; }
  }
  int id = blockIdx.x * blockDim.x + threadIdx.x;
  if (id >= 128 * K) return;
  int c = id >> 12;
  int r = id & 4095;
  int t = r >> 9;
  int l = (r >> 3) & 63;
  int j = r & 7;
  int k = c * 32 + ((l >> 4) << 3) + j;
  int n = t * 16 + (l & 15);
  dst[id] = __float2bfloat16(src[k * 128 + n]);
}

// ---------------------------------------------------------------------------
// Fused encoder: out = (relu(norm(raw3)@W1+b1)) @ W2 + b2; W2 staged in LDS
// ---------------------------------------------------------------------------
__launch_bounds__(256)
__global__ void encoder_fused(const float* __restrict__ raw,
                              const float* __restrict__ mptr,
                              const float* __restrict__ sptr,
                              const float* __restrict__ W1,   // [3][128] f32
                              const float* __restrict__ b1,
                              const __hip_bfloat16* __restrict__ W2f, // frag-major
                              const float* __restrict__ b2,
                              __hip_bfloat16* __restrict__ out, int rows){
  __shared__ __align__(16) short bsh[16384];
  const int tid = threadIdx.x, w = tid >> 6, l = tid & 63, m = l & 15, q = l >> 4;
  const short* wsrc = (const short*)W2f;
#pragma unroll
  for (int i = 0; i < 8; i++){
    int inst = w * 8 + i;
    gl_lds16(wsrc + inst * 512 + l * 8, &bsh[inst * 512]);
  }
  float s0 = mptr[0], s1 = mptr[1], s2 = mptr[2];
  float d0 = sptr[0], d1 = sptr[1], d2 = sptr[2];
  const int row0 = blockIdx.x * 64 + w * 16;
  const int ra = min(row0 + m, rows - 1);
  float x0 = (raw[3*ra]   - s0) / d0;
  float x1 = (raw[3*ra+1] - s1) / d1;
  float x2 = (raw[3*ra+2] - s2) / d2;
  bf16x8 afr[4];
#pragma unroll
  for (int c = 0; c < 4; c++){
    int nb = c * 32 + q * 8;
#pragma unroll
    for (int j = 0; j < 8; j++){
      float h = b1[nb+j] + x0 * W1[nb+j] + x1 * W1[128+nb+j] + x2 * W1[256+nb+j];
      afr[c][j] = f2bf(fmaxf(h, 0.f));
    }
  }
  f32x4 acc[8];
#pragma unroll
  for (int t = 0; t < 8; t++) acc[t] = (f32x4){0.f,0.f,0.f,0.f};
  __syncthreads();
#pragma unroll
  for (int c = 0; c < 4; c++){
#pragma unroll
    for (int t = 0; t < 8; t++){
      bf16x8 b = *(const bf16x8*)&bsh[(c*8 + t)*512 + l*8];
      acc[t] = __builtin_amdgcn_mfma_f32_16x16x32_bf16(afr[c], b, acc[t], 0, 0, 0);
    }
  }
  const int row_d = row0 + q * 4;
#pragma unroll
  for (int t = 0; t < 8; t++){
    int col = t * 16 + m;
    float bb = b2[col];
#pragma unroll
    for (int r = 0; r < 4; r++){
      int e = row_d + r;
      if (e < rows) out[(size_t)e * HDIM + col] = __float2bfloat16(acc[t][r] + bb);
    }
  }
}

// ---------------------------------------------------------------------------
// Decoder layer 1: out_f32 = relu(A_bf16 @ W + b); W staged once in LDS
// ---------------------------------------------------------------------------
__launch_bounds__(256)
__global__ void gemm128_g(const __hip_bfloat16* __restrict__ A,
                          const __hip_bfloat16* __restrict__ Wf,
                          const float* __restrict__ bias,
                          float* __restrict__ out, int rows){
  __shared__ __align__(16) short bsh[16384];
  const int tid = threadIdx.x, w = tid >> 6, l = tid & 63, m = l & 15, q = l >> 4;
  const short* wsrc = (const short*)Wf;
#pragma unroll
  for (int i = 0; i < 8; i++){
    int inst = w * 8 + i;
    gl_lds16(wsrc + inst * 512 + l * 8, &bsh[inst * 512]);
  }
  const int row0 = blockIdx.x * 64 + w * 16;
  const int ra = min(row0 + m, rows - 1);
  const short* pa = (const short*)A + (size_t)ra * HDIM + q * 8;
  bf16x8 afr[4];
#pragma unroll
  for (int c = 0; c < 4; c++) afr[c] = *(const bf16x8*)(pa + c * 32);
  f32x4 acc[8];
#pragma unroll
  for (int t = 0; t < 8; t++) acc[t] = (f32x4){0.f,0.f,0.f,0.f};
  __syncthreads();
#pragma unroll
  for (int c = 0; c < 4; c++){
#pragma unroll
    for (int t = 0; t < 8; t++){
      bf16x8 b = *(const bf16x8*)&bsh[(c*8 + t)*512 + l*8];
      acc[t] = __builtin_amdgcn_mfma_f32_16x16x32_bf16(afr[c], b, acc[t], 0, 0, 0);
    }
  }
  const int row_d = row0 + q * 4;
#pragma unroll
  for (int t = 0; t < 8; t++){
    int col = t * 16 + m;
    float bb = bias[col];
#pragma unroll
    for (int r = 0; r < 4; r++){
      int e = row_d + r;
      if (e < rows) out[(size_t)e * HDIM + col] = fmaxf(acc[t][r] + bb, 0.f);
    }
  }
}

// ---------------------------------------------------------------------------
// Edge block v6: ef += MLP([ef | nf[snd] | nf[rcv]])  — permuted edge space.
// 512 threads (8 waves), 128 rows/block, 8KB dbuf chunks shared by 8 waves
// (1 staging instruction per wave per chunk).
// ---------------------------------------------------------------------------
__launch_bounds__(512)
__global__ void edge_block(const int* __restrict__ psnd,
                           const int* __restrict__ prcv,
                           const __hip_bfloat16* __restrict__ nf,
                           __hip_bfloat16* __restrict__ ef,
                           const __hip_bfloat16* __restrict__ Wfrag, // eW1|eW2 frag-major
                           const float* __restrict__ b1,
                           const float* __restrict__ b2,
                           int E){
  __shared__ __align__(16) short bsh[2][4096];   // 2 x 8 KB
  __shared__ __align__(16) short hsh[8][16][136];
  const int tid = threadIdx.x, w = tid >> 6, l = tid & 63, m = l & 15, q = l >> 4;
  const short* wsrc = (const short*)Wfrag;
  gl_lds16(wsrc + w*512 + l*8, &bsh[0][w*512]);   // chunk 0

  const int row0 = blockIdx.x * 128 + w * 16;
  const int ra = min(row0 + m, E - 1);
  const int si = psnd[ra], ri = prcv[ra];
  const short* pe = (const short*)ef + (size_t)ra * HDIM + q * 8;
  const short* ps = (const short*)nf + (size_t)si * HDIM + q * 8;
  const short* pr = (const short*)nf + (size_t)ri * HDIM + q * 8;
  bf16x8 afr[12];
#pragma unroll
  for (int c = 0; c < 4; c++){
    afr[c]   = *(const bf16x8*)(pe + c * 32);
    afr[4+c] = *(const bf16x8*)(ps + c * 32);
    afr[8+c] = *(const bf16x8*)(pr + c * 32);
  }
  f32x4 acc[8];
#pragma unroll
  for (int t = 0; t < 8; t++) acc[t] = (f32x4){0.f,0.f,0.f,0.f};
  __syncthreads();   // chunk 0 staged
#pragma unroll
  for (int c = 0; c < 12; c++){
    gl_lds16(wsrc + (c+1)*4096 + w*512 + l*8, &bsh[(c+1)&1][w*512]);
    const short* bb = &bsh[c & 1][0];
#pragma unroll
    for (int t = 0; t < 8; t++){
      bf16x8 b = *(const bf16x8*)(bb + t*512 + l*8);
      acc[t] = __builtin_amdgcn_mfma_f32_16x16x32_bf16(afr[c], b, acc[t], 0, 0, 0);
    }
    __syncthreads();
  }
#pragma unroll
  for (int t = 0; t < 8; t++){
    float bb = b1[t * 16 + m];
#pragma unroll
    for (int r = 0; r < 4; r++)
      hsh[w][q*4 + r][t*16 + m] = f2bf(fmaxf(acc[t][r] + bb, 0.f));
  }
  const short* ph = &hsh[w][m][0] + q * 8;
  f32x4 acc2[8];
#pragma unroll
  for (int t = 0; t < 8; t++) acc2[t] = (f32x4){0.f,0.f,0.f,0.f};
#pragma unroll
  for (int c = 12; c < 16; c++){
    if (c + 1 < 16)
      gl_lds16(wsrc + (c+1)*4096 + w*512 + l*8, &bsh[(c+1)&1][w*512]);
    bf16x8 a = *(const bf16x8*)(ph + (c - 12) * 32);
    const short* bb = &bsh[c & 1][0];
#pragma unroll
    for (int t = 0; t < 8; t++){
      bf16x8 b = *(const bf16x8*)(bb + t*512 + l*8);
      acc2[t] = __builtin_amdgcn_mfma_f32_16x16x32_bf16(a, b, acc2[t], 0, 0, 0);
    }
    if (c < 15) __syncthreads();
  }
#pragma unroll
  for (int t = 0; t < 8; t++){
    float bb = b2[t * 16 + m];
#pragma unroll
    for (int r = 0; r < 4; r++)
      hsh[w][q*4 + r][t*16 + m] = f2bf(acc2[t][r] + bb);
  }
  int orow = row0 + (l >> 2);
  if (orow < E){
    const short* src = &hsh[w][l >> 2][(l & 3) * 32];
    short* dst = (short*)ef + (size_t)orow * HDIM + (l & 3) * 32;
#pragma unroll
    for (int k = 0; k < 4; k++){
      bf16x8 vnew = *(const bf16x8*)(src + k * 8);
      bf16x8 vold = *(const bf16x8*)(dst + k * 8);
      bf16x8 vo;
#pragma unroll
      for (int j = 0; j < 8; j++) vo[j] = f2bf(bfb2f(vnew[j]) + bfb2f(vold[j]));
      *(bf16x8*)(dst + k * 8) = vo;
    }
  }
}

// ---------------------------------------------------------------------------
// Node block v6: agg = streaming gather over contiguous ef rows (CSR order);
// nf += MLP([nf | agg]). 512 threads, 128 rows/block, 12 chunks.
// ---------------------------------------------------------------------------
__launch_bounds__(512)
__global__ void node_block(const int* __restrict__ row_start,
                           const __hip_bfloat16* __restrict__ ef,  // permuted
                           __hip_bfloat16* __restrict__ nf,
                           const __hip_bfloat16* __restrict__ Wfrag, // nW1|nW2
                           const float* __restrict__ b1,
                           const float* __restrict__ b2,
                           int N){
  __shared__ __align__(16) short bsh[2][4096];
  __shared__ __align__(16) short hsh[8][16][136];
  const int tid = threadIdx.x, w = tid >> 6, l = tid & 63, m = l & 15, q = l >> 4;
  const short* wsrc = (const short*)Wfrag;
  gl_lds16(wsrc + w*512 + l*8, &bsh[0][w*512]);

  const int row0 = blockIdx.x * 128 + w * 16;
  const int ra = min(row0 + m, N - 1);
  const short* pn = (const short*)nf + (size_t)ra * HDIM + q * 8;
  bf16x8 afr[8];
#pragma unroll
  for (int c = 0; c < 4; c++) afr[c] = *(const bf16x8*)(pn + c * 32);
  float sum[4][8];
#pragma unroll
  for (int c = 0; c < 4; c++)
#pragma unroll
    for (int j = 0; j < 8; j++) sum[c][j] = 0.f;
  int s0 = row_start[ra], s1 = row_start[ra + 1];
  for (int it = s0; it < s1; it++){
    const short* pf = (const short*)ef + (size_t)it * HDIM + q * 8;
#pragma unroll
    for (int c = 0; c < 4; c++){
      bf16x8 v = *(const bf16x8*)(pf + c * 32);
#pragma unroll
      for (int j = 0; j < 8; j++) sum[c][j] += bfb2f(v[j]);
    }
  }
#pragma unroll
  for (int c = 0; c < 4; c++)
#pragma unroll
    for (int j = 0; j < 8; j++) afr[4 + c][j] = f2bf(sum[c][j]);

  f32x4 acc[8];
#pragma unroll
  for (int t = 0; t < 8; t++) acc[t] = (f32x4){0.f,0.f,0.f,0.f};
  __syncthreads();
#pragma unroll
  for (int c = 0; c < 8; c++){
    gl_lds16(wsrc + (c+1)*4096 + w*512 + l*8, &bsh[(c+1)&1][w*512]);
    const short* bb = &bsh[c & 1][0];
#pragma unroll
    for (int t = 0; t < 8; t++){
      bf16x8 b = *(const bf16x8*)(bb + t*512 + l*8);
      acc[t] = __builtin_amdgcn_mfma_f32_16x16x32_bf16(afr[c], b, acc[t], 0, 0, 0);
    }
    __syncthreads();
  }
#pragma unroll
  for (int t = 0; t < 8; t++){
    float bb = b1[t * 16 + m];
#pragma unroll
    for (int r = 0; r < 4; r++)
      hsh[w][q*4 + r][t*16 + m] = f2bf(fmaxf(acc[t][r] + bb, 0.f));
  }
  const short* ph = &hsh[w][m][0] + q * 8;
  f32x4 acc2[8];
#pragma unroll
  for (int t = 0; t < 8; t++) acc2[t] = (f32x4){0.f,0.f,0.f,0.f};
#pragma unroll
  for (int c = 8; c < 12; c++){
    if (c + 1 < 12)
      gl_lds16(wsrc + (c+1)*4096 + w*512 + l*8, &bsh[(c+1)&1][w*512]);
    bf16x8 a = *(const bf16x8*)(ph + (c - 8) * 32);
    const short* bb = &bsh[c & 1][0];
#pragma unroll
    for (int t = 0; t < 8; t++){
      bf16x8 b = *(const bf16x8*)(bb + t*512 + l*8);
      acc2[t] = __builtin_amdgcn_mfma_f32_16x16x32_bf16(a, b, acc2[t], 0, 0, 0);
    }
    if (c < 11) __syncthreads();
  }
#pragma unroll
  for (int t = 0; t < 8; t++){
    float bb = b2[t * 16 + m];
#pragma unroll
    for (int r = 0; r < 4; r++)
      hsh[w][q*4 + r][t*16 + m] = f2bf(acc2[t][r] + bb);
  }
  int orow = row0 + (l >> 2);
  if (orow < N){
    const short* src = &hsh[w][l >> 2][(l & 3) * 32];
    short* dst = (short*)nf + (size_t)orow * HDIM + (l & 3) * 32;
#pragma unroll
    for (int k = 0; k < 4; k++){
      bf16x8 vnew = *(const bf16x8*)(src + k * 8);
      bf16x8 vold = *(const bf16x8*)(dst + k * 8);
      bf16x8 vo;
#pragma unroll
      for (int j = 0; j < 8; j++) vo[j] = f2bf(bfb2f(vnew[j]) + bfb2f(vold[j]));
      *(bf16x8*)(dst + k * 8) = vo;
    }
  }
}

// ---------------------------------------------------------------------------
// Decoder final layer: [rows,128] fp32 @ [128,3] + b
// ---------------------------------------------------------------------------
__global__ void dec_final(const float* __restrict__ hbuf,
                          const float* __restrict__ W2,
                          const float* __restrict__ b2,
                          float* __restrict__ outd, int rows){
  __shared__ float hl[64 * 129];
  __shared__ float Wl[HDIM * 3];
  __shared__ float bl[3];
  int t = threadIdx.x;
  int node0 = blockIdx.x * 64;
  for (int i = t; i < HDIM * 3; i += 256) Wl[i] = W2[i];
  if (t < 3) bl[t] = b2[t];
#pragma unroll
  for (int i = 0; i < 32; i++){
    int lin = t + i * 256;
    int r = lin >> 7;
    int c = lin & 127;
    int node = node0 + r;
    hl[r * 129 + c] = (node < rows) ? hbuf[(size_t)node * HDIM + c] : 0.f;
  }
  __syncthreads();
  if (t < 64){
    int node = node0 + t;
    if (node < rows){
      float a0 = bl[0], a1 = bl[1], a2 = bl[2];
      for (int k = 0; k < HDIM; k++){
        float v = hl[t * 129 + k];
        a0 += v * Wl[k * 3];
        a1 += v * Wl[k * 3 + 1];
        a2 += v * Wl[k * 3 + 2];
      }
      outd[3 * node]     = a0;
      outd[3 * node + 1] = a1;
      outd[3 * node + 2] = a2;
    }
  }
}

// ---------------------------------------------------------------------------
// Epilogue + finalize (partials, no atomics)
// ---------------------------------------------------------------------------
__global__ void epilogue(const float* __restrict__ dec_out,
                         const float* __restrict__ zl,
                         const float* __restrict__ z_target,
                         const float* __restrict__ fin,
                         float* __restrict__ d_out,
                         float* __restrict__ lpart, int N){
  __shared__ float red[4][4];
  int tid = threadIdx.x, w = tid >> 6, l = tid & 63;
  int n = blockIdx.x * blockDim.x + tid;
  float s[4] = {0.f,0.f,0.f,0.f};
  if (n < N){
#pragma unroll
    for (int d = 0; d < 3; d++){
      float om = fin[12 + d], os = fin[15 + d];
      float o   = dec_out[3*n + d];
      float zld = zl[3*n + d];
      float zt  = z_target[3*n + d];
      float tgt = zt - zld;
      float tn  = (tgt - om) / os;
      float diff = tn - o;
      s[0] += diff * diff;
      float zp = zld + o * os + om;
      d_out[3*n + d] = zp;
      float e = zp - zt;
      s[1 + d] = e * e;
    }
  }
#pragma unroll
  for (int k = 0; k < 4; k++) s[k] = wave_sum(s[k]);
  if (l == 0)
#pragma unroll
    for (int k = 0; k < 4; k++) red[w][k] = s[k];
  __syncthreads();
  if (tid < 4)
    lpart[(size_t)blockIdx.x * 4 + tid] =
      red[0][tid] + red[1][tid] + red[2][tid] + red[3][tid];
}

__global__ void finalize_out(const float* __restrict__ lpart, int nb,
                             float* __restrict__ d_out, int N){
  __shared__ float red[4];
  __shared__ float vals[4];
  int tid = threadIdx.x, w = tid >> 6, l = tid & 63;
  for (int j = 0; j < 4; j++){
    float s = 0.f;
    for (int b = tid; b < nb; b += 256) s += lpart[(size_t)b * 4 + j];
    s = wave_sum(s);
    if (l == 0) red[w] = s;
    __syncthreads();
    if (tid == 0) vals[j] = red[0] + red[1] + red[2] + red[3];
    __syncthreads();
  }
  if (tid == 0){
    float cN = (float)N;
    float loss = vals[0] / (3.f * cN);
    float rmse = (sqrtf(vals[1] / cN) + sqrtf(vals[2] / cN) + sqrtf(vals[3] / cN)) / 3.f;
    d_out[(size_t)3 * N]     = loss;
    d_out[(size_t)3 * N + 1] = rmse;
  }
}

// ---------------------------------------------------------------------------
extern "C" void kernel_launch(void* const* d_in, const int* in_sizes, int n_in,
                              void* d_out, int out_size, void* d_ws, size_t ws_size,
                              hipStream_t stream){
  const float* z           = (const float*)d_in[0];
  const float* z_target    = (const float*)d_in[1];
  const float* pos         = (const float*)d_in[2];
  const float* enc_node_W1 = (const float*)d_in[3];
  const float* enc_node_b1 = (const float*)d_in[4];
  const float* enc_node_W2 = (const float*)d_in[5];
  const float* enc_node_b2 = (const float*)d_in[6];
  const float* enc_edge_W1 = (const float*)d_in[7];
  const float* enc_edge_b1 = (const float*)d_in[8];
  const float* enc_edge_W2 = (const float*)d_in[9];
  const float* enc_edge_b2 = (const float*)d_in[10];
  const float* dec_W1      = (const float*)d_in[11];
  const float* dec_b1      = (const float*)d_in[12];
  const float* dec_W2      = (const float*)d_in[13];
  const float* dec_b2      = (const float*)d_in[14];
  const float* blk_edge_W1 = (const float*)d_in[15];
  const float* blk_edge_b1 = (const float*)d_in[16];
  const float* blk_edge_W2 = (const float*)d_in[17];
  const float* blk_edge_b2 = (const float*)d_in[18];
  const float* blk_node_W1 = (const float*)d_in[19];
  const float* blk_node_b1 = (const float*)d_in[20];
  const float* blk_node_W2 = (const float*)d_in[21];
  const float* blk_node_b2 = (const float*)d_in[22];
  const int*   senders     = (const int*)d_in[23];
  const int*   receivers   = (const int*)d_in[24];

  const int N = in_sizes[1] / 3;
  const int E = in_sizes[23];
  const float* zl = z + (size_t)N * 3;

  const int neb = ceil_div(E, TPB);
  const int nnb = ceil_div(N, TPB);

  char* p = (char*)d_ws;
  auto carve = [&](size_t bytes) -> char* {
    char* r = p; p += (bytes + 255) & ~(size_t)255; return r;
  };
  float* stats_raw = (float*)carve(32 * 4);
  float* stats_fin = (float*)carve(32 * 4);
  float* epart     = (float*)carve((size_t)neb * 6 * 4);
  float* npart     = (float*)carve((size_t)nnb * 12 * 4);
  float* lpart     = (float*)carve((size_t)nnb * 4 * 4);
  float* ef_raw    = (float*)carve((size_t)E * 3 * 4);
  float* dec_out   = (float*)carve((size_t)N * 3 * 4);
  float* hbuf      = (float*)carve((size_t)N * HDIM * 4);
  int*   deg       = (int*)carve((size_t)N * 4);
  int*   row_start = (int*)carve((size_t)(N + 1) * 4);
  int*   cursor    = (int*)carve((size_t)N * 4);
  int*   pinv      = (int*)carve((size_t)E * 4);
  int*   psnd      = (int*)carve((size_t)E * 4);
  int*   prcv      = (int*)carve((size_t)E * 4);
  __hip_bfloat16* wp = (__hip_bfloat16*)carve((size_t)507904 * 2);
  __hip_bfloat16* ef = (__hip_bfloat16*)carve((size_t)E * HDIM * 2);
  __hip_bfloat16* nf = (__hip_bfloat16*)carve((size_t)N * HDIM * 2);

  float* out = (float*)d_out;

  hipMemsetAsync(deg, 0, (size_t)N * 4, stream);

  // CSR + permutation first (edge_raw_stats scatters via pinv)
  csr_hist<<<neb, TPB, 0, stream>>>(receivers, deg, E);
  csr_scan<<<1, 1024, 0, stream>>>(deg, row_start, N, E);
  hipMemcpyAsync(cursor, row_start, (size_t)N * 4, hipMemcpyDeviceToDevice, stream);
  csr_scatter<<<neb, TPB, 0, stream>>>(senders, receivers, cursor, pinv, psnd, prcv, E);

  edge_raw_stats<<<neb, TPB, 0, stream>>>(pos, senders, receivers, pinv, ef_raw, epart, E);
  node_stats<<<nnb, TPB, 0, stream>>>(zl, z_target, npart, N);
  reduce_stats<<<1, TPB, 0, stream>>>(epart, neb, npart, nnb, stats_raw);
  finalize_stats<<<1, 1, 0, stream>>>(stats_raw, stats_fin, E, N);

  pack_weights<<<dim3(192, 19), TPB, 0, stream>>>(enc_edge_W2, enc_node_W2, dec_W1,
                                                  blk_edge_W1, blk_edge_W2,
                                                  blk_node_W1, blk_node_W2, wp);

  encoder_fused<<<ceil_div(E, 64), TPB, 0, stream>>>(ef_raw, stats_fin + 0, stats_fin + 3,
                                                     enc_edge_W1, enc_edge_b1,
                                                     wp, enc_edge_b2, ef, E);
  encoder_fused<<<ceil_div(N, 64), TPB, 0, stream>>>(zl, stats_fin + 6, stats_fin + 9,
                                                     enc_node_W1, enc_node_b1,
                                                     wp + 16384, enc_node_b2, nf, N);

  for (int b = 0; b < 4; b++){
    const __hip_bfloat16* eWf = wp + 49152 + (size_t)b * 114688;   // eW1|eW2 (16 chunks)
    const __hip_bfloat16* nWf = eWf + 65536;                       // nW1|nW2 (12 chunks)
    const float* eb1 = blk_edge_b1 + (size_t)b * 128;
    const float* eb2 = blk_edge_b2 + (size_t)b * 128;
    const float* nb1 = blk_node_b1 + (size_t)b * 128;
    const float* nb2 = blk_node_b2 + (size_t)b * 128;

    edge_block<<<ceil_div(E, 128), 512, 0, stream>>>(psnd, prcv, nf, ef,
                                                     eWf, eb1, eb2, E);
    node_block<<<ceil_div(N, 128), 512, 0, stream>>>(row_start, ef, nf,
                                                     nWf, nb1, nb2, N);
  }

  gemm128_g<<<ceil_div(N, 64), TPB, 0, stream>>>(nf, wp + 32768, dec_b1, hbuf, N);
  dec_final<<<ceil_div(N, 64), TPB, 0, stream>>>(hbuf, dec_W2, dec_b2, dec_out, N);

  epilogue<<<nnb, TPB, 0, stream>>>(dec_out, zl, z_target, stats_fin,
                                    out, lpart, N);
  finalize_out<<<1, TPB, 0, stream>>>(lpart, nnb, out, N);
}